// Round 1
// baseline (2207.724 us; speedup 1.0000x reference)
//
#include <hip/hip_runtime.h>

#define NN 32768
#define HH 128
#define GG 50
#define EE 524288

constexpr float GSTEP = 10.0f / 49.0f;
constexpr float GCOEF = -0.5f / (GSTEP * GSTEP);
constexpr float PI_OVER_CUT = 0.31415926535897931f;   // pi / 10
constexpr float LOG2F_ = 0.69314718055994531f;

__device__ __forceinline__ float sspf(float x) {
    // shifted softplus, overflow-safe like jax.nn.softplus
    return fmaxf(x, 0.0f) + log1pf(expf(-fabsf(x))) - LOG2F_;
}
__device__ __forceinline__ unsigned fenc(float f) {
    unsigned b = __float_as_uint(f);
    return (b & 0x80000000u) ? ~b : (b | 0x80000000u);
}
__device__ __forceinline__ float fdec(unsigned u) {
    unsigned b = (u & 0x80000000u) ? (u ^ 0x80000000u) : ~u;
    return __uint_as_float(b);
}
__device__ __forceinline__ int get_mask(const void* mp, int mode, int e) {
    if (mode) return ((const unsigned char*)mp)[e] != 0;
    return ((const int*)mp)[e] != 0;
}

#define FMA8(ACCROW, AV, B0, B1)                                   \
    ACCROW[0] += (AV) * B0.x; ACCROW[1] += (AV) * B0.y;            \
    ACCROW[2] += (AV) * B0.z; ACCROW[3] += (AV) * B0.w;            \
    ACCROW[4] += (AV) * B1.x; ACCROW[5] += (AV) * B1.y;            \
    ACCROW[6] += (AV) * B1.z; ACCROW[7] += (AV) * B1.w;

// ---------------------------------------------------------------------------
// Detect whether virtual_edge_mask arrived as 1-byte bools or int32.
// int32 little-endian 0/1 values => bytes at offset%4 != 0 are ALL zero.
__global__ void k_detect(const unsigned char* __restrict__ mb, int* __restrict__ flag) {
    __shared__ int any;
    if (threadIdx.x == 0) any = 0;
    __syncthreads();
    int local = 0;
    for (int i = threadIdx.x; i < 16384; i += blockDim.x)
        if ((i & 3) != 0 && mb[i]) local = 1;
    if (local) atomicOr(&any, 1);
    __syncthreads();
    if (threadIdx.x == 0) *flag = any;   // 1 => byte mode, 0 => int32 mode
}

// ---------------------------------------------------------------------------
// u = h @ attn_w1[0:128], v = h @ attn_w1[128:256], xh = h @ lin1_w
__global__ __launch_bounds__(256) void k_node_proj(
    const float* __restrict__ h, const float* __restrict__ attn_w1,
    const float* __restrict__ lin1_w,
    float* __restrict__ u, float* __restrict__ v, float* __restrict__ xh)
{
    __shared__ alignas(16) float hT[HH][68];
    const int tid = threadIdx.x;
    const int n0 = blockIdx.x * 64;
    const int mat = blockIdx.y;
    const float* __restrict__ W = (mat == 0) ? attn_w1 : (mat == 1 ? attn_w1 + HH * HH : lin1_w);
    float* __restrict__ out = (mat == 0) ? u : (mat == 1 ? v : xh);

    for (int idx = tid; idx < 64 * HH; idx += 256) {
        const int n = idx >> 7, k = idx & 127;
        hT[k][n] = h[(size_t)(n0 + n) * HH + k];
    }
    __syncthreads();

    const int te = tid & 15, tj = tid >> 4;
    float acc[4][8] = {};
    for (int k = 0; k < HH; k++) {
        const float4 a  = *(const float4*)&hT[k][te * 4];
        const float4 b0 = *(const float4*)(W + (size_t)k * HH + tj * 8);
        const float4 b1 = *(const float4*)(W + (size_t)k * HH + tj * 8 + 4);
        const float av[4] = {a.x, a.y, a.z, a.w};
#pragma unroll
        for (int i = 0; i < 4; i++) { const float ai = av[i]; FMA8(acc[i], ai, b0, b1); }
    }
#pragma unroll
    for (int i = 0; i < 4; i++) {
        float* o = out + (size_t)(n0 + te * 4 + i) * HH + tj * 8;
        float4 r0 = {acc[i][0], acc[i][1], acc[i][2], acc[i][3]};
        float4 r1 = {acc[i][4], acc[i][5], acc[i][6], acc[i][7]};
        *(float4*)o = r0;
        *(float4*)(o + 4) = r1;
    }
}

// ---------------------------------------------------------------------------
// Per-edge: d, gaussian smear, attention score; atomicMax of masked scores.
__global__ __launch_bounds__(256) void k_edge_score(
    const float* __restrict__ pos, const int* __restrict__ ei,
    const void* __restrict__ maskp, const int* __restrict__ flagp,
    const float* __restrict__ u, const float* __restrict__ v,
    const float* __restrict__ attn_w1, const float* __restrict__ attn_b1,
    const float* __restrict__ attn_w2, const float* __restrict__ attn_b2,
    float* __restrict__ dbuf, float* __restrict__ score, unsigned* __restrict__ menc)
{
    __shared__ alignas(16) float eaT[GG][64];
    __shared__ float dsh[64];
    __shared__ int rsh[64], csh[64];
    __shared__ float parts[64][17];
    const int tid = threadIdx.x;
    const int e0 = blockIdx.x * 64;

    if (tid < 64) {
        const int e = e0 + tid;
        const int r = ei[e], c = ei[EE + e];
        rsh[tid] = r; csh[tid] = c;
        const float dx = pos[r * 3 + 0] - pos[c * 3 + 0];
        const float dy = pos[r * 3 + 1] - pos[c * 3 + 1];
        const float dz = pos[r * 3 + 2] - pos[c * 3 + 2];
        const float d = sqrtf(dx * dx + dy * dy + dz * dz);
        dsh[tid] = d;
        dbuf[e] = d;
    }
    __syncthreads();
    {
        const int e = tid & 63, g0 = tid >> 6;
        const float d = dsh[e];
        for (int g = g0; g < GG; g += 4) {
            const float t = d - g * GSTEP;
            eaT[g][e] = expf(GCOEF * t * t);
        }
    }
    __syncthreads();

    const int te = tid & 15, tj = tid >> 4;
    const float* __restrict__ W1C = attn_w1 + 256 * HH;
    float acc[4][8] = {};
    for (int g = 0; g < GG; g++) {
        const float4 a  = *(const float4*)&eaT[g][te * 4];
        const float4 b0 = *(const float4*)(W1C + g * HH + tj * 8);
        const float4 b1 = *(const float4*)(W1C + g * HH + tj * 8 + 4);
        const float av[4] = {a.x, a.y, a.z, a.w};
#pragma unroll
        for (int i = 0; i < 4; i++) { const float ai = av[i]; FMA8(acc[i], ai, b0, b1); }
    }

    const float4 w20 = *(const float4*)(attn_w2 + tj * 8);
    const float4 w21 = *(const float4*)(attn_w2 + tj * 8 + 4);
    const float4 ab0 = *(const float4*)(attn_b1 + tj * 8);
    const float4 ab1 = *(const float4*)(attn_b1 + tj * 8 + 4);
    const float w2v[8] = {w20.x, w20.y, w20.z, w20.w, w21.x, w21.y, w21.z, w21.w};
    const float b1v[8] = {ab0.x, ab0.y, ab0.z, ab0.w, ab1.x, ab1.y, ab1.z, ab1.w};

#pragma unroll
    for (int i = 0; i < 4; i++) {
        const int le = te * 4 + i;
        const int r = rsh[le], c = csh[le];
        const float4 u0 = *(const float4*)(u + (size_t)r * HH + tj * 8);
        const float4 u1 = *(const float4*)(u + (size_t)r * HH + tj * 8 + 4);
        const float4 v0 = *(const float4*)(v + (size_t)c * HH + tj * 8);
        const float4 v1 = *(const float4*)(v + (size_t)c * HH + tj * 8 + 4);
        const float uv[8] = {u0.x + v0.x, u0.y + v0.y, u0.z + v0.z, u0.w + v0.w,
                             u1.x + v1.x, u1.y + v1.y, u1.z + v1.z, u1.w + v1.w};
        float pe = 0.0f;
#pragma unroll
        for (int jj = 0; jj < 8; jj++) {
            float z = acc[i][jj] + uv[jj] + b1v[jj];
            z = fmaxf(z, 0.0f);
            pe += z * w2v[jj];
        }
        parts[le][tj] = pe;
    }
    __syncthreads();
    if (tid < 64) {
        float s = attn_b2[0];
#pragma unroll
        for (int t = 0; t < 16; t++) s += parts[tid][t];
        score[e0 + tid] = s;
        const int mode = *flagp;
        if (get_mask(maskp, mode, e0 + tid))
            atomicMax(&menc[rsh[tid]], fenc(s));
    }
}

// ---------------------------------------------------------------------------
__global__ void k_expsum(const float* __restrict__ score, const int* __restrict__ ei,
                         const void* __restrict__ maskp, const int* __restrict__ flagp,
                         const unsigned* __restrict__ menc, float* __restrict__ ssum)
{
    const int e = blockIdx.x * 256 + threadIdx.x;
    if (e >= EE) return;
    const int mode = *flagp;
    if (get_mask(maskp, mode, e)) {
        const int r = ei[e];
        const float m = fdec(menc[r]);
        atomicAdd(&ssum[r], expf(score[e] - m));
    }
}

// ---------------------------------------------------------------------------
// Per-edge filter MLP (two GEMM tiles) + message scatter into agg.
__global__ __launch_bounds__(256) void k_filter(
    const int* __restrict__ ei, const void* __restrict__ maskp, const int* __restrict__ flagp,
    const float* __restrict__ dbuf, const float* __restrict__ score,
    const unsigned* __restrict__ menc, const float* __restrict__ ssum,
    const float* __restrict__ filt_w1, const float* __restrict__ filt_b1,
    const float* __restrict__ filt_w2, const float* __restrict__ filt_b2,
    const float* __restrict__ xh, float* __restrict__ agg)
{
    __shared__ alignas(16) float eaT[GG][64];
    __shared__ alignas(16) float T2T[HH][68];
    __shared__ float dsh[64], decsh[64], Csh[64];
    __shared__ int rsh[64], csh[64];
    const int tid = threadIdx.x;
    const int e0 = blockIdx.x * 64;

    if (tid < 64) {
        const int e = e0 + tid;
        const int r = ei[e], c = ei[EE + e];
        rsh[tid] = r; csh[tid] = c;
        const float d = dbuf[e];
        dsh[tid] = d;
        Csh[tid] = 0.5f * (cosf(d * PI_OVER_CUT) + 1.0f);
        const int mode = *flagp;
        float dec = 1.0f;
        if (get_mask(maskp, mode, e)) {
            const float m = fdec(menc[r]);
            dec = expf(score[e] - m) / (ssum[r] + 1e-16f);
        }
        decsh[tid] = dec;
    }
    __syncthreads();
    {
        const int e = tid & 63, g0 = tid >> 6;
        const float d = dsh[e];
        const float dec = decsh[e];
        for (int g = g0; g < GG; g += 4) {
            const float t = d - g * GSTEP;
            eaT[g][e] = expf(GCOEF * t * t) * dec;
        }
    }
    __syncthreads();

    const int te = tid & 15, tj = tid >> 4;
    float acc[4][8] = {};
    for (int g = 0; g < GG; g++) {
        const float4 a  = *(const float4*)&eaT[g][te * 4];
        const float4 b0 = *(const float4*)(filt_w1 + g * HH + tj * 8);
        const float4 b1 = *(const float4*)(filt_w1 + g * HH + tj * 8 + 4);
        const float av[4] = {a.x, a.y, a.z, a.w};
#pragma unroll
        for (int i = 0; i < 4; i++) { const float ai = av[i]; FMA8(acc[i], ai, b0, b1); }
    }
    const float4 fb0 = *(const float4*)(filt_b1 + tj * 8);
    const float4 fb1 = *(const float4*)(filt_b1 + tj * 8 + 4);
    const float fbv[8] = {fb0.x, fb0.y, fb0.z, fb0.w, fb1.x, fb1.y, fb1.z, fb1.w};
#pragma unroll
    for (int jj = 0; jj < 8; jj++) {
        const int j = tj * 8 + jj;
#pragma unroll
        for (int i = 0; i < 4; i++)
            T2T[j][te * 4 + i] = sspf(acc[i][jj] + fbv[jj]);
    }
    __syncthreads();

    float acc2[4][8] = {};
    for (int k = 0; k < HH; k++) {
        const float4 a  = *(const float4*)&T2T[k][te * 4];
        const float4 b0 = *(const float4*)(filt_w2 + (size_t)k * HH + tj * 8);
        const float4 b1 = *(const float4*)(filt_w2 + (size_t)k * HH + tj * 8 + 4);
        const float av[4] = {a.x, a.y, a.z, a.w};
#pragma unroll
        for (int i = 0; i < 4; i++) { const float ai = av[i]; FMA8(acc2[i], ai, b0, b1); }
    }
    const float4 c0 = *(const float4*)(filt_b2 + tj * 8);
    const float4 c1 = *(const float4*)(filt_b2 + tj * 8 + 4);
    const float fb2v[8] = {c0.x, c0.y, c0.z, c0.w, c1.x, c1.y, c1.z, c1.w};

#pragma unroll
    for (int i = 0; i < 4; i++) {
        const int le = te * 4 + i;
        const int r = rsh[le], c = csh[le];
        const float C = Csh[le];
        const float4 x0 = *(const float4*)(xh + (size_t)r * HH + tj * 8);
        const float4 x1 = *(const float4*)(xh + (size_t)r * HH + tj * 8 + 4);
        const float xv[8] = {x0.x, x0.y, x0.z, x0.w, x1.x, x1.y, x1.z, x1.w};
        float* aggc = agg + (size_t)c * HH + tj * 8;
#pragma unroll
        for (int jj = 0; jj < 8; jj++) {
            const float Wv = (acc2[i][jj] + fb2v[jj]) * C;
            atomicAdd(&aggc[jj], xv[jj] * Wv);
        }
    }
}

// ---------------------------------------------------------------------------
// h_update = ssp(agg @ lin2_w + lin2_b) @ lin_w + lin_b
__global__ __launch_bounds__(256) void k_final(
    const float* __restrict__ agg, const float* __restrict__ lin2_w,
    const float* __restrict__ lin2_b, const float* __restrict__ lin_w,
    const float* __restrict__ lin_b, float* __restrict__ out)
{
    __shared__ alignas(16) float AT[HH][68];
    __shared__ alignas(16) float T2T[HH][68];
    const int tid = threadIdx.x;
    const int n0 = blockIdx.x * 64;
    for (int idx = tid; idx < 64 * HH; idx += 256) {
        const int n = idx >> 7, k = idx & 127;
        AT[k][n] = agg[(size_t)(n0 + n) * HH + k];
    }
    __syncthreads();

    const int te = tid & 15, tj = tid >> 4;
    float acc[4][8] = {};
    for (int k = 0; k < HH; k++) {
        const float4 a  = *(const float4*)&AT[k][te * 4];
        const float4 b0 = *(const float4*)(lin2_w + (size_t)k * HH + tj * 8);
        const float4 b1 = *(const float4*)(lin2_w + (size_t)k * HH + tj * 8 + 4);
        const float av[4] = {a.x, a.y, a.z, a.w};
#pragma unroll
        for (int i = 0; i < 4; i++) { const float ai = av[i]; FMA8(acc[i], ai, b0, b1); }
    }
    const float4 l20 = *(const float4*)(lin2_b + tj * 8);
    const float4 l21 = *(const float4*)(lin2_b + tj * 8 + 4);
    const float l2v[8] = {l20.x, l20.y, l20.z, l20.w, l21.x, l21.y, l21.z, l21.w};
#pragma unroll
    for (int jj = 0; jj < 8; jj++) {
        const int j = tj * 8 + jj;
#pragma unroll
        for (int i = 0; i < 4; i++)
            T2T[j][te * 4 + i] = sspf(acc[i][jj] + l2v[jj]);
    }
    __syncthreads();

    float acc2[4][8] = {};
    for (int k = 0; k < HH; k++) {
        const float4 a  = *(const float4*)&T2T[k][te * 4];
        const float4 b0 = *(const float4*)(lin_w + (size_t)k * HH + tj * 8);
        const float4 b1 = *(const float4*)(lin_w + (size_t)k * HH + tj * 8 + 4);
        const float av[4] = {a.x, a.y, a.z, a.w};
#pragma unroll
        for (int i = 0; i < 4; i++) { const float ai = av[i]; FMA8(acc2[i], ai, b0, b1); }
    }
    const float4 lb0 = *(const float4*)(lin_b + tj * 8);
    const float4 lb1 = *(const float4*)(lin_b + tj * 8 + 4);
    const float lbv[8] = {lb0.x, lb0.y, lb0.z, lb0.w, lb1.x, lb1.y, lb1.z, lb1.w};
#pragma unroll
    for (int i = 0; i < 4; i++) {
        float* o = out + (size_t)(n0 + te * 4 + i) * HH + tj * 8;
        float4 r0 = {acc2[i][0] + lbv[0], acc2[i][1] + lbv[1], acc2[i][2] + lbv[2], acc2[i][3] + lbv[3]};
        float4 r1 = {acc2[i][4] + lbv[4], acc2[i][5] + lbv[5], acc2[i][6] + lbv[6], acc2[i][7] + lbv[7]};
        *(float4*)o = r0;
        *(float4*)(o + 4) = r1;
    }
}

// ---------------------------------------------------------------------------
__global__ void k_copy_pos(const float* __restrict__ pos, float* __restrict__ out) {
    const int i = blockIdx.x * 256 + threadIdx.x;
    if (i < NN * 3) out[i] = pos[i];
}

// ---------------------------------------------------------------------------
extern "C" void kernel_launch(void* const* d_in, const int* in_sizes, int n_in,
                              void* d_out, int out_size, void* d_ws, size_t ws_size,
                              hipStream_t stream)
{
    const float* h       = (const float*)d_in[0];
    const float* pos     = (const float*)d_in[1];
    const int*   ei      = (const int*)d_in[2];
    const void*  maskp   = d_in[3];
    const float* attn_w1 = (const float*)d_in[4];
    const float* attn_b1 = (const float*)d_in[5];
    const float* attn_w2 = (const float*)d_in[6];
    const float* attn_b2 = (const float*)d_in[7];
    const float* filt_w1 = (const float*)d_in[8];
    const float* filt_b1 = (const float*)d_in[9];
    const float* filt_w2 = (const float*)d_in[10];
    const float* filt_b2 = (const float*)d_in[11];
    const float* lin1_w  = (const float*)d_in[12];
    const float* lin2_w  = (const float*)d_in[13];
    const float* lin2_b  = (const float*)d_in[14];
    const float* lin_w   = (const float*)d_in[15];
    const float* lin_b   = (const float*)d_in[16];

    float* ws   = (float*)d_ws;
    float* u    = ws;
    float* v    = u + (size_t)NN * HH;
    float* xh   = v + (size_t)NN * HH;
    float* dbuf = xh + (size_t)NN * HH;
    float* score = dbuf + EE;
    unsigned* menc = (unsigned*)(score + EE);
    float* ssum = (float*)(menc + NN);
    float* agg  = ssum + NN;
    int* flag   = (int*)(agg + (size_t)NN * HH);

    float* out_h   = (float*)d_out;
    float* out_pos = out_h + (size_t)NN * HH;

    hipMemsetAsync(menc, 0, NN * sizeof(unsigned), stream);
    hipMemsetAsync(ssum, 0, NN * sizeof(float), stream);
    hipMemsetAsync(agg, 0, (size_t)NN * HH * sizeof(float), stream);

    k_detect<<<1, 256, 0, stream>>>((const unsigned char*)maskp, flag);
    k_node_proj<<<dim3(NN / 64, 3), 256, 0, stream>>>(h, attn_w1, lin1_w, u, v, xh);
    k_edge_score<<<EE / 64, 256, 0, stream>>>(pos, ei, maskp, flag, u, v,
                                              attn_w1, attn_b1, attn_w2, attn_b2,
                                              dbuf, score, menc);
    k_expsum<<<EE / 256, 256, 0, stream>>>(score, ei, maskp, flag, menc, ssum);
    k_filter<<<EE / 64, 256, 0, stream>>>(ei, maskp, flag, dbuf, score, menc, ssum,
                                          filt_w1, filt_b1, filt_w2, filt_b2, xh, agg);
    k_final<<<NN / 64, 256, 0, stream>>>(agg, lin2_w, lin2_b, lin_w, lin_b, out_h);
    k_copy_pos<<<(NN * 3 + 255) / 256, 256, 0, stream>>>(pos, out_pos);
}

// Round 2
// 2205.280 us; speedup vs baseline: 1.0011x; 1.0011x over previous
//
#include <hip/hip_runtime.h>

#define NN 32768
#define HH 128
#define GG 50
#define EE 524288

constexpr float GSTEP = 10.0f / 49.0f;
constexpr float GCOEF = -0.5f / (GSTEP * GSTEP);
constexpr float PI_OVER_CUT = 0.31415926535897931f;   // pi / 10
constexpr float LOG2F_ = 0.69314718055994531f;

__device__ __forceinline__ float sspf(float x) {
    return fmaxf(x, 0.0f) + log1pf(expf(-fabsf(x))) - LOG2F_;
}
__device__ __forceinline__ unsigned fenc(float f) {
    unsigned b = __float_as_uint(f);
    return (b & 0x80000000u) ? ~b : (b | 0x80000000u);
}
__device__ __forceinline__ float fdec(unsigned u) {
    unsigned b = (u & 0x80000000u) ? (u ^ 0x80000000u) : ~u;
    return __uint_as_float(b);
}
__device__ __forceinline__ int get_mask(const void* mp, int mode, int e) {
    if (mode) return ((const unsigned char*)mp)[e] != 0;
    return ((const int*)mp)[e] != 0;
}

#define FMA8(ACCROW, AV, B0, B1)                                   \
    ACCROW[0] += (AV) * B0.x; ACCROW[1] += (AV) * B0.y;            \
    ACCROW[2] += (AV) * B0.z; ACCROW[3] += (AV) * B0.w;            \
    ACCROW[4] += (AV) * B1.x; ACCROW[5] += (AV) * B1.y;            \
    ACCROW[6] += (AV) * B1.z; ACCROW[7] += (AV) * B1.w;

// ---------------------------------------------------------------------------
__global__ void k_detect(const unsigned char* __restrict__ mb, int* __restrict__ flag) {
    __shared__ int any;
    if (threadIdx.x == 0) any = 0;
    __syncthreads();
    int local = 0;
    for (int i = threadIdx.x; i < 16384; i += blockDim.x)
        if ((i & 3) != 0 && mb[i]) local = 1;
    if (local) atomicOr(&any, 1);
    __syncthreads();
    if (threadIdx.x == 0) *flag = any;   // 1 => byte mode, 0 => int32 mode
}

// ---------------------------------------------------------------------------
__global__ __launch_bounds__(256) void k_node_proj(
    const float* __restrict__ h, const float* __restrict__ attn_w1,
    const float* __restrict__ lin1_w,
    float* __restrict__ u, float* __restrict__ v, float* __restrict__ xh)
{
    __shared__ alignas(16) float hT[HH][68];
    const int tid = threadIdx.x;
    const int n0 = blockIdx.x * 64;
    const int mat = blockIdx.y;
    const float* __restrict__ W = (mat == 0) ? attn_w1 : (mat == 1 ? attn_w1 + HH * HH : lin1_w);
    float* __restrict__ out = (mat == 0) ? u : (mat == 1 ? v : xh);

    for (int idx = tid; idx < 64 * HH; idx += 256) {
        const int n = idx >> 7, k = idx & 127;
        hT[k][n] = h[(size_t)(n0 + n) * HH + k];
    }
    __syncthreads();

    const int te = tid & 15, tj = tid >> 4;
    float acc[4][8] = {};
    for (int k = 0; k < HH; k++) {
        const float4 a  = *(const float4*)&hT[k][te * 4];
        const float4 b0 = *(const float4*)(W + (size_t)k * HH + tj * 8);
        const float4 b1 = *(const float4*)(W + (size_t)k * HH + tj * 8 + 4);
        const float av[4] = {a.x, a.y, a.z, a.w};
#pragma unroll
        for (int i = 0; i < 4; i++) { const float ai = av[i]; FMA8(acc[i], ai, b0, b1); }
    }
#pragma unroll
    for (int i = 0; i < 4; i++) {
        float* o = out + (size_t)(n0 + te * 4 + i) * HH + tj * 8;
        float4 r0 = {acc[i][0], acc[i][1], acc[i][2], acc[i][3]};
        float4 r1 = {acc[i][4], acc[i][5], acc[i][6], acc[i][7]};
        *(float4*)o = r0;
        *(float4*)(o + 4) = r1;
    }
}

// ---------------------------------------------------------------------------
__global__ __launch_bounds__(256) void k_edge_score(
    const float* __restrict__ pos, const int* __restrict__ ei,
    const void* __restrict__ maskp, const int* __restrict__ flagp,
    const float* __restrict__ u, const float* __restrict__ v,
    const float* __restrict__ attn_w1, const float* __restrict__ attn_b1,
    const float* __restrict__ attn_w2, const float* __restrict__ attn_b2,
    float* __restrict__ dbuf, float* __restrict__ score, unsigned* __restrict__ menc)
{
    __shared__ alignas(16) float eaT[GG][64];
    __shared__ float dsh[64];
    __shared__ int rsh[64], csh[64];
    __shared__ float parts[64][17];
    const int tid = threadIdx.x;
    const int e0 = blockIdx.x * 64;

    if (tid < 64) {
        const int e = e0 + tid;
        const int r = ei[e], c = ei[EE + e];
        rsh[tid] = r; csh[tid] = c;
        const float dx = pos[r * 3 + 0] - pos[c * 3 + 0];
        const float dy = pos[r * 3 + 1] - pos[c * 3 + 1];
        const float dz = pos[r * 3 + 2] - pos[c * 3 + 2];
        const float d = sqrtf(dx * dx + dy * dy + dz * dz);
        dsh[tid] = d;
        dbuf[e] = d;
    }
    __syncthreads();
    {
        const int e = tid & 63, g0 = tid >> 6;
        const float d = dsh[e];
        for (int g = g0; g < GG; g += 4) {
            const float t = d - g * GSTEP;
            eaT[g][e] = expf(GCOEF * t * t);
        }
    }
    __syncthreads();

    const int te = tid & 15, tj = tid >> 4;
    const float* __restrict__ W1C = attn_w1 + 256 * HH;
    float acc[4][8] = {};
    for (int g = 0; g < GG; g++) {
        const float4 a  = *(const float4*)&eaT[g][te * 4];
        const float4 b0 = *(const float4*)(W1C + g * HH + tj * 8);
        const float4 b1 = *(const float4*)(W1C + g * HH + tj * 8 + 4);
        const float av[4] = {a.x, a.y, a.z, a.w};
#pragma unroll
        for (int i = 0; i < 4; i++) { const float ai = av[i]; FMA8(acc[i], ai, b0, b1); }
    }

    const float4 w20 = *(const float4*)(attn_w2 + tj * 8);
    const float4 w21 = *(const float4*)(attn_w2 + tj * 8 + 4);
    const float4 ab0 = *(const float4*)(attn_b1 + tj * 8);
    const float4 ab1 = *(const float4*)(attn_b1 + tj * 8 + 4);
    const float w2v[8] = {w20.x, w20.y, w20.z, w20.w, w21.x, w21.y, w21.z, w21.w};
    const float b1v[8] = {ab0.x, ab0.y, ab0.z, ab0.w, ab1.x, ab1.y, ab1.z, ab1.w};

#pragma unroll
    for (int i = 0; i < 4; i++) {
        const int le = te * 4 + i;
        const int r = rsh[le], c = csh[le];
        const float4 u0 = *(const float4*)(u + (size_t)r * HH + tj * 8);
        const float4 u1 = *(const float4*)(u + (size_t)r * HH + tj * 8 + 4);
        const float4 v0 = *(const float4*)(v + (size_t)c * HH + tj * 8);
        const float4 v1 = *(const float4*)(v + (size_t)c * HH + tj * 8 + 4);
        const float uv[8] = {u0.x + v0.x, u0.y + v0.y, u0.z + v0.z, u0.w + v0.w,
                             u1.x + v1.x, u1.y + v1.y, u1.z + v1.z, u1.w + v1.w};
        float pe = 0.0f;
#pragma unroll
        for (int jj = 0; jj < 8; jj++) {
            float z = acc[i][jj] + uv[jj] + b1v[jj];
            z = fmaxf(z, 0.0f);
            pe += z * w2v[jj];
        }
        parts[le][tj] = pe;
    }
    __syncthreads();
    if (tid < 64) {
        float s = attn_b2[0];
#pragma unroll
        for (int t = 0; t < 16; t++) s += parts[tid][t];
        score[e0 + tid] = s;
        const int mode = *flagp;
        if (get_mask(maskp, mode, e0 + tid))
            atomicMax(&menc[rsh[tid]], fenc(s));
    }
}

// ---------------------------------------------------------------------------
__global__ void k_expsum(const float* __restrict__ score, const int* __restrict__ ei,
                         const void* __restrict__ maskp, const int* __restrict__ flagp,
                         const unsigned* __restrict__ menc, float* __restrict__ ssum)
{
    const int e = blockIdx.x * 256 + threadIdx.x;
    if (e >= EE) return;
    const int mode = *flagp;
    if (get_mask(maskp, mode, e)) {
        const int r = ei[e];
        const float m = fdec(menc[r]);
        atomicAdd(&ssum[r], expf(score[e] - m));
    }
}

// ---------------------------------------------------------------------------
// Counting sort of edges by destination (col).
__global__ void k_hist(const int* __restrict__ ei, int* __restrict__ count) {
    const int e = blockIdx.x * 256 + threadIdx.x;
    if (e < EE) atomicAdd(&count[ei[EE + e]], 1);
}

__global__ __launch_bounds__(512) void k_scan(const int* __restrict__ count,
                                              int* __restrict__ offsets,
                                              int* __restrict__ cursor)
{
    __shared__ int s[512];
    const int t = threadIdx.x;
    const int base_i = t * 64;
    int sum = 0;
    for (int i = 0; i < 64; i++) sum += count[base_i + i];
    s[t] = sum;
    __syncthreads();
    for (int off = 1; off < 512; off <<= 1) {
        int v = (t >= off) ? s[t - off] : 0;
        __syncthreads();
        s[t] += v;
        __syncthreads();
    }
    int run = s[t] - sum;   // exclusive prefix
    for (int i = 0; i < 64; i++) {
        offsets[base_i + i] = run;
        cursor[base_i + i] = run;
        run += count[base_i + i];
    }
    if (t == 511) offsets[NN] = run;   // == EE
}

__global__ void k_scatter(const int* __restrict__ ei, int* __restrict__ cursor,
                          int* __restrict__ perm)
{
    const int e = blockIdx.x * 256 + threadIdx.x;
    if (e >= EE) return;
    const int c = ei[EE + e];
    const int pos = atomicAdd(&cursor[c], 1);
    perm[pos] = e;
}

// ---------------------------------------------------------------------------
// Per-edge filter MLP on PERMUTED edges; stream msg to workspace (no atomics).
__global__ __launch_bounds__(256) void k_filter_perm(
    const int* __restrict__ ei, const void* __restrict__ maskp, const int* __restrict__ flagp,
    const float* __restrict__ dbuf, const float* __restrict__ score,
    const unsigned* __restrict__ menc, const float* __restrict__ ssum,
    const int* __restrict__ perm,
    const float* __restrict__ filt_w1, const float* __restrict__ filt_b1,
    const float* __restrict__ filt_w2, const float* __restrict__ filt_b2,
    const float* __restrict__ xh, float* __restrict__ msg)
{
    __shared__ alignas(16) float eaT[GG][64];
    __shared__ alignas(16) float T2T[HH][68];
    __shared__ float dsh[64], decsh[64], Csh[64];
    __shared__ int rsh[64];
    const int tid = threadIdx.x;
    const int e0 = blockIdx.x * 64;

    if (tid < 64) {
        const int pe = perm[e0 + tid];
        const int r = ei[pe];
        rsh[tid] = r;
        const float d = dbuf[pe];
        dsh[tid] = d;
        Csh[tid] = 0.5f * (cosf(d * PI_OVER_CUT) + 1.0f);
        const int mode = *flagp;
        float dec = 1.0f;
        if (get_mask(maskp, mode, pe)) {
            const float m = fdec(menc[r]);
            dec = expf(score[pe] - m) / (ssum[r] + 1e-16f);
        }
        decsh[tid] = dec;
    }
    __syncthreads();
    {
        const int e = tid & 63, g0 = tid >> 6;
        const float d = dsh[e];
        const float dec = decsh[e];
        for (int g = g0; g < GG; g += 4) {
            const float t = d - g * GSTEP;
            eaT[g][e] = expf(GCOEF * t * t) * dec;
        }
    }
    __syncthreads();

    const int te = tid & 15, tj = tid >> 4;
    float acc[4][8] = {};
    for (int g = 0; g < GG; g++) {
        const float4 a  = *(const float4*)&eaT[g][te * 4];
        const float4 b0 = *(const float4*)(filt_w1 + g * HH + tj * 8);
        const float4 b1 = *(const float4*)(filt_w1 + g * HH + tj * 8 + 4);
        const float av[4] = {a.x, a.y, a.z, a.w};
#pragma unroll
        for (int i = 0; i < 4; i++) { const float ai = av[i]; FMA8(acc[i], ai, b0, b1); }
    }
    const float4 fb0 = *(const float4*)(filt_b1 + tj * 8);
    const float4 fb1 = *(const float4*)(filt_b1 + tj * 8 + 4);
    const float fbv[8] = {fb0.x, fb0.y, fb0.z, fb0.w, fb1.x, fb1.y, fb1.z, fb1.w};
#pragma unroll
    for (int jj = 0; jj < 8; jj++) {
        const int j = tj * 8 + jj;
#pragma unroll
        for (int i = 0; i < 4; i++)
            T2T[j][te * 4 + i] = sspf(acc[i][jj] + fbv[jj]);
    }
    __syncthreads();

    float acc2[4][8] = {};
    for (int k = 0; k < HH; k++) {
        const float4 a  = *(const float4*)&T2T[k][te * 4];
        const float4 b0 = *(const float4*)(filt_w2 + (size_t)k * HH + tj * 8);
        const float4 b1 = *(const float4*)(filt_w2 + (size_t)k * HH + tj * 8 + 4);
        const float av[4] = {a.x, a.y, a.z, a.w};
#pragma unroll
        for (int i = 0; i < 4; i++) { const float ai = av[i]; FMA8(acc2[i], ai, b0, b1); }
    }
    const float4 c0 = *(const float4*)(filt_b2 + tj * 8);
    const float4 c1 = *(const float4*)(filt_b2 + tj * 8 + 4);
    const float fb2v[8] = {c0.x, c0.y, c0.z, c0.w, c1.x, c1.y, c1.z, c1.w};

#pragma unroll
    for (int i = 0; i < 4; i++) {
        const int le = te * 4 + i;
        const int r = rsh[le];
        const float C = Csh[le];
        const float4 x0 = *(const float4*)(xh + (size_t)r * HH + tj * 8);
        const float4 x1 = *(const float4*)(xh + (size_t)r * HH + tj * 8 + 4);
        float* mo = msg + (size_t)(e0 + le) * HH + tj * 8;
        float4 m0 = {x0.x * (acc2[i][0] + fb2v[0]) * C, x0.y * (acc2[i][1] + fb2v[1]) * C,
                     x0.z * (acc2[i][2] + fb2v[2]) * C, x0.w * (acc2[i][3] + fb2v[3]) * C};
        float4 m1 = {x1.x * (acc2[i][4] + fb2v[4]) * C, x1.y * (acc2[i][5] + fb2v[5]) * C,
                     x1.z * (acc2[i][6] + fb2v[6]) * C, x1.w * (acc2[i][7] + fb2v[7]) * C};
        *(float4*)mo = m0;
        *(float4*)(mo + 4) = m1;
    }
}

// ---------------------------------------------------------------------------
// One wave per node: reduce its contiguous msg slot range. No atomics.
__global__ __launch_bounds__(256) void k_agg(
    const float* __restrict__ msg, const int* __restrict__ offsets,
    float* __restrict__ agg)
{
    const int tid = threadIdx.x;
    const int node = blockIdx.x * 4 + (tid >> 6);
    const int lane = tid & 63;
    if (node >= NN) return;
    const int b = offsets[node], e = offsets[node + 1];
    float a0 = 0.0f, a1 = 0.0f;
    for (int i = b; i < e; i++) {
        const float2 m = *(const float2*)&msg[(size_t)i * HH + lane * 2];
        a0 += m.x; a1 += m.y;
    }
    float2 r = {a0, a1};
    *(float2*)&agg[(size_t)node * HH + lane * 2] = r;
}

// ---------------------------------------------------------------------------
// FALLBACK (ws too small): original atomic-scatter filter.
__global__ __launch_bounds__(256) void k_filter(
    const int* __restrict__ ei, const void* __restrict__ maskp, const int* __restrict__ flagp,
    const float* __restrict__ dbuf, const float* __restrict__ score,
    const unsigned* __restrict__ menc, const float* __restrict__ ssum,
    const float* __restrict__ filt_w1, const float* __restrict__ filt_b1,
    const float* __restrict__ filt_w2, const float* __restrict__ filt_b2,
    const float* __restrict__ xh, float* __restrict__ agg)
{
    __shared__ alignas(16) float eaT[GG][64];
    __shared__ alignas(16) float T2T[HH][68];
    __shared__ float dsh[64], decsh[64], Csh[64];
    __shared__ int rsh[64], csh[64];
    const int tid = threadIdx.x;
    const int e0 = blockIdx.x * 64;

    if (tid < 64) {
        const int e = e0 + tid;
        const int r = ei[e], c = ei[EE + e];
        rsh[tid] = r; csh[tid] = c;
        const float d = dbuf[e];
        dsh[tid] = d;
        Csh[tid] = 0.5f * (cosf(d * PI_OVER_CUT) + 1.0f);
        const int mode = *flagp;
        float dec = 1.0f;
        if (get_mask(maskp, mode, e)) {
            const float m = fdec(menc[r]);
            dec = expf(score[e] - m) / (ssum[r] + 1e-16f);
        }
        decsh[tid] = dec;
    }
    __syncthreads();
    {
        const int e = tid & 63, g0 = tid >> 6;
        const float d = dsh[e];
        const float dec = decsh[e];
        for (int g = g0; g < GG; g += 4) {
            const float t = d - g * GSTEP;
            eaT[g][e] = expf(GCOEF * t * t) * dec;
        }
    }
    __syncthreads();

    const int te = tid & 15, tj = tid >> 4;
    float acc[4][8] = {};
    for (int g = 0; g < GG; g++) {
        const float4 a  = *(const float4*)&eaT[g][te * 4];
        const float4 b0 = *(const float4*)(filt_w1 + g * HH + tj * 8);
        const float4 b1 = *(const float4*)(filt_w1 + g * HH + tj * 8 + 4);
        const float av[4] = {a.x, a.y, a.z, a.w};
#pragma unroll
        for (int i = 0; i < 4; i++) { const float ai = av[i]; FMA8(acc[i], ai, b0, b1); }
    }
    const float4 fb0 = *(const float4*)(filt_b1 + tj * 8);
    const float4 fb1 = *(const float4*)(filt_b1 + tj * 8 + 4);
    const float fbv[8] = {fb0.x, fb0.y, fb0.z, fb0.w, fb1.x, fb1.y, fb1.z, fb1.w};
#pragma unroll
    for (int jj = 0; jj < 8; jj++) {
        const int j = tj * 8 + jj;
#pragma unroll
        for (int i = 0; i < 4; i++)
            T2T[j][te * 4 + i] = sspf(acc[i][jj] + fbv[jj]);
    }
    __syncthreads();

    float acc2[4][8] = {};
    for (int k = 0; k < HH; k++) {
        const float4 a  = *(const float4*)&T2T[k][te * 4];
        const float4 b0 = *(const float4*)(filt_w2 + (size_t)k * HH + tj * 8);
        const float4 b1 = *(const float4*)(filt_w2 + (size_t)k * HH + tj * 8 + 4);
        const float av[4] = {a.x, a.y, a.z, a.w};
#pragma unroll
        for (int i = 0; i < 4; i++) { const float ai = av[i]; FMA8(acc2[i], ai, b0, b1); }
    }
    const float4 c0 = *(const float4*)(filt_b2 + tj * 8);
    const float4 c1 = *(const float4*)(filt_b2 + tj * 8 + 4);
    const float fb2v[8] = {c0.x, c0.y, c0.z, c0.w, c1.x, c1.y, c1.z, c1.w};

#pragma unroll
    for (int i = 0; i < 4; i++) {
        const int le = te * 4 + i;
        const int r = rsh[le], c = csh[le];
        const float C = Csh[le];
        const float4 x0 = *(const float4*)(xh + (size_t)r * HH + tj * 8);
        const float4 x1 = *(const float4*)(xh + (size_t)r * HH + tj * 8 + 4);
        const float xv[8] = {x0.x, x0.y, x0.z, x0.w, x1.x, x1.y, x1.z, x1.w};
        float* aggc = agg + (size_t)c * HH + tj * 8;
#pragma unroll
        for (int jj = 0; jj < 8; jj++) {
            const float Wv = (acc2[i][jj] + fb2v[jj]) * C;
            atomicAdd(&aggc[jj], xv[jj] * Wv);
        }
    }
}

// ---------------------------------------------------------------------------
__global__ __launch_bounds__(256) void k_final(
    const float* __restrict__ agg, const float* __restrict__ lin2_w,
    const float* __restrict__ lin2_b, const float* __restrict__ lin_w,
    const float* __restrict__ lin_b, float* __restrict__ out)
{
    __shared__ alignas(16) float AT[HH][68];
    __shared__ alignas(16) float T2T[HH][68];
    const int tid = threadIdx.x;
    const int n0 = blockIdx.x * 64;
    for (int idx = tid; idx < 64 * HH; idx += 256) {
        const int n = idx >> 7, k = idx & 127;
        AT[k][n] = agg[(size_t)(n0 + n) * HH + k];
    }
    __syncthreads();

    const int te = tid & 15, tj = tid >> 4;
    float acc[4][8] = {};
    for (int k = 0; k < HH; k++) {
        const float4 a  = *(const float4*)&AT[k][te * 4];
        const float4 b0 = *(const float4*)(lin2_w + (size_t)k * HH + tj * 8);
        const float4 b1 = *(const float4*)(lin2_w + (size_t)k * HH + tj * 8 + 4);
        const float av[4] = {a.x, a.y, a.z, a.w};
#pragma unroll
        for (int i = 0; i < 4; i++) { const float ai = av[i]; FMA8(acc[i], ai, b0, b1); }
    }
    const float4 l20 = *(const float4*)(lin2_b + tj * 8);
    const float4 l21 = *(const float4*)(lin2_b + tj * 8 + 4);
    const float l2v[8] = {l20.x, l20.y, l20.z, l20.w, l21.x, l21.y, l21.z, l21.w};
#pragma unroll
    for (int jj = 0; jj < 8; jj++) {
        const int j = tj * 8 + jj;
#pragma unroll
        for (int i = 0; i < 4; i++)
            T2T[j][te * 4 + i] = sspf(acc[i][jj] + l2v[jj]);
    }
    __syncthreads();

    float acc2[4][8] = {};
    for (int k = 0; k < HH; k++) {
        const float4 a  = *(const float4*)&T2T[k][te * 4];
        const float4 b0 = *(const float4*)(lin_w + (size_t)k * HH + tj * 8);
        const float4 b1 = *(const float4*)(lin_w + (size_t)k * HH + tj * 8 + 4);
        const float av[4] = {a.x, a.y, a.z, a.w};
#pragma unroll
        for (int i = 0; i < 4; i++) { const float ai = av[i]; FMA8(acc2[i], ai, b0, b1); }
    }
    const float4 lb0 = *(const float4*)(lin_b + tj * 8);
    const float4 lb1 = *(const float4*)(lin_b + tj * 8 + 4);
    const float lbv[8] = {lb0.x, lb0.y, lb0.z, lb0.w, lb1.x, lb1.y, lb1.z, lb1.w};
#pragma unroll
    for (int i = 0; i < 4; i++) {
        float* o = out + (size_t)(n0 + te * 4 + i) * HH + tj * 8;
        float4 r0 = {acc2[i][0] + lbv[0], acc2[i][1] + lbv[1], acc2[i][2] + lbv[2], acc2[i][3] + lbv[3]};
        float4 r1 = {acc2[i][4] + lbv[4], acc2[i][5] + lbv[5], acc2[i][6] + lbv[6], acc2[i][7] + lbv[7]};
        *(float4*)o = r0;
        *(float4*)(o + 4) = r1;
    }
}

// ---------------------------------------------------------------------------
__global__ void k_copy_pos(const float* __restrict__ pos, float* __restrict__ out) {
    const int i = blockIdx.x * 256 + threadIdx.x;
    if (i < NN * 3) out[i] = pos[i];
}

// ---------------------------------------------------------------------------
extern "C" void kernel_launch(void* const* d_in, const int* in_sizes, int n_in,
                              void* d_out, int out_size, void* d_ws, size_t ws_size,
                              hipStream_t stream)
{
    const float* h       = (const float*)d_in[0];
    const float* pos     = (const float*)d_in[1];
    const int*   ei      = (const int*)d_in[2];
    const void*  maskp   = d_in[3];
    const float* attn_w1 = (const float*)d_in[4];
    const float* attn_b1 = (const float*)d_in[5];
    const float* attn_w2 = (const float*)d_in[6];
    const float* attn_b2 = (const float*)d_in[7];
    const float* filt_w1 = (const float*)d_in[8];
    const float* filt_b1 = (const float*)d_in[9];
    const float* filt_w2 = (const float*)d_in[10];
    const float* filt_b2 = (const float*)d_in[11];
    const float* lin1_w  = (const float*)d_in[12];
    const float* lin2_w  = (const float*)d_in[13];
    const float* lin2_b  = (const float*)d_in[14];
    const float* lin_w   = (const float*)d_in[15];
    const float* lin_b   = (const float*)d_in[16];

    char* p = (char*)d_ws;
    auto alloc = [&](size_t bytes) { char* r = p; p += (bytes + 255) & ~(size_t)255; return r; };

    float*    u       = (float*)alloc((size_t)NN * HH * 4);
    float*    v       = (float*)alloc((size_t)NN * HH * 4);
    float*    xh      = (float*)alloc((size_t)NN * HH * 4);
    float*    dbuf    = (float*)alloc((size_t)EE * 4);
    float*    score   = (float*)alloc((size_t)EE * 4);
    unsigned* menc    = (unsigned*)alloc((size_t)NN * 4);
    float*    ssum    = (float*)alloc((size_t)NN * 4);
    float*    agg     = (float*)alloc((size_t)NN * HH * 4);
    int*      flag    = (int*)alloc(4);
    int*      count   = (int*)alloc((size_t)NN * 4);
    int*      offsets = (int*)alloc((size_t)(NN + 1) * 4);
    int*      cursor  = (int*)alloc((size_t)NN * 4);
    int*      perm    = (int*)alloc((size_t)EE * 4);
    size_t    base_bytes = (size_t)(p - (char*)d_ws);
    float*    msg     = (float*)alloc((size_t)EE * HH * 4);
    size_t    full_bytes = (size_t)(p - (char*)d_ws);
    const bool big_ws = ws_size >= full_bytes;
    (void)base_bytes;

    float* out_h   = (float*)d_out;
    float* out_pos = out_h + (size_t)NN * HH;

    hipMemsetAsync(menc, 0, NN * sizeof(unsigned), stream);
    hipMemsetAsync(ssum, 0, NN * sizeof(float), stream);

    k_detect<<<1, 256, 0, stream>>>((const unsigned char*)maskp, flag);
    k_node_proj<<<dim3(NN / 64, 3), 256, 0, stream>>>(h, attn_w1, lin1_w, u, v, xh);
    k_edge_score<<<EE / 64, 256, 0, stream>>>(pos, ei, maskp, flag, u, v,
                                              attn_w1, attn_b1, attn_w2, attn_b2,
                                              dbuf, score, menc);
    k_expsum<<<EE / 256, 256, 0, stream>>>(score, ei, maskp, flag, menc, ssum);

    if (big_ws) {
        hipMemsetAsync(count, 0, NN * sizeof(int), stream);
        k_hist<<<EE / 256, 256, 0, stream>>>(ei, count);
        k_scan<<<1, 512, 0, stream>>>(count, offsets, cursor);
        k_scatter<<<EE / 256, 256, 0, stream>>>(ei, cursor, perm);
        k_filter_perm<<<EE / 64, 256, 0, stream>>>(ei, maskp, flag, dbuf, score, menc, ssum,
                                                   perm, filt_w1, filt_b1, filt_w2, filt_b2,
                                                   xh, msg);
        k_agg<<<NN / 4, 256, 0, stream>>>(msg, offsets, agg);
    } else {
        hipMemsetAsync(agg, 0, (size_t)NN * HH * sizeof(float), stream);
        k_filter<<<EE / 64, 256, 0, stream>>>(ei, maskp, flag, dbuf, score, menc, ssum,
                                              filt_w1, filt_b1, filt_w2, filt_b2, xh, agg);
    }

    k_final<<<NN / 64, 256, 0, stream>>>(agg, lin2_w, lin2_b, lin_w, lin_b, out_h);
    k_copy_pos<<<(NN * 3 + 255) / 256, 256, 0, stream>>>(pos, out_pos);
}

// Round 3
// 886.236 us; speedup vs baseline: 2.4911x; 2.4884x over previous
//
#include <hip/hip_runtime.h>

#define NN 32768
#define HH 128
#define GG 50
#define EE 524288

constexpr float GSTEP = 10.0f / 49.0f;
constexpr float GCOEF = -0.5f / (GSTEP * GSTEP);
constexpr float PI_OVER_CUT = 0.31415926535897931f;   // pi / 10
constexpr float LOG2F_ = 0.69314718055994531f;

__device__ __forceinline__ float sspf(float x) {
    return fmaxf(x, 0.0f) + log1pf(expf(-fabsf(x))) - LOG2F_;
}
__device__ __forceinline__ unsigned fenc(float f) {
    unsigned b = __float_as_uint(f);
    return (b & 0x80000000u) ? ~b : (b | 0x80000000u);
}
__device__ __forceinline__ float fdec(unsigned u) {
    unsigned b = (u & 0x80000000u) ? (u ^ 0x80000000u) : ~u;
    return __uint_as_float(b);
}
__device__ __forceinline__ int get_mask(const void* mp, int mode, int e) {
    if (mode) return ((const unsigned char*)mp)[e] != 0;
    return ((const int*)mp)[e] != 0;
}

#define FMA8(ACCROW, AV, B0, B1)                                   \
    ACCROW[0] += (AV) * B0.x; ACCROW[1] += (AV) * B0.y;            \
    ACCROW[2] += (AV) * B0.z; ACCROW[3] += (AV) * B0.w;            \
    ACCROW[4] += (AV) * B1.x; ACCROW[5] += (AV) * B1.y;            \
    ACCROW[6] += (AV) * B1.z; ACCROW[7] += (AV) * B1.w;

// ---------------------------------------------------------------------------
__global__ void k_detect(const unsigned char* __restrict__ mb, int* __restrict__ flag) {
    __shared__ int any;
    if (threadIdx.x == 0) any = 0;
    __syncthreads();
    int local = 0;
    for (int i = threadIdx.x; i < 16384; i += blockDim.x)
        if ((i & 3) != 0 && mb[i]) local = 1;
    if (local) atomicOr(&any, 1);
    __syncthreads();
    if (threadIdx.x == 0) *flag = any;   // 1 => byte mode, 0 => int32 mode
}

// ---------------------------------------------------------------------------
__global__ __launch_bounds__(256) void k_node_proj(
    const float* __restrict__ h, const float* __restrict__ attn_w1,
    const float* __restrict__ lin1_w,
    float* __restrict__ u, float* __restrict__ v, float* __restrict__ xh)
{
    __shared__ alignas(16) float hT[HH][68];
    const int tid = threadIdx.x;
    const int n0 = blockIdx.x * 64;
    const int mat = blockIdx.y;
    const float* __restrict__ W = (mat == 0) ? attn_w1 : (mat == 1 ? attn_w1 + HH * HH : lin1_w);
    float* __restrict__ out = (mat == 0) ? u : (mat == 1 ? v : xh);

    for (int idx = tid; idx < 64 * HH; idx += 256) {
        const int n = idx >> 7, k = idx & 127;
        hT[k][n] = h[(size_t)(n0 + n) * HH + k];
    }
    __syncthreads();

    const int te = tid & 15, tj = tid >> 4;
    float acc[4][8] = {};
    for (int k = 0; k < HH; k++) {
        const float4 a  = *(const float4*)&hT[k][te * 4];
        const float4 b0 = *(const float4*)(W + (size_t)k * HH + tj * 8);
        const float4 b1 = *(const float4*)(W + (size_t)k * HH + tj * 8 + 4);
        const float av[4] = {a.x, a.y, a.z, a.w};
#pragma unroll
        for (int i = 0; i < 4; i++) { const float ai = av[i]; FMA8(acc[i], ai, b0, b1); }
    }
#pragma unroll
    for (int i = 0; i < 4; i++) {
        float* o = out + (size_t)(n0 + te * 4 + i) * HH + tj * 8;
        float4 r0 = {acc[i][0], acc[i][1], acc[i][2], acc[i][3]};
        float4 r1 = {acc[i][4], acc[i][5], acc[i][6], acc[i][7]};
        *(float4*)o = r0;
        *(float4*)(o + 4) = r1;
    }
}

// ---------------------------------------------------------------------------
__global__ __launch_bounds__(256) void k_edge_score(
    const float* __restrict__ pos, const int* __restrict__ ei,
    const void* __restrict__ maskp, const int* __restrict__ flagp,
    const float* __restrict__ u, const float* __restrict__ v,
    const float* __restrict__ attn_w1, const float* __restrict__ attn_b1,
    const float* __restrict__ attn_w2, const float* __restrict__ attn_b2,
    float* __restrict__ dbuf, float* __restrict__ score, unsigned* __restrict__ menc)
{
    __shared__ alignas(16) float eaT[GG][64];
    __shared__ float dsh[64];
    __shared__ int rsh[64], csh[64];
    __shared__ float parts[64][17];
    const int tid = threadIdx.x;
    const int e0 = blockIdx.x * 64;

    if (tid < 64) {
        const int e = e0 + tid;
        const int r = ei[e], c = ei[EE + e];
        rsh[tid] = r; csh[tid] = c;
        const float dx = pos[r * 3 + 0] - pos[c * 3 + 0];
        const float dy = pos[r * 3 + 1] - pos[c * 3 + 1];
        const float dz = pos[r * 3 + 2] - pos[c * 3 + 2];
        const float d = sqrtf(dx * dx + dy * dy + dz * dz);
        dsh[tid] = d;
        dbuf[e] = d;
    }
    __syncthreads();
    {
        const int e = tid & 63, g0 = tid >> 6;
        const float d = dsh[e];
        for (int g = g0; g < GG; g += 4) {
            const float t = d - g * GSTEP;
            eaT[g][e] = expf(GCOEF * t * t);
        }
    }
    __syncthreads();

    const int te = tid & 15, tj = tid >> 4;
    const float* __restrict__ W1C = attn_w1 + 256 * HH;
    float acc[4][8] = {};
    for (int g = 0; g < GG; g++) {
        const float4 a  = *(const float4*)&eaT[g][te * 4];
        const float4 b0 = *(const float4*)(W1C + g * HH + tj * 8);
        const float4 b1 = *(const float4*)(W1C + g * HH + tj * 8 + 4);
        const float av[4] = {a.x, a.y, a.z, a.w};
#pragma unroll
        for (int i = 0; i < 4; i++) { const float ai = av[i]; FMA8(acc[i], ai, b0, b1); }
    }

    const float4 w20 = *(const float4*)(attn_w2 + tj * 8);
    const float4 w21 = *(const float4*)(attn_w2 + tj * 8 + 4);
    const float4 ab0 = *(const float4*)(attn_b1 + tj * 8);
    const float4 ab1 = *(const float4*)(attn_b1 + tj * 8 + 4);
    const float w2v[8] = {w20.x, w20.y, w20.z, w20.w, w21.x, w21.y, w21.z, w21.w};
    const float b1v[8] = {ab0.x, ab0.y, ab0.z, ab0.w, ab1.x, ab1.y, ab1.z, ab1.w};

#pragma unroll
    for (int i = 0; i < 4; i++) {
        const int le = te * 4 + i;
        const int r = rsh[le], c = csh[le];
        const float4 u0 = *(const float4*)(u + (size_t)r * HH + tj * 8);
        const float4 u1 = *(const float4*)(u + (size_t)r * HH + tj * 8 + 4);
        const float4 v0 = *(const float4*)(v + (size_t)c * HH + tj * 8);
        const float4 v1 = *(const float4*)(v + (size_t)c * HH + tj * 8 + 4);
        const float uv[8] = {u0.x + v0.x, u0.y + v0.y, u0.z + v0.z, u0.w + v0.w,
                             u1.x + v1.x, u1.y + v1.y, u1.z + v1.z, u1.w + v1.w};
        float pe = 0.0f;
#pragma unroll
        for (int jj = 0; jj < 8; jj++) {
            float z = acc[i][jj] + uv[jj] + b1v[jj];
            z = fmaxf(z, 0.0f);
            pe += z * w2v[jj];
        }
        parts[le][tj] = pe;
    }
    __syncthreads();
    if (tid < 64) {
        float s = attn_b2[0];
#pragma unroll
        for (int t = 0; t < 16; t++) s += parts[tid][t];
        score[e0 + tid] = s;
        const int mode = *flagp;
        if (get_mask(maskp, mode, e0 + tid))
            atomicMax(&menc[rsh[tid]], fenc(s));
    }
}

// ---------------------------------------------------------------------------
__global__ void k_expsum(const float* __restrict__ score, const int* __restrict__ ei,
                         const void* __restrict__ maskp, const int* __restrict__ flagp,
                         const unsigned* __restrict__ menc, float* __restrict__ ssum)
{
    const int e = blockIdx.x * 256 + threadIdx.x;
    if (e >= EE) return;
    const int mode = *flagp;
    if (get_mask(maskp, mode, e)) {
        const int r = ei[e];
        const float m = fdec(menc[r]);
        atomicAdd(&ssum[r], expf(score[e] - m));
    }
}

// ---------------------------------------------------------------------------
// Counting sort of edges by destination (col).
__global__ void k_hist(const int* __restrict__ ei, int* __restrict__ count) {
    const int e = blockIdx.x * 256 + threadIdx.x;
    if (e < EE) atomicAdd(&count[ei[EE + e]], 1);
}

__global__ __launch_bounds__(512) void k_scan(const int* __restrict__ count,
                                              int* __restrict__ offsets,
                                              int* __restrict__ cursor)
{
    __shared__ int s[512];
    const int t = threadIdx.x;
    const int base_i = t * 64;
    int sum = 0;
    for (int i = 0; i < 64; i++) sum += count[base_i + i];
    s[t] = sum;
    __syncthreads();
    for (int off = 1; off < 512; off <<= 1) {
        int v = (t >= off) ? s[t - off] : 0;
        __syncthreads();
        s[t] += v;
        __syncthreads();
    }
    int run = s[t] - sum;   // exclusive prefix
    for (int i = 0; i < 64; i++) {
        offsets[base_i + i] = run;
        cursor[base_i + i] = run;
        run += count[base_i + i];
    }
    if (t == 511) offsets[NN] = run;   // == EE
}

__global__ void k_scatter(const int* __restrict__ ei, int* __restrict__ cursor,
                          int* __restrict__ perm)
{
    const int e = blockIdx.x * 256 + threadIdx.x;
    if (e >= EE) return;
    const int c = ei[EE + e];
    const int pos = atomicAdd(&cursor[c], 1);
    perm[pos] = e;
}

// ---------------------------------------------------------------------------
// Filter MLP on dest-sorted edges; per-block segmented reduction in LDS.
// Interior dest segments -> plain coalesced stores; block-crossing dests
// (only first/last dest of a block can cross) -> atomicAdd.
__global__ __launch_bounds__(256) void k_filter_perm(
    const int* __restrict__ ei, const void* __restrict__ maskp, const int* __restrict__ flagp,
    const float* __restrict__ dbuf, const float* __restrict__ score,
    const unsigned* __restrict__ menc, const float* __restrict__ ssum,
    const int* __restrict__ perm,
    const float* __restrict__ filt_w1, const float* __restrict__ filt_b1,
    const float* __restrict__ filt_w2, const float* __restrict__ filt_b2,
    const float* __restrict__ xh, float* __restrict__ agg)
{
    __shared__ alignas(16) float smem[GG * 64 + HH * 68];   // eaT | T2T, later msgb
    float (*eaT)[64]   = reinterpret_cast<float(*)[64]>(smem);
    float (*T2T)[68]   = reinterpret_cast<float(*)[68]>(smem + GG * 64);
    float (*msgb)[132] = reinterpret_cast<float(*)[132]>(smem);  // 64*132 <= GG*64+HH*68
    __shared__ float dsh[64], decsh[64], Csh[64];
    __shared__ int rsh[64], csh[64];
    __shared__ int shflags;
    const int tid = threadIdx.x;
    const int e0 = blockIdx.x * 64;

    if (tid < 64) {
        const int pe = perm[e0 + tid];
        const int r = ei[pe];
        rsh[tid] = r;
        csh[tid] = ei[EE + pe];
        const float d = dbuf[pe];
        dsh[tid] = d;
        Csh[tid] = 0.5f * (cosf(d * PI_OVER_CUT) + 1.0f);
        const int mode = *flagp;
        float dec = 1.0f;
        if (get_mask(maskp, mode, pe)) {
            const float m = fdec(menc[r]);
            dec = expf(score[pe] - m) / (ssum[r] + 1e-16f);
        }
        decsh[tid] = dec;
    }
    if (tid == 64) {
        const int cfirst = ei[EE + perm[e0]];
        const int clast  = ei[EE + perm[e0 + 63]];
        int f = 0;
        if (e0 > 0 && ei[EE + perm[e0 - 1]] == cfirst) f |= 1;
        if (e0 + 64 < EE && ei[EE + perm[e0 + 64]] == clast) f |= 2;
        shflags = f;
    }
    __syncthreads();
    {
        const int e = tid & 63, g0 = tid >> 6;
        const float d = dsh[e];
        const float dec = decsh[e];
        for (int g = g0; g < GG; g += 4) {
            const float t = d - g * GSTEP;
            eaT[g][e] = expf(GCOEF * t * t) * dec;
        }
    }
    __syncthreads();

    const int te = tid & 15, tj = tid >> 4;
    float acc[4][8] = {};
    for (int g = 0; g < GG; g++) {
        const float4 a  = *(const float4*)&eaT[g][te * 4];
        const float4 b0 = *(const float4*)(filt_w1 + g * HH + tj * 8);
        const float4 b1 = *(const float4*)(filt_w1 + g * HH + tj * 8 + 4);
        const float av[4] = {a.x, a.y, a.z, a.w};
#pragma unroll
        for (int i = 0; i < 4; i++) { const float ai = av[i]; FMA8(acc[i], ai, b0, b1); }
    }
    const float4 fb0 = *(const float4*)(filt_b1 + tj * 8);
    const float4 fb1 = *(const float4*)(filt_b1 + tj * 8 + 4);
    const float fbv[8] = {fb0.x, fb0.y, fb0.z, fb0.w, fb1.x, fb1.y, fb1.z, fb1.w};
#pragma unroll
    for (int jj = 0; jj < 8; jj++) {
        const int j = tj * 8 + jj;
#pragma unroll
        for (int i = 0; i < 4; i++)
            T2T[j][te * 4 + i] = sspf(acc[i][jj] + fbv[jj]);
    }
    __syncthreads();

    float acc2[4][8] = {};
    for (int k = 0; k < HH; k++) {
        const float4 a  = *(const float4*)&T2T[k][te * 4];
        const float4 b0 = *(const float4*)(filt_w2 + (size_t)k * HH + tj * 8);
        const float4 b1 = *(const float4*)(filt_w2 + (size_t)k * HH + tj * 8 + 4);
        const float av[4] = {a.x, a.y, a.z, a.w};
#pragma unroll
        for (int i = 0; i < 4; i++) { const float ai = av[i]; FMA8(acc2[i], ai, b0, b1); }
    }
    const float4 c0 = *(const float4*)(filt_b2 + tj * 8);
    const float4 c1 = *(const float4*)(filt_b2 + tj * 8 + 4);
    const float fb2v[8] = {c0.x, c0.y, c0.z, c0.w, c1.x, c1.y, c1.z, c1.w};
    __syncthreads();   // all T2T reads done; smem may be reused as msgb

#pragma unroll
    for (int i = 0; i < 4; i++) {
        const int le = te * 4 + i;
        const int r = rsh[le];
        const float C = Csh[le];
        const float4 x0 = *(const float4*)(xh + (size_t)r * HH + tj * 8);
        const float4 x1 = *(const float4*)(xh + (size_t)r * HH + tj * 8 + 4);
        float4 m0 = {x0.x * (acc2[i][0] + fb2v[0]) * C, x0.y * (acc2[i][1] + fb2v[1]) * C,
                     x0.z * (acc2[i][2] + fb2v[2]) * C, x0.w * (acc2[i][3] + fb2v[3]) * C};
        float4 m1 = {x1.x * (acc2[i][4] + fb2v[4]) * C, x1.y * (acc2[i][5] + fb2v[5]) * C,
                     x1.z * (acc2[i][6] + fb2v[6]) * C, x1.w * (acc2[i][7] + fb2v[7]) * C};
        *(float4*)&msgb[le][tj * 8]     = m0;
        *(float4*)&msgb[le][tj * 8 + 4] = m1;
    }
    __syncthreads();

    if (tid < HH) {
        const int j = tid;
        const int fl = shflags;
        const int cfirst = csh[0], clast = csh[63];
        float a = msgb[0][j];
        int cur = cfirst;
        for (int e = 1; e < 64; e++) {
            const int de = csh[e];
            if (de != cur) {
                if ((cur == cfirst && (fl & 1)) || (cur == clast && (fl & 2)))
                    atomicAdd(&agg[(size_t)cur * HH + j], a);
                else
                    agg[(size_t)cur * HH + j] = a;
                a = 0.0f;
                cur = de;
            }
            a += msgb[e][j];
        }
        if ((cur == cfirst && (fl & 1)) || (cur == clast && (fl & 2)))
            atomicAdd(&agg[(size_t)cur * HH + j], a);
        else
            agg[(size_t)cur * HH + j] = a;
    }
}

// ---------------------------------------------------------------------------
__global__ __launch_bounds__(256) void k_final(
    const float* __restrict__ agg, const float* __restrict__ lin2_w,
    const float* __restrict__ lin2_b, const float* __restrict__ lin_w,
    const float* __restrict__ lin_b, float* __restrict__ out)
{
    __shared__ alignas(16) float AT[HH][68];
    __shared__ alignas(16) float T2T[HH][68];
    const int tid = threadIdx.x;
    const int n0 = blockIdx.x * 64;
    for (int idx = tid; idx < 64 * HH; idx += 256) {
        const int n = idx >> 7, k = idx & 127;
        AT[k][n] = agg[(size_t)(n0 + n) * HH + k];
    }
    __syncthreads();

    const int te = tid & 15, tj = tid >> 4;
    float acc[4][8] = {};
    for (int k = 0; k < HH; k++) {
        const float4 a  = *(const float4*)&AT[k][te * 4];
        const float4 b0 = *(const float4*)(lin2_w + (size_t)k * HH + tj * 8);
        const float4 b1 = *(const float4*)(lin2_w + (size_t)k * HH + tj * 8 + 4);
        const float av[4] = {a.x, a.y, a.z, a.w};
#pragma unroll
        for (int i = 0; i < 4; i++) { const float ai = av[i]; FMA8(acc[i], ai, b0, b1); }
    }
    const float4 l20 = *(const float4*)(lin2_b + tj * 8);
    const float4 l21 = *(const float4*)(lin2_b + tj * 8 + 4);
    const float l2v[8] = {l20.x, l20.y, l20.z, l20.w, l21.x, l21.y, l21.z, l21.w};
#pragma unroll
    for (int jj = 0; jj < 8; jj++) {
        const int j = tj * 8 + jj;
#pragma unroll
        for (int i = 0; i < 4; i++)
            T2T[j][te * 4 + i] = sspf(acc[i][jj] + l2v[jj]);
    }
    __syncthreads();

    float acc2[4][8] = {};
    for (int k = 0; k < HH; k++) {
        const float4 a  = *(const float4*)&T2T[k][te * 4];
        const float4 b0 = *(const float4*)(lin_w + (size_t)k * HH + tj * 8);
        const float4 b1 = *(const float4*)(lin_w + (size_t)k * HH + tj * 8 + 4);
        const float av[4] = {a.x, a.y, a.z, a.w};
#pragma unroll
        for (int i = 0; i < 4; i++) { const float ai = av[i]; FMA8(acc2[i], ai, b0, b1); }
    }
    const float4 lb0 = *(const float4*)(lin_b + tj * 8);
    const float4 lb1 = *(const float4*)(lin_b + tj * 8 + 4);
    const float lbv[8] = {lb0.x, lb0.y, lb0.z, lb0.w, lb1.x, lb1.y, lb1.z, lb1.w};
#pragma unroll
    for (int i = 0; i < 4; i++) {
        float* o = out + (size_t)(n0 + te * 4 + i) * HH + tj * 8;
        float4 r0 = {acc2[i][0] + lbv[0], acc2[i][1] + lbv[1], acc2[i][2] + lbv[2], acc2[i][3] + lbv[3]};
        float4 r1 = {acc2[i][4] + lbv[4], acc2[i][5] + lbv[5], acc2[i][6] + lbv[6], acc2[i][7] + lbv[7]};
        *(float4*)o = r0;
        *(float4*)(o + 4) = r1;
    }
}

// ---------------------------------------------------------------------------
__global__ void k_copy_pos(const float* __restrict__ pos, float* __restrict__ out) {
    const int i = blockIdx.x * 256 + threadIdx.x;
    if (i < NN * 3) out[i] = pos[i];
}

// ---------------------------------------------------------------------------
extern "C" void kernel_launch(void* const* d_in, const int* in_sizes, int n_in,
                              void* d_out, int out_size, void* d_ws, size_t ws_size,
                              hipStream_t stream)
{
    const float* h       = (const float*)d_in[0];
    const float* pos     = (const float*)d_in[1];
    const int*   ei      = (const int*)d_in[2];
    const void*  maskp   = d_in[3];
    const float* attn_w1 = (const float*)d_in[4];
    const float* attn_b1 = (const float*)d_in[5];
    const float* attn_w2 = (const float*)d_in[6];
    const float* attn_b2 = (const float*)d_in[7];
    const float* filt_w1 = (const float*)d_in[8];
    const float* filt_b1 = (const float*)d_in[9];
    const float* filt_w2 = (const float*)d_in[10];
    const float* filt_b2 = (const float*)d_in[11];
    const float* lin1_w  = (const float*)d_in[12];
    const float* lin2_w  = (const float*)d_in[13];
    const float* lin2_b  = (const float*)d_in[14];
    const float* lin_w   = (const float*)d_in[15];
    const float* lin_b   = (const float*)d_in[16];

    // Workspace layout — identical footprint to the round-1 kernel (~72 MB,
    // proven to fit). The sort arrays live inside u, which is dead after
    // k_edge_score (stream-ordered).
    char* p = (char*)d_ws;
    auto alloc = [&](size_t bytes) { char* r = p; p += (bytes + 255) & ~(size_t)255; return r; };

    float*    u     = (float*)alloc((size_t)NN * HH * 4);
    float*    v     = (float*)alloc((size_t)NN * HH * 4);
    float*    xh    = (float*)alloc((size_t)NN * HH * 4);
    float*    dbuf  = (float*)alloc((size_t)EE * 4);
    float*    score = (float*)alloc((size_t)EE * 4);
    unsigned* menc  = (unsigned*)alloc((size_t)NN * 4);
    float*    ssum  = (float*)alloc((size_t)NN * 4);
    float*    agg   = (float*)alloc((size_t)NN * HH * 4);
    int*      flag  = (int*)alloc(4);

    int* count   = (int*)u;                 // carved from dead u
    int* offsets = count + NN;              // NN+1 ints
    int* cursor  = offsets + NN + 64;
    int* perm    = cursor + NN;             // EE ints; total 2.43 MB << 16 MB

    float* out_h   = (float*)d_out;
    float* out_pos = out_h + (size_t)NN * HH;

    hipMemsetAsync(menc, 0, NN * sizeof(unsigned), stream);
    hipMemsetAsync(ssum, 0, NN * sizeof(float), stream);

    k_detect<<<1, 256, 0, stream>>>((const unsigned char*)maskp, flag);
    k_node_proj<<<dim3(NN / 64, 3), 256, 0, stream>>>(h, attn_w1, lin1_w, u, v, xh);
    k_edge_score<<<EE / 64, 256, 0, stream>>>(pos, ei, maskp, flag, u, v,
                                              attn_w1, attn_b1, attn_w2, attn_b2,
                                              dbuf, score, menc);
    k_expsum<<<EE / 256, 256, 0, stream>>>(score, ei, maskp, flag, menc, ssum);

    // u is dead from here on; build the dest-sorted permutation in its space.
    hipMemsetAsync(count, 0, NN * sizeof(int), stream);
    k_hist<<<EE / 256, 256, 0, stream>>>(ei, count);
    k_scan<<<1, 512, 0, stream>>>(count, offsets, cursor);
    k_scatter<<<EE / 256, 256, 0, stream>>>(ei, cursor, perm);

    hipMemsetAsync(agg, 0, (size_t)NN * HH * sizeof(float), stream);
    k_filter_perm<<<EE / 64, 256, 0, stream>>>(ei, maskp, flag, dbuf, score, menc, ssum,
                                               perm, filt_w1, filt_b1, filt_w2, filt_b2,
                                               xh, agg);

    k_final<<<NN / 64, 256, 0, stream>>>(agg, lin2_w, lin2_b, lin_w, lin_b, out_h);
    k_copy_pos<<<(NN * 3 + 255) / 256, 256, 0, stream>>>(pos, out_pos);
}

// Round 4
// 705.795 us; speedup vs baseline: 3.1280x; 1.2557x over previous
//
#include <hip/hip_runtime.h>

#define NN 32768
#define HH 128
#define GG 50
#define EE 524288

constexpr float GSTEP = 10.0f / 49.0f;
constexpr float GCOEF = -0.5f / (GSTEP * GSTEP);
constexpr float PI_OVER_CUT = 0.31415926535897931f;   // pi / 10
constexpr float LOG2F_ = 0.69314718055994531f;

typedef __attribute__((ext_vector_type(8))) short bf16x8;
typedef __attribute__((ext_vector_type(4))) float f32x4;
typedef unsigned short ushort_t;

__device__ __forceinline__ float sspf(float x) {
    return fmaxf(x, 0.0f) + log1pf(expf(-fabsf(x))) - LOG2F_;
}
__device__ __forceinline__ unsigned fenc(float f) {
    unsigned b = __float_as_uint(f);
    return (b & 0x80000000u) ? ~b : (b | 0x80000000u);
}
__device__ __forceinline__ float fdec(unsigned u) {
    unsigned b = (u & 0x80000000u) ? (u ^ 0x80000000u) : ~u;
    return __uint_as_float(b);
}
__device__ __forceinline__ int get_mask(const void* mp, int mode, int e) {
    if (mode) return ((const unsigned char*)mp)[e] != 0;
    return ((const int*)mp)[e] != 0;
}
__device__ __forceinline__ ushort_t f2bf(float f) {   // RNE f32 -> bf16
    unsigned u = __float_as_uint(f);
    return (ushort_t)((u + 0x7FFFu + ((u >> 16) & 1u)) >> 16);
}

#define FMA8(ACCROW, AV, B0, B1)                                   \
    ACCROW[0] += (AV) * B0.x; ACCROW[1] += (AV) * B0.y;            \
    ACCROW[2] += (AV) * B0.z; ACCROW[3] += (AV) * B0.w;            \
    ACCROW[4] += (AV) * B1.x; ACCROW[5] += (AV) * B1.y;            \
    ACCROW[6] += (AV) * B1.z; ACCROW[7] += (AV) * B1.w;

// ---------------------------------------------------------------------------
__global__ void k_detect(const unsigned char* __restrict__ mb, int* __restrict__ flag) {
    __shared__ int any;
    if (threadIdx.x == 0) any = 0;
    __syncthreads();
    int local = 0;
    for (int i = threadIdx.x; i < 16384; i += blockDim.x)
        if ((i & 3) != 0 && mb[i]) local = 1;
    if (local) atomicOr(&any, 1);
    __syncthreads();
    if (threadIdx.x == 0) *flag = any;   // 1 => byte mode, 0 => int32 mode
}

// ---------------------------------------------------------------------------
// One-time: transpose filter weights to bf16 [n][k] layouts (k zero-padded).
__global__ void k_prep_w(const float* __restrict__ filt_w1, const float* __restrict__ filt_w2,
                         ushort_t* __restrict__ w1t, ushort_t* __restrict__ w2t)
{
    const int t = blockIdx.x * 256 + threadIdx.x;
    if (t < 128 * 64) {                      // w1t[n][g], g padded 50->64
        const int n = t >> 6, g = t & 63;
        const float val = (g < GG) ? filt_w1[g * HH + n] : 0.0f;
        w1t[t] = f2bf(val);
    }
    if (t < 128 * 128) {                     // w2t[n][k]
        const int n = t >> 7, k = t & 127;
        w2t[t] = f2bf(filt_w2[k * HH + n]);
    }
}

// ---------------------------------------------------------------------------
__global__ __launch_bounds__(256) void k_node_proj(
    const float* __restrict__ h, const float* __restrict__ attn_w1,
    const float* __restrict__ lin1_w,
    float* __restrict__ u, float* __restrict__ v, float* __restrict__ xh)
{
    __shared__ alignas(16) float hT[HH][68];
    const int tid = threadIdx.x;
    const int n0 = blockIdx.x * 64;
    const int mat = blockIdx.y;
    const float* __restrict__ W = (mat == 0) ? attn_w1 : (mat == 1 ? attn_w1 + HH * HH : lin1_w);
    float* __restrict__ out = (mat == 0) ? u : (mat == 1 ? v : xh);

    for (int idx = tid; idx < 64 * HH; idx += 256) {
        const int n = idx >> 7, k = idx & 127;
        hT[k][n] = h[(size_t)(n0 + n) * HH + k];
    }
    __syncthreads();

    const int te = tid & 15, tj = tid >> 4;
    float acc[4][8] = {};
    for (int k = 0; k < HH; k++) {
        const float4 a  = *(const float4*)&hT[k][te * 4];
        const float4 b0 = *(const float4*)(W + (size_t)k * HH + tj * 8);
        const float4 b1 = *(const float4*)(W + (size_t)k * HH + tj * 8 + 4);
        const float av[4] = {a.x, a.y, a.z, a.w};
#pragma unroll
        for (int i = 0; i < 4; i++) { const float ai = av[i]; FMA8(acc[i], ai, b0, b1); }
    }
#pragma unroll
    for (int i = 0; i < 4; i++) {
        float* o = out + (size_t)(n0 + te * 4 + i) * HH + tj * 8;
        float4 r0 = {acc[i][0], acc[i][1], acc[i][2], acc[i][3]};
        float4 r1 = {acc[i][4], acc[i][5], acc[i][6], acc[i][7]};
        *(float4*)o = r0;
        *(float4*)(o + 4) = r1;
    }
}

// ---------------------------------------------------------------------------
__global__ __launch_bounds__(256) void k_edge_score(
    const float* __restrict__ pos, const int* __restrict__ ei,
    const void* __restrict__ maskp, const int* __restrict__ flagp,
    const float* __restrict__ u, const float* __restrict__ v,
    const float* __restrict__ attn_w1, const float* __restrict__ attn_b1,
    const float* __restrict__ attn_w2, const float* __restrict__ attn_b2,
    float* __restrict__ dbuf, float* __restrict__ score, unsigned* __restrict__ menc)
{
    __shared__ alignas(16) float eaT[GG][64];
    __shared__ float dsh[64];
    __shared__ int rsh[64], csh[64];
    __shared__ float parts[64][17];
    const int tid = threadIdx.x;
    const int e0 = blockIdx.x * 64;

    if (tid < 64) {
        const int e = e0 + tid;
        const int r = ei[e], c = ei[EE + e];
        rsh[tid] = r; csh[tid] = c;
        const float dx = pos[r * 3 + 0] - pos[c * 3 + 0];
        const float dy = pos[r * 3 + 1] - pos[c * 3 + 1];
        const float dz = pos[r * 3 + 2] - pos[c * 3 + 2];
        const float d = sqrtf(dx * dx + dy * dy + dz * dz);
        dsh[tid] = d;
        dbuf[e] = d;
    }
    __syncthreads();
    {
        const int e = tid & 63, g0 = tid >> 6;
        const float d = dsh[e];
        for (int g = g0; g < GG; g += 4) {
            const float t = d - g * GSTEP;
            eaT[g][e] = expf(GCOEF * t * t);
        }
    }
    __syncthreads();

    const int te = tid & 15, tj = tid >> 4;
    const float* __restrict__ W1C = attn_w1 + 256 * HH;
    float acc[4][8] = {};
    for (int g = 0; g < GG; g++) {
        const float4 a  = *(const float4*)&eaT[g][te * 4];
        const float4 b0 = *(const float4*)(W1C + g * HH + tj * 8);
        const float4 b1 = *(const float4*)(W1C + g * HH + tj * 8 + 4);
        const float av[4] = {a.x, a.y, a.z, a.w};
#pragma unroll
        for (int i = 0; i < 4; i++) { const float ai = av[i]; FMA8(acc[i], ai, b0, b1); }
    }

    const float4 w20 = *(const float4*)(attn_w2 + tj * 8);
    const float4 w21 = *(const float4*)(attn_w2 + tj * 8 + 4);
    const float4 ab0 = *(const float4*)(attn_b1 + tj * 8);
    const float4 ab1 = *(const float4*)(attn_b1 + tj * 8 + 4);
    const float w2v[8] = {w20.x, w20.y, w20.z, w20.w, w21.x, w21.y, w21.z, w21.w};
    const float b1v[8] = {ab0.x, ab0.y, ab0.z, ab0.w, ab1.x, ab1.y, ab1.z, ab1.w};

#pragma unroll
    for (int i = 0; i < 4; i++) {
        const int le = te * 4 + i;
        const int r = rsh[le], c = csh[le];
        const float4 u0 = *(const float4*)(u + (size_t)r * HH + tj * 8);
        const float4 u1 = *(const float4*)(u + (size_t)r * HH + tj * 8 + 4);
        const float4 v0 = *(const float4*)(v + (size_t)c * HH + tj * 8);
        const float4 v1 = *(const float4*)(v + (size_t)c * HH + tj * 8 + 4);
        const float uv[8] = {u0.x + v0.x, u0.y + v0.y, u0.z + v0.z, u0.w + v0.w,
                             u1.x + v1.x, u1.y + v1.y, u1.z + v1.z, u1.w + v1.w};
        float pe = 0.0f;
#pragma unroll
        for (int jj = 0; jj < 8; jj++) {
            float z = acc[i][jj] + uv[jj] + b1v[jj];
            z = fmaxf(z, 0.0f);
            pe += z * w2v[jj];
        }
        parts[le][tj] = pe;
    }
    __syncthreads();
    if (tid < 64) {
        float s = attn_b2[0];
#pragma unroll
        for (int t = 0; t < 16; t++) s += parts[tid][t];
        score[e0 + tid] = s;
        const int mode = *flagp;
        if (get_mask(maskp, mode, e0 + tid))
            atomicMax(&menc[rsh[tid]], fenc(s));
    }
}

// ---------------------------------------------------------------------------
__global__ void k_expsum(const float* __restrict__ score, const int* __restrict__ ei,
                         const void* __restrict__ maskp, const int* __restrict__ flagp,
                         const unsigned* __restrict__ menc, float* __restrict__ ssum)
{
    const int e = blockIdx.x * 256 + threadIdx.x;
    if (e >= EE) return;
    const int mode = *flagp;
    if (get_mask(maskp, mode, e)) {
        const int r = ei[e];
        const float m = fdec(menc[r]);
        atomicAdd(&ssum[r], expf(score[e] - m));
    }
}

// ---------------------------------------------------------------------------
// Counting sort of edges by destination (col).
__global__ void k_hist(const int* __restrict__ ei, int* __restrict__ count) {
    const int e = blockIdx.x * 256 + threadIdx.x;
    if (e < EE) atomicAdd(&count[ei[EE + e]], 1);
}

__global__ __launch_bounds__(512) void k_scan(const int* __restrict__ count,
                                              int* __restrict__ offsets,
                                              int* __restrict__ cursor)
{
    __shared__ int s[512];
    const int t = threadIdx.x;
    const int base_i = t * 64;
    int sum = 0;
    for (int i = 0; i < 64; i++) sum += count[base_i + i];
    s[t] = sum;
    __syncthreads();
    for (int off = 1; off < 512; off <<= 1) {
        int v = (t >= off) ? s[t - off] : 0;
        __syncthreads();
        s[t] += v;
        __syncthreads();
    }
    int run = s[t] - sum;   // exclusive prefix
    for (int i = 0; i < 64; i++) {
        offsets[base_i + i] = run;
        cursor[base_i + i] = run;
        run += count[base_i + i];
    }
    if (t == 511) offsets[NN] = run;   // == EE
}

__global__ void k_scatter(const int* __restrict__ ei, int* __restrict__ cursor,
                          int* __restrict__ perm)
{
    const int e = blockIdx.x * 256 + threadIdx.x;
    if (e >= EE) return;
    const int c = ei[EE + e];
    const int pos = atomicAdd(&cursor[c], 1);
    perm[pos] = e;
}

// ---------------------------------------------------------------------------
// MFMA filter MLP on dest-sorted edges + LDS segmented reduction.
// 64 edges/block, 4 waves. Both GEMMs on mfma_f32_16x16x32_bf16.
// A/B fragments use the SAME k-slot convention -> any HW k-permutation
// cancels; only the (HW-verified) C/D layout matters.
__global__ __launch_bounds__(256) void k_filter_mfma(
    const int* __restrict__ ei, const void* __restrict__ maskp, const int* __restrict__ flagp,
    const float* __restrict__ dbuf, const float* __restrict__ score,
    const unsigned* __restrict__ menc, const float* __restrict__ ssum,
    const int* __restrict__ perm,
    const ushort_t* __restrict__ w1t, const float* __restrict__ filt_b1,
    const ushort_t* __restrict__ w2t, const float* __restrict__ filt_b2,
    const float* __restrict__ xh, float* __restrict__ agg)
{
    __shared__ alignas(16) unsigned char smem[57344];
    // EA  @0      : ea   bf16 [64e][64k],  stride 128B, swz ((e&7)<<4)
    // W1  @8192   : w1t  bf16 [128n][64k], stride 128B, swz ((n&7)<<4)
    // T1  @24576  : t1   bf16 [64e][128k], stride 256B, swz ((e&7)<<4)
    // WB  @40960  : w2t half bf16 [64n][128k], stride 256B, swz ((n&7)<<4)
    // msgb @0     : f32 [64][132] overlay (EA/W1/T1 dead)
    unsigned char* EA = smem;
    unsigned char* W1 = smem + 8192;
    unsigned char* T1 = smem + 24576;
    unsigned char* WB = smem + 40960;
    float* msgb = (float*)smem;

    __shared__ float dsh[64], decsh[64], Csh[64];
    __shared__ int rsh[64], csh[64];
    __shared__ int shflags;

    const int tid  = threadIdx.x;
    const int e0   = blockIdx.x * 64;
    const int lane = tid & 63;
    const int wv   = tid >> 6;
    const int col0 = lane & 15;
    const int g4   = lane >> 4;

    // ---- phase A: scalar prep + stage W1 + stage WB(half0) ----
    if (tid < 64) {
        const int pe = perm[e0 + tid];
        const int r = ei[pe];
        rsh[tid] = r;
        csh[tid] = ei[EE + pe];
        const float d = dbuf[pe];
        dsh[tid] = d;
        Csh[tid] = 0.5f * (cosf(d * PI_OVER_CUT) + 1.0f);
        const int mode = *flagp;
        float dec = 1.0f;
        if (get_mask(maskp, mode, pe)) {
            const float m = fdec(menc[r]);
            dec = expf(score[pe] - m) / (ssum[r] + 1e-16f);
        }
        decsh[tid] = dec;
    }
    if (tid == 64) {
        const int cfirst = ei[EE + perm[e0]];
        const int clast  = ei[EE + perm[e0 + 63]];
        int f = 0;
        if (e0 > 0 && ei[EE + perm[e0 - 1]] == cfirst) f |= 1;
        if (e0 + 64 < EE && ei[EE + perm[e0 + 64]] == clast) f |= 2;
        shflags = f;
    }
    for (int p = tid; p < 1024; p += 256) {        // W1: 16KB
        const int byte = p * 16;
        const int n = byte >> 7;
        *(float4*)(W1 + (byte ^ ((n & 7) << 4))) = *(const float4*)((const char*)w1t + byte);
    }
    for (int p = tid; p < 1024; p += 256) {        // WB half0: 16KB
        const int byte = p * 16;
        const int nl = byte >> 8;
        *(float4*)(WB + (byte ^ ((nl & 7) << 4))) = *(const float4*)((const char*)w2t + byte);
    }
    __syncthreads();

    // ---- phase B: ea -> bf16 LDS ----
    {
        const int e = tid & 63;
        const float d = dsh[e], dec = decsh[e];
        for (int jj = wv; jj < 8; jj += 4) {
            bf16x8 pk;
#pragma unroll
            for (int b = 0; b < 8; b++) {
                const int g = jj * 8 + b;
                float val = 0.0f;
                if (g < GG) { const float t = d - g * GSTEP; val = expf(GCOEF * t * t) * dec; }
                pk[b] = (short)f2bf(val);
            }
            const int byte = e * 128 + jj * 16;
            *(bf16x8*)(EA + (byte ^ ((e & 7) << 4))) = pk;
        }
    }
    float b1v[8], b2v[8];
#pragma unroll
    for (int n = 0; n < 8; n++) {
        b1v[n] = filt_b1[n * 16 + col0];
        b2v[n] = filt_b2[n * 16 + col0];
    }
    __syncthreads();

    // ---- GEMM1: T1 = ssp(ea @ w1 + b1) ----
    const int m = wv * 16 + col0;                  // A row for this lane
    f32x4 acc[8] = {};
#pragma unroll
    for (int kk = 0; kk < 2; kk++) {
        const int abyte = m * 128 + kk * 64 + g4 * 16;
        const bf16x8 af = *(const bf16x8*)(EA + (abyte ^ ((m & 7) << 4)));
#pragma unroll
        for (int n = 0; n < 8; n++) {
            const int nn = n * 16 + col0;
            const int bbyte = nn * 128 + kk * 64 + g4 * 16;
            const bf16x8 bf_ = *(const bf16x8*)(W1 + (bbyte ^ ((nn & 7) << 4)));
            acc[n] = __builtin_amdgcn_mfma_f32_16x16x32_bf16(af, bf_, acc[n], 0, 0, 0);
        }
    }
    // epilogue1: lane holds D[row=(wv*16+g4*4+rg)][col=n*16+col0]
#pragma unroll
    for (int n = 0; n < 8; n++) {
#pragma unroll
        for (int rg = 0; rg < 4; rg++) {
            const int row = wv * 16 + g4 * 4 + rg;
            const float tv = sspf(acc[n][rg] + b1v[n]);
            const int byte = row * 256 + (n * 16 + col0) * 2;
            *(ushort_t*)(T1 + (byte ^ ((row & 7) << 4))) = f2bf(tv);
        }
    }

    // ---- GEMM2: W = t1 @ w2 + b2 (two N-halves, WB restaged) ----
    f32x4 acc2[8] = {};
#pragma unroll
    for (int half = 0; half < 2; half++) {
        if (half == 1) {
            __syncthreads();                       // all waves done with WB half0
            for (int p = tid; p < 1024; p += 256) {
                const int byte = p * 16;
                const int nl = byte >> 8;
                *(float4*)(WB + (byte ^ ((nl & 7) << 4))) =
                    *(const float4*)((const char*)w2t + 16384 + byte);
            }
            __syncthreads();
        }
#pragma unroll
        for (int kk = 0; kk < 4; kk++) {
            const int abyte = m * 256 + kk * 64 + g4 * 16;
            const bf16x8 af = *(const bf16x8*)(T1 + (abyte ^ ((m & 7) << 4)));
#pragma unroll
            for (int q = 0; q < 4; q++) {
                const int nl = q * 16 + col0;
                const int bbyte = nl * 256 + kk * 64 + g4 * 16;
                const bf16x8 bf_ = *(const bf16x8*)(WB + (bbyte ^ ((nl & 7) << 4)));
                acc2[half * 4 + q] =
                    __builtin_amdgcn_mfma_f32_16x16x32_bf16(af, bf_, acc2[half * 4 + q], 0, 0, 0);
            }
        }
    }

    // ---- epilogue2: msg = xh[r] * (W+b2) * C -> msgb (overlay) ----
    int rr[4]; float CC[4];
#pragma unroll
    for (int rg = 0; rg < 4; rg++) {
        const int e = wv * 16 + g4 * 4 + rg;
        rr[rg] = rsh[e];
        CC[rg] = Csh[e];
    }
    __syncthreads();                               // EA/W1/T1/WB all dead
#pragma unroll
    for (int n = 0; n < 8; n++) {
        const int col = n * 16 + col0;
#pragma unroll
        for (int rg = 0; rg < 4; rg++) {
            const int e = wv * 16 + g4 * 4 + rg;
            const float Wv = (acc2[n][rg] + b2v[n]) * CC[rg];
            msgb[e * 132 + col] = xh[(size_t)rr[rg] * HH + col] * Wv;
        }
    }
    __syncthreads();

    // ---- segmented reduction over dest-sorted edges ----
    if (tid < HH) {
        const int j = tid;
        const int fl = shflags;
        const int cfirst = csh[0], clast = csh[63];
        float a = msgb[0 * 132 + j];
        int cur = cfirst;
        for (int e = 1; e < 64; e++) {
            const int de = csh[e];
            if (de != cur) {
                if ((cur == cfirst && (fl & 1)) || (cur == clast && (fl & 2)))
                    atomicAdd(&agg[(size_t)cur * HH + j], a);
                else
                    agg[(size_t)cur * HH + j] = a;
                a = 0.0f;
                cur = de;
            }
            a += msgb[e * 132 + j];
        }
        if ((cur == cfirst && (fl & 1)) || (cur == clast && (fl & 2)))
            atomicAdd(&agg[(size_t)cur * HH + j], a);
        else
            agg[(size_t)cur * HH + j] = a;
    }
}

// ---------------------------------------------------------------------------
__global__ __launch_bounds__(256) void k_final(
    const float* __restrict__ agg, const float* __restrict__ lin2_w,
    const float* __restrict__ lin2_b, const float* __restrict__ lin_w,
    const float* __restrict__ lin_b, float* __restrict__ out)
{
    __shared__ alignas(16) float AT[HH][68];
    __shared__ alignas(16) float T2T[HH][68];
    const int tid = threadIdx.x;
    const int n0 = blockIdx.x * 64;
    for (int idx = tid; idx < 64 * HH; idx += 256) {
        const int n = idx >> 7, k = idx & 127;
        AT[k][n] = agg[(size_t)(n0 + n) * HH + k];
    }
    __syncthreads();

    const int te = tid & 15, tj = tid >> 4;
    float acc[4][8] = {};
    for (int k = 0; k < HH; k++) {
        const float4 a  = *(const float4*)&AT[k][te * 4];
        const float4 b0 = *(const float4*)(lin2_w + (size_t)k * HH + tj * 8);
        const float4 b1 = *(const float4*)(lin2_w + (size_t)k * HH + tj * 8 + 4);
        const float av[4] = {a.x, a.y, a.z, a.w};
#pragma unroll
        for (int i = 0; i < 4; i++) { const float ai = av[i]; FMA8(acc[i], ai, b0, b1); }
    }
    const float4 l20 = *(const float4*)(lin2_b + tj * 8);
    const float4 l21 = *(const float4*)(lin2_b + tj * 8 + 4);
    const float l2v[8] = {l20.x, l20.y, l20.z, l20.w, l21.x, l21.y, l21.z, l21.w};
#pragma unroll
    for (int jj = 0; jj < 8; jj++) {
        const int j = tj * 8 + jj;
#pragma unroll
        for (int i = 0; i < 4; i++)
            T2T[j][te * 4 + i] = sspf(acc[i][jj] + l2v[jj]);
    }
    __syncthreads();

    float acc2[4][8] = {};
    for (int k = 0; k < HH; k++) {
        const float4 a  = *(const float4*)&T2T[k][te * 4];
        const float4 b0 = *(const float4*)(lin_w + (size_t)k * HH + tj * 8);
        const float4 b1 = *(const float4*)(lin_w + (size_t)k * HH + tj * 8 + 4);
        const float av[4] = {a.x, a.y, a.z, a.w};
#pragma unroll
        for (int i = 0; i < 4; i++) { const float ai = av[i]; FMA8(acc2[i], ai, b0, b1); }
    }
    const float4 lb0 = *(const float4*)(lin_b + tj * 8);
    const float4 lb1 = *(const float4*)(lin_b + tj * 8 + 4);
    const float lbv[8] = {lb0.x, lb0.y, lb0.z, lb0.w, lb1.x, lb1.y, lb1.z, lb1.w};
#pragma unroll
    for (int i = 0; i < 4; i++) {
        float* o = out + (size_t)(n0 + te * 4 + i) * HH + tj * 8;
        float4 r0 = {acc2[i][0] + lbv[0], acc2[i][1] + lbv[1], acc2[i][2] + lbv[2], acc2[i][3] + lbv[3]};
        float4 r1 = {acc2[i][4] + lbv[4], acc2[i][5] + lbv[5], acc2[i][6] + lbv[6], acc2[i][7] + lbv[7]};
        *(float4*)o = r0;
        *(float4*)(o + 4) = r1;
    }
}

// ---------------------------------------------------------------------------
__global__ void k_copy_pos(const float* __restrict__ pos, float* __restrict__ out) {
    const int i = blockIdx.x * 256 + threadIdx.x;
    if (i < NN * 3) out[i] = pos[i];
}

// ---------------------------------------------------------------------------
extern "C" void kernel_launch(void* const* d_in, const int* in_sizes, int n_in,
                              void* d_out, int out_size, void* d_ws, size_t ws_size,
                              hipStream_t stream)
{
    const float* h       = (const float*)d_in[0];
    const float* pos     = (const float*)d_in[1];
    const int*   ei      = (const int*)d_in[2];
    const void*  maskp   = d_in[3];
    const float* attn_w1 = (const float*)d_in[4];
    const float* attn_b1 = (const float*)d_in[5];
    const float* attn_w2 = (const float*)d_in[6];
    const float* attn_b2 = (const float*)d_in[7];
    const float* filt_w1 = (const float*)d_in[8];
    const float* filt_b1 = (const float*)d_in[9];
    const float* filt_w2 = (const float*)d_in[10];
    const float* filt_b2 = (const float*)d_in[11];
    const float* lin1_w  = (const float*)d_in[12];
    const float* lin2_w  = (const float*)d_in[13];
    const float* lin2_b  = (const float*)d_in[14];
    const float* lin_w   = (const float*)d_in[15];
    const float* lin_b   = (const float*)d_in[16];

    char* p = (char*)d_ws;
    auto alloc = [&](size_t bytes) { char* r = p; p += (bytes + 255) & ~(size_t)255; return r; };

    float*    u     = (float*)alloc((size_t)NN * HH * 4);
    float*    v     = (float*)alloc((size_t)NN * HH * 4);
    float*    xh    = (float*)alloc((size_t)NN * HH * 4);
    float*    dbuf  = (float*)alloc((size_t)EE * 4);
    float*    score = (float*)alloc((size_t)EE * 4);
    unsigned* menc  = (unsigned*)alloc((size_t)NN * 4);
    float*    ssum  = (float*)alloc((size_t)NN * 4);
    float*    agg   = (float*)alloc((size_t)NN * HH * 4);
    int*      flag  = (int*)alloc(4);
    ushort_t* w1t   = (ushort_t*)alloc((size_t)128 * 64 * 2);
    ushort_t* w2t   = (ushort_t*)alloc((size_t)128 * 128 * 2);

    int* count   = (int*)u;                 // carved from dead u
    int* offsets = count + NN;              // NN+1 ints
    int* cursor  = offsets + NN + 64;
    int* perm    = cursor + NN;             // EE ints

    float* out_h   = (float*)d_out;
    float* out_pos = out_h + (size_t)NN * HH;

    hipMemsetAsync(menc, 0, NN * sizeof(unsigned), stream);
    hipMemsetAsync(ssum, 0, NN * sizeof(float), stream);

    k_detect<<<1, 256, 0, stream>>>((const unsigned char*)maskp, flag);
    k_prep_w<<<64, 256, 0, stream>>>(filt_w1, filt_w2, w1t, w2t);
    k_node_proj<<<dim3(NN / 64, 3), 256, 0, stream>>>(h, attn_w1, lin1_w, u, v, xh);
    k_edge_score<<<EE / 64, 256, 0, stream>>>(pos, ei, maskp, flag, u, v,
                                              attn_w1, attn_b1, attn_w2, attn_b2,
                                              dbuf, score, menc);
    k_expsum<<<EE / 256, 256, 0, stream>>>(score, ei, maskp, flag, menc, ssum);

    // u dead from here; build dest-sorted permutation in its space.
    hipMemsetAsync(count, 0, NN * sizeof(int), stream);
    k_hist<<<EE / 256, 256, 0, stream>>>(ei, count);
    k_scan<<<1, 512, 0, stream>>>(count, offsets, cursor);
    k_scatter<<<EE / 256, 256, 0, stream>>>(ei, cursor, perm);

    hipMemsetAsync(agg, 0, (size_t)NN * HH * sizeof(float), stream);
    k_filter_mfma<<<EE / 64, 256, 0, stream>>>(ei, maskp, flag, dbuf, score, menc, ssum,
                                               perm, w1t, filt_b1, w2t, filt_b2, xh, agg);

    k_final<<<NN / 64, 256, 0, stream>>>(agg, lin2_w, lin2_b, lin_w, lin_b, out_h);
    k_copy_pos<<<(NN * 3 + 255) / 256, 256, 0, stream>>>(pos, out_pos);
}

// Round 6
// 600.066 us; speedup vs baseline: 3.6791x; 1.1762x over previous
//
#include <hip/hip_runtime.h>

#define NN 32768
#define HH 128
#define GG 50
#define EE 524288

constexpr float GSTEP = 10.0f / 49.0f;
constexpr float GCOEF = -0.5f / (GSTEP * GSTEP);
constexpr float PI_OVER_CUT = 0.31415926535897931f;   // pi / 10
constexpr float LOG2F_ = 0.69314718055994531f;

typedef __attribute__((ext_vector_type(8))) short bf16x8;
typedef __attribute__((ext_vector_type(4))) float f32x4;
typedef unsigned short ushort_t;

__device__ __forceinline__ float sspf(float x) {
    return fmaxf(x, 0.0f) + log1pf(expf(-fabsf(x))) - LOG2F_;
}
__device__ __forceinline__ unsigned fenc(float f) {
    unsigned b = __float_as_uint(f);
    return (b & 0x80000000u) ? ~b : (b | 0x80000000u);
}
__device__ __forceinline__ float fdec(unsigned u) {
    unsigned b = (u & 0x80000000u) ? (u ^ 0x80000000u) : ~u;
    return __uint_as_float(b);
}
__device__ __forceinline__ int get_mask(const void* mp, int mode, int e) {
    if (mode) return ((const unsigned char*)mp)[e] != 0;
    return ((const int*)mp)[e] != 0;
}
__device__ __forceinline__ ushort_t f2bf(float f) {   // RNE f32 -> bf16
    unsigned u = __float_as_uint(f);
    return (ushort_t)((u + 0x7FFFu + ((u >> 16) & 1u)) >> 16);
}

#define FMA8(ACCROW, AV, B0, B1)                                   \
    ACCROW[0] += (AV) * B0.x; ACCROW[1] += (AV) * B0.y;            \
    ACCROW[2] += (AV) * B0.z; ACCROW[3] += (AV) * B0.w;            \
    ACCROW[4] += (AV) * B1.x; ACCROW[5] += (AV) * B1.y;            \
    ACCROW[6] += (AV) * B1.z; ACCROW[7] += (AV) * B1.w;

// ---------------------------------------------------------------------------
__global__ void k_detect(const unsigned char* __restrict__ mb, int* __restrict__ flag) {
    __shared__ int any;
    if (threadIdx.x == 0) any = 0;
    __syncthreads();
    int local = 0;
    for (int i = threadIdx.x; i < 16384; i += blockDim.x)
        if ((i & 3) != 0 && mb[i]) local = 1;
    if (local) atomicOr(&any, 1);
    __syncthreads();
    if (threadIdx.x == 0) *flag = any;   // 1 => byte mode, 0 => int32 mode
}

// ---------------------------------------------------------------------------
// One-time: transpose filter weights to bf16 [n][k] layouts (k zero-padded).
__global__ void k_prep_w(const float* __restrict__ filt_w1, const float* __restrict__ filt_w2,
                         ushort_t* __restrict__ w1t, ushort_t* __restrict__ w2t)
{
    const int t = blockIdx.x * 256 + threadIdx.x;
    if (t < 128 * 64) {                      // w1t[n][g], g padded 50->64
        const int n = t >> 6, g = t & 63;
        const float val = (g < GG) ? filt_w1[g * HH + n] : 0.0f;
        w1t[t] = f2bf(val);
    }
    if (t < 128 * 128) {                     // w2t[n][k]
        const int n = t >> 7, k = t & 127;
        w2t[t] = f2bf(filt_w2[k * HH + n]);
    }
}

// ---------------------------------------------------------------------------
// u = h @ attn_w1[0:128], v = h @ attn_w1[128:256], xhb = bf16(h @ lin1_w)
__global__ __launch_bounds__(256) void k_node_proj(
    const float* __restrict__ h, const float* __restrict__ attn_w1,
    const float* __restrict__ lin1_w,
    float* __restrict__ u, float* __restrict__ v, ushort_t* __restrict__ xhb)
{
    __shared__ alignas(16) float hT[HH][68];
    const int tid = threadIdx.x;
    const int n0 = blockIdx.x * 64;
    const int mat = blockIdx.y;
    const float* __restrict__ W = (mat == 0) ? attn_w1 : (mat == 1 ? attn_w1 + HH * HH : lin1_w);

    for (int idx = tid; idx < 64 * HH; idx += 256) {
        const int n = idx >> 7, k = idx & 127;
        hT[k][n] = h[(size_t)(n0 + n) * HH + k];
    }
    __syncthreads();

    const int te = tid & 15, tj = tid >> 4;
    float acc[4][8] = {};
    for (int k = 0; k < HH; k++) {
        const float4 a  = *(const float4*)&hT[k][te * 4];
        const float4 b0 = *(const float4*)(W + (size_t)k * HH + tj * 8);
        const float4 b1 = *(const float4*)(W + (size_t)k * HH + tj * 8 + 4);
        const float av[4] = {a.x, a.y, a.z, a.w};
#pragma unroll
        for (int i = 0; i < 4; i++) { const float ai = av[i]; FMA8(acc[i], ai, b0, b1); }
    }
    if (mat < 2) {
        float* __restrict__ out = (mat == 0) ? u : v;
#pragma unroll
        for (int i = 0; i < 4; i++) {
            float* o = out + (size_t)(n0 + te * 4 + i) * HH + tj * 8;
            float4 r0 = {acc[i][0], acc[i][1], acc[i][2], acc[i][3]};
            float4 r1 = {acc[i][4], acc[i][5], acc[i][6], acc[i][7]};
            *(float4*)o = r0;
            *(float4*)(o + 4) = r1;
        }
    } else {
#pragma unroll
        for (int i = 0; i < 4; i++) {
            unsigned pk[4];
#pragma unroll
            for (int p = 0; p < 4; p++)
                pk[p] = (unsigned)f2bf(acc[i][2 * p]) | ((unsigned)f2bf(acc[i][2 * p + 1]) << 16);
            uint4 r = {pk[0], pk[1], pk[2], pk[3]};
            *(uint4*)(xhb + (size_t)(n0 + te * 4 + i) * HH + tj * 8) = r;
        }
    }
}

// ---------------------------------------------------------------------------
__global__ __launch_bounds__(256) void k_edge_score(
    const float* __restrict__ pos, const int* __restrict__ ei,
    const void* __restrict__ maskp, const int* __restrict__ flagp,
    const float* __restrict__ u, const float* __restrict__ v,
    const float* __restrict__ attn_w1, const float* __restrict__ attn_b1,
    const float* __restrict__ attn_w2, const float* __restrict__ attn_b2,
    float* __restrict__ dbuf, float* __restrict__ score, unsigned* __restrict__ menc)
{
    __shared__ alignas(16) float eaT[GG][64];
    __shared__ float dsh[64];
    __shared__ int rsh[64], csh[64];
    __shared__ float parts[64][17];
    const int tid = threadIdx.x;
    const int e0 = blockIdx.x * 64;

    if (tid < 64) {
        const int e = e0 + tid;
        const int r = ei[e], c = ei[EE + e];
        rsh[tid] = r; csh[tid] = c;
        const float dx = pos[r * 3 + 0] - pos[c * 3 + 0];
        const float dy = pos[r * 3 + 1] - pos[c * 3 + 1];
        const float dz = pos[r * 3 + 2] - pos[c * 3 + 2];
        const float d = sqrtf(dx * dx + dy * dy + dz * dz);
        dsh[tid] = d;
        dbuf[e] = d;
    }
    __syncthreads();
    {
        const int e = tid & 63, g0 = tid >> 6;
        const float d = dsh[e];
        for (int g = g0; g < GG; g += 4) {
            const float t = d - g * GSTEP;
            eaT[g][e] = expf(GCOEF * t * t);
        }
    }
    __syncthreads();

    const int te = tid & 15, tj = tid >> 4;
    const float* __restrict__ W1C = attn_w1 + 256 * HH;
    float acc[4][8] = {};
    for (int g = 0; g < GG; g++) {
        const float4 a  = *(const float4*)&eaT[g][te * 4];
        const float4 b0 = *(const float4*)(W1C + g * HH + tj * 8);
        const float4 b1 = *(const float4*)(W1C + g * HH + tj * 8 + 4);
        const float av[4] = {a.x, a.y, a.z, a.w};
#pragma unroll
        for (int i = 0; i < 4; i++) { const float ai = av[i]; FMA8(acc[i], ai, b0, b1); }
    }

    const float4 w20 = *(const float4*)(attn_w2 + tj * 8);
    const float4 w21 = *(const float4*)(attn_w2 + tj * 8 + 4);
    const float4 ab0 = *(const float4*)(attn_b1 + tj * 8);
    const float4 ab1 = *(const float4*)(attn_b1 + tj * 8 + 4);
    const float w2v[8] = {w20.x, w20.y, w20.z, w20.w, w21.x, w21.y, w21.z, w21.w};
    const float b1v[8] = {ab0.x, ab0.y, ab0.z, ab0.w, ab1.x, ab1.y, ab1.z, ab1.w};

#pragma unroll
    for (int i = 0; i < 4; i++) {
        const int le = te * 4 + i;
        const int r = rsh[le], c = csh[le];
        const float4 u0 = *(const float4*)(u + (size_t)r * HH + tj * 8);
        const float4 u1 = *(const float4*)(u + (size_t)r * HH + tj * 8 + 4);
        const float4 v0 = *(const float4*)(v + (size_t)c * HH + tj * 8);
        const float4 v1 = *(const float4*)(v + (size_t)c * HH + tj * 8 + 4);
        const float uv[8] = {u0.x + v0.x, u0.y + v0.y, u0.z + v0.z, u0.w + v0.w,
                             u1.x + v1.x, u1.y + v1.y, u1.z + v1.z, u1.w + v1.w};
        float pe = 0.0f;
#pragma unroll
        for (int jj = 0; jj < 8; jj++) {
            float z = acc[i][jj] + uv[jj] + b1v[jj];
            z = fmaxf(z, 0.0f);
            pe += z * w2v[jj];
        }
        parts[le][tj] = pe;
    }
    __syncthreads();
    if (tid < 64) {
        float s = attn_b2[0];
#pragma unroll
        for (int t = 0; t < 16; t++) s += parts[tid][t];
        score[e0 + tid] = s;
        const int mode = *flagp;
        if (get_mask(maskp, mode, e0 + tid))
            atomicMax(&menc[rsh[tid]], fenc(s));
    }
}

// ---------------------------------------------------------------------------
// Merged: histogram by dest + masked exp-sum by source (one edge pass).
__global__ void k_prep_edges(const float* __restrict__ score, const int* __restrict__ ei,
                             const void* __restrict__ maskp, const int* __restrict__ flagp,
                             const unsigned* __restrict__ menc,
                             float* __restrict__ ssum, int* __restrict__ count)
{
    const int e = blockIdx.x * 256 + threadIdx.x;
    if (e >= EE) return;
    atomicAdd(&count[ei[EE + e]], 1);
    const int mode = *flagp;
    if (get_mask(maskp, mode, e)) {
        const int r = ei[e];
        const float m = fdec(menc[r]);
        atomicAdd(&ssum[r], expf(score[e] - m));
    }
}

// ---------------------------------------------------------------------------
__global__ __launch_bounds__(512) void k_scan(const int* __restrict__ count,
                                              int* __restrict__ offsets,
                                              int* __restrict__ cursor)
{
    __shared__ int s[512];
    const int t = threadIdx.x;
    const int base_i = t * 64;
    int sum = 0;
    for (int i = 0; i < 64; i++) sum += count[base_i + i];
    s[t] = sum;
    __syncthreads();
    for (int off = 1; off < 512; off <<= 1) {
        int v = (t >= off) ? s[t - off] : 0;
        __syncthreads();
        s[t] += v;
        __syncthreads();
    }
    int run = s[t] - sum;   // exclusive prefix
    for (int i = 0; i < 64; i++) {
        offsets[base_i + i] = run;
        cursor[base_i + i] = run;
        run += count[base_i + i];
    }
    if (t == 511) offsets[NN] = run;   // == EE
}

__global__ void k_scatter(const int* __restrict__ ei, int* __restrict__ cursor,
                          int* __restrict__ perm)
{
    const int e = blockIdx.x * 256 + threadIdx.x;
    if (e >= EE) return;
    const int c = ei[EE + e];
    const int pos = atomicAdd(&cursor[c], 1);
    perm[pos] = e;
}

// ---------------------------------------------------------------------------
// MFMA filter MLP on dest-sorted edges + LDS segmented reduction.
// 64 edges/block, 4 waves, ~34KB LDS -> 4 blocks/CU. xh gathered as bf16
// into registers BEFORE the GEMMs (latency hidden under MFMA phases).
// LDS map (32KB main buffer):
//   [0,8K)   EA  bf16[64e][64k]            -> WBh (16KB, restaged 2x)
//   [8,16K)  W1h bf16[64n][64k] (restaged) -> (part of WBh)
//   [16,32K) T1  bf16[64e][128k]
//   [0,32K)  msgb f32[64][128] (+8*g4 col-skew) after GEMM2
__global__ __launch_bounds__(256, 4) void k_filter_mfma(
    const int* __restrict__ ei, const void* __restrict__ maskp, const int* __restrict__ flagp,
    const float* __restrict__ dbuf, const float* __restrict__ score,
    const unsigned* __restrict__ menc, const float* __restrict__ ssum,
    const int* __restrict__ perm,
    const ushort_t* __restrict__ w1t, const float* __restrict__ filt_b1,
    const ushort_t* __restrict__ w2t, const float* __restrict__ filt_b2,
    const ushort_t* __restrict__ xhb, float* __restrict__ agg)
{
    __shared__ alignas(16) unsigned char smem[32768];
    unsigned char* EA = smem;
    unsigned char* W1 = smem + 8192;
    unsigned char* T1 = smem + 16384;
    unsigned char* WB = smem;
    float* msgb = (float*)smem;

    __shared__ float dsh[64], decsh[64], Csh[64];
    __shared__ int rsh[64], csh[64];
    __shared__ int shflags;

    const int tid  = threadIdx.x;
    const int e0   = blockIdx.x * 64;
    const int lane = tid & 63;
    const int wv   = tid >> 6;
    const int col0 = lane & 15;
    const int g4   = lane >> 4;

    // ---- phase A: scalar prep + stage W1 half0 ----
    if (tid < 64) {
        const int pe = perm[e0 + tid];
        const int r = ei[pe];
        rsh[tid] = r;
        csh[tid] = ei[EE + pe];
        const float d = dbuf[pe];
        dsh[tid] = d;
        Csh[tid] = 0.5f * (cosf(d * PI_OVER_CUT) + 1.0f);
        const int mode = *flagp;
        float dec = 1.0f;
        if (get_mask(maskp, mode, pe)) {
            const float m = fdec(menc[r]);
            dec = expf(score[pe] - m) / (ssum[r] + 1e-16f);
        }
        decsh[tid] = dec;
    }
    if (tid == 64) {
        const int cfirst = ei[EE + perm[e0]];
        const int clast  = ei[EE + perm[e0 + 63]];
        int f = 0;
        if (e0 > 0 && ei[EE + perm[e0 - 1]] == cfirst) f |= 1;
        if (e0 + 64 < EE && ei[EE + perm[e0 + 64]] == clast) f |= 2;
        shflags = f;
    }
    for (int p = tid; p < 512; p += 256) {       // W1 half0: 8KB
        const int byte = p * 16;
        const int n = byte >> 7;
        *(float4*)(W1 + (byte ^ ((n & 7) << 4))) = *(const float4*)((const char*)w1t + byte);
    }
    __syncthreads();

    // ---- phase B: EA fill + xh register prefetch ----
    {
        const int e = tid & 63, jg = tid >> 6;
        const float d = dsh[e], dec = decsh[e];
        for (int jj = jg; jj < 8; jj += 4) {
            bf16x8 pk;
#pragma unroll
            for (int b = 0; b < 8; b++) {
                const int g = jj * 8 + b;
                float val = 0.0f;
                if (g < GG) { const float t = d - g * GSTEP; val = expf(GCOEF * t * t) * dec; }
                pk[b] = (short)f2bf(val);
            }
            const int byte = e * 128 + jj * 16;
            *(bf16x8*)(EA + (byte ^ ((e & 7) << 4))) = pk;
        }
    }
    int rr[4]; float CC[4];
#pragma unroll
    for (int rg = 0; rg < 4; rg++) {
        const int e = wv * 16 + g4 * 4 + rg;
        rr[rg] = rsh[e];
        CC[rg] = Csh[e];
    }
    ushort_t xr[4][8];                           // issued here, used in epilogue2
#pragma unroll
    for (int rg = 0; rg < 4; rg++)
#pragma unroll
        for (int n = 0; n < 8; n++)
            xr[rg][n] = xhb[(size_t)rr[rg] * HH + n * 16 + col0];
    float b1v[8], b2v[8];
#pragma unroll
    for (int n = 0; n < 8; n++) {
        b1v[n] = filt_b1[n * 16 + col0];
        b2v[n] = filt_b2[n * 16 + col0];
    }
    __syncthreads();

    // ---- GEMM1: T1 = ssp(ea @ w1 + b1), W1 staged in two 8KB halves ----
    const int m = wv * 16 + col0;
    f32x4 acc[8] = {};
#pragma unroll
    for (int h = 0; h < 2; h++) {
        if (h == 1) {
            __syncthreads();
            for (int p = tid; p < 512; p += 256) {
                const int byte = p * 16;
                const int n = byte >> 7;
                *(float4*)(W1 + (byte ^ ((n & 7) << 4))) =
                    *(const float4*)((const char*)w1t + 8192 + byte);
            }
            __syncthreads();
        }
#pragma unroll
        for (int kk = 0; kk < 2; kk++) {
            const int abyte = m * 128 + kk * 64 + g4 * 16;
            const bf16x8 af = *(const bf16x8*)(EA + (abyte ^ ((m & 7) << 4)));
#pragma unroll
            for (int q = 0; q < 4; q++) {
                const int l = q * 16 + col0;
                const int bbyte = l * 128 + kk * 64 + g4 * 16;
                const bf16x8 bf_ = *(const bf16x8*)(W1 + (bbyte ^ ((l & 7) << 4)));
                acc[h * 4 + q] = __builtin_amdgcn_mfma_f32_16x16x32_bf16(af, bf_, acc[h * 4 + q], 0, 0, 0);
            }
        }
    }
    // epilogue1 -> T1 (bf16): lane holds D[row][col=n*16+col0], row=wv*16+g4*4+rg
#pragma unroll
    for (int n = 0; n < 8; n++) {
#pragma unroll
        for (int rg = 0; rg < 4; rg++) {
            const int row = wv * 16 + g4 * 4 + rg;
            const float tv = sspf(acc[n][rg] + b1v[n]);
            const int lbyte = row * 256 + (n * 16 + col0) * 2;   // local offset in T1
            *(ushort_t*)(T1 + (lbyte ^ ((row & 7) << 4))) = f2bf(tv);
        }
    }
    __syncthreads();

    // ---- GEMM2: W = t1 @ w2 + b2, WB staged in two 16KB halves over EA/W1 ----
    f32x4 acc2[8] = {};
#pragma unroll
    for (int h = 0; h < 2; h++) {
        for (int p = tid; p < 1024; p += 256) {
            const int byte = p * 16;
            const int nl = byte >> 8;
            *(float4*)(WB + (byte ^ ((nl & 7) << 4))) =
                *(const float4*)((const char*)w2t + h * 16384 + byte);
        }
        __syncthreads();
#pragma unroll
        for (int kk = 0; kk < 4; kk++) {
            const int abyte = m * 256 + kk * 64 + g4 * 16;
            const bf16x8 af = *(const bf16x8*)(T1 + (abyte ^ ((m & 7) << 4)));
#pragma unroll
            for (int q = 0; q < 4; q++) {
                const int l = q * 16 + col0;
                const int bbyte = l * 256 + kk * 64 + g4 * 16;
                const bf16x8 bf_ = *(const bf16x8*)(WB + (bbyte ^ ((l & 7) << 4)));
                acc2[h * 4 + q] = __builtin_amdgcn_mfma_f32_16x16x32_bf16(af, bf_, acc2[h * 4 + q], 0, 0, 0);
            }
        }
        __syncthreads();   // h0: before restaging WB half1; h1: WB/T1 dead
    }

    // ---- epilogue2: msg = xh[r] * (W+b2) * C -> msgb (skewed, overlay) ----
#pragma unroll
    for (int n = 0; n < 8; n++) {
        const int col = n * 16 + col0;
#pragma unroll
        for (int rg = 0; rg < 4; rg++) {
            const int e = wv * 16 + g4 * 4 + rg;
            const float Wv = (acc2[n][rg] + b2v[n]) * CC[rg];
            const float xv = __uint_as_float(((unsigned)xr[rg][n]) << 16);
            msgb[e * 128 + ((col + 8 * g4) & 127)] = xv * Wv;
        }
    }
    __syncthreads();

    // ---- segmented reduction: 2 halves x 32 edges, all 256 threads ----
    {
        const int q = tid >> 7;          // 0 or 1
        const int j = tid & 127;
        const int base = q * 32;
        const int fl = shflags;
        const int cfirst = csh[base], clast = csh[base + 31];
        const int f1 = (q == 0) ? (fl & 1) : (csh[base - 1] == cfirst);
        const int f2 = (q == 1) ? (fl & 2) : (csh[base + 32] == clast);
        float a = msgb[base * 128 + ((j + 8 * ((base >> 2) & 3)) & 127)];
        int cur = cfirst;
        for (int e = base + 1; e < base + 32; e++) {
            const int de = csh[e];
            if (de != cur) {
                if ((cur == cfirst && f1) || (cur == clast && f2))
                    atomicAdd(&agg[(size_t)cur * HH + j], a);
                else
                    agg[(size_t)cur * HH + j] = a;
                a = 0.0f;
                cur = de;
            }
            a += msgb[e * 128 + ((j + 8 * ((e >> 2) & 3)) & 127)];
        }
        if ((cur == cfirst && f1) || (cur == clast && f2))
            atomicAdd(&agg[(size_t)cur * HH + j], a);
        else
            agg[(size_t)cur * HH + j] = a;
    }
}

// ---------------------------------------------------------------------------
__global__ __launch_bounds__(256) void k_final(
    const float* __restrict__ agg, const float* __restrict__ lin2_w,
    const float* __restrict__ lin2_b, const float* __restrict__ lin_w,
    const float* __restrict__ lin_b, float* __restrict__ out)
{
    __shared__ alignas(16) float AT[HH][68];
    __shared__ alignas(16) float T2T[HH][68];
    const int tid = threadIdx.x;
    const int n0 = blockIdx.x * 64;
    for (int idx = tid; idx < 64 * HH; idx += 256) {
        const int n = idx >> 7, k = idx & 127;
        AT[k][n] = agg[(size_t)(n0 + n) * HH + k];
    }
    __syncthreads();

    const int te = tid & 15, tj = tid >> 4;
    float acc[4][8] = {};
    for (int k = 0; k < HH; k++) {
        const float4 a  = *(const float4*)&AT[k][te * 4];
        const float4 b0 = *(const float4*)(lin2_w + (size_t)k * HH + tj * 8);
        const float4 b1 = *(const float4*)(lin2_w + (size_t)k * HH + tj * 8 + 4);
        const float av[4] = {a.x, a.y, a.z, a.w};
#pragma unroll
        for (int i = 0; i < 4; i++) { const float ai = av[i]; FMA8(acc[i], ai, b0, b1); }
    }
    const float4 l20 = *(const float4*)(lin2_b + tj * 8);
    const float4 l21 = *(const float4*)(lin2_b + tj * 8 + 4);
    const float l2v[8] = {l20.x, l20.y, l20.z, l20.w, l21.x, l21.y, l21.z, l21.w};
#pragma unroll
    for (int jj = 0; jj < 8; jj++) {
        const int j = tj * 8 + jj;
#pragma unroll
        for (int i = 0; i < 4; i++)
            T2T[j][te * 4 + i] = sspf(acc[i][jj] + l2v[jj]);
    }
    __syncthreads();

    float acc2[4][8] = {};
    for (int k = 0; k < HH; k++) {
        const float4 a  = *(const float4*)&T2T[k][te * 4];
        const float4 b0 = *(const float4*)(lin_w + (size_t)k * HH + tj * 8);
        const float4 b1 = *(const float4*)(lin_w + (size_t)k * HH + tj * 8 + 4);
        const float av[4] = {a.x, a.y, a.z, a.w};
#pragma unroll
        for (int i = 0; i < 4; i++) { const float ai = av[i]; FMA8(acc2[i], ai, b0, b1); }
    }
    const float4 lb0 = *(const float4*)(lin_b + tj * 8);
    const float4 lb1 = *(const float4*)(lin_b + tj * 8 + 4);
    const float lbv[8] = {lb0.x, lb0.y, lb0.z, lb0.w, lb1.x, lb1.y, lb1.z, lb1.w};
#pragma unroll
    for (int i = 0; i < 4; i++) {
        float* o = out + (size_t)(n0 + te * 4 + i) * HH + tj * 8;
        float4 r0 = {acc2[i][0] + lbv[0], acc2[i][1] + lbv[1], acc2[i][2] + lbv[2], acc2[i][3] + lbv[3]};
        float4 r1 = {acc2[i][4] + lbv[4], acc2[i][5] + lbv[5], acc2[i][6] + lbv[6], acc2[i][7] + lbv[7]};
        *(float4*)o = r0;
        *(float4*)(o + 4) = r1;
    }
}

// ---------------------------------------------------------------------------
__global__ void k_copy_pos(const float* __restrict__ pos, float* __restrict__ out) {
    const int i = blockIdx.x * 256 + threadIdx.x;
    if (i < NN * 3) out[i] = pos[i];
}

// ---------------------------------------------------------------------------
extern "C" void kernel_launch(void* const* d_in, const int* in_sizes, int n_in,
                              void* d_out, int out_size, void* d_ws, size_t ws_size,
                              hipStream_t stream)
{
    const float* h       = (const float*)d_in[0];
    const float* pos     = (const float*)d_in[1];
    const int*   ei      = (const int*)d_in[2];
    const void*  maskp   = d_in[3];
    const float* attn_w1 = (const float*)d_in[4];
    const float* attn_b1 = (const float*)d_in[5];
    const float* attn_w2 = (const float*)d_in[6];
    const float* attn_b2 = (const float*)d_in[7];
    const float* filt_w1 = (const float*)d_in[8];
    const float* filt_b1 = (const float*)d_in[9];
    const float* filt_w2 = (const float*)d_in[10];
    const float* filt_b2 = (const float*)d_in[11];
    const float* lin1_w  = (const float*)d_in[12];
    const float* lin2_w  = (const float*)d_in[13];
    const float* lin2_b  = (const float*)d_in[14];
    const float* lin_w   = (const float*)d_in[15];
    const float* lin_b   = (const float*)d_in[16];

    char* p = (char*)d_ws;
    auto alloc = [&](size_t bytes) { char* r = p; p += (bytes + 255) & ~(size_t)255; return r; };

    float*    u     = (float*)alloc((size_t)NN * HH * 4);
    float*    v     = (float*)alloc((size_t)NN * HH * 4);
    ushort_t* xhb   = (ushort_t*)alloc((size_t)NN * HH * 2);
    float*    dbuf  = (float*)alloc((size_t)EE * 4);
    float*    score = (float*)alloc((size_t)EE * 4);
    unsigned* menc  = (unsigned*)alloc((size_t)NN * 4);
    float*    ssum  = (float*)alloc((size_t)NN * 4);
    float*    agg   = (float*)alloc((size_t)NN * HH * 4);
    int*      flag  = (int*)alloc(4);
    ushort_t* w1t   = (ushort_t*)alloc((size_t)128 * 64 * 2);
    ushort_t* w2t   = (ushort_t*)alloc((size_t)128 * 128 * 2);

    int* count   = (int*)u;                 // carved from u (dead after k_edge_score)
    int* offsets = count + NN;              // NN+1 ints
    int* cursor  = offsets + NN + 64;
    int* perm    = cursor + NN;             // EE ints

    float* out_h   = (float*)d_out;
    float* out_pos = out_h + (size_t)NN * HH;

    hipMemsetAsync(menc, 0, NN * sizeof(unsigned), stream);
    hipMemsetAsync(ssum, 0, NN * sizeof(float), stream);

    k_detect<<<1, 256, 0, stream>>>((const unsigned char*)maskp, flag);
    k_prep_w<<<64, 256, 0, stream>>>(filt_w1, filt_w2, w1t, w2t);
    k_node_proj<<<dim3(NN / 64, 3), 256, 0, stream>>>(h, attn_w1, lin1_w, u, v, xhb);
    k_edge_score<<<EE / 64, 256, 0, stream>>>(pos, ei, maskp, flag, u, v,
                                              attn_w1, attn_b1, attn_w2, attn_b2,
                                              dbuf, score, menc);

    // u dead from here; build dest-sorted permutation in its space.
    hipMemsetAsync(count, 0, NN * sizeof(int), stream);
    k_prep_edges<<<EE / 256, 256, 0, stream>>>(score, ei, maskp, flag, menc, ssum, count);
    k_scan<<<1, 512, 0, stream>>>(count, offsets, cursor);
    k_scatter<<<EE / 256, 256, 0, stream>>>(ei, cursor, perm);

    hipMemsetAsync(agg, 0, (size_t)NN * HH * sizeof(float), stream);
    k_filter_mfma<<<EE / 64, 256, 0, stream>>>(ei, maskp, flag, dbuf, score, menc, ssum,
                                               perm, w1t, filt_b1, w2t, filt_b2, xhb, agg);

    k_final<<<NN / 64, 256, 0, stream>>>(agg, lin2_w, lin2_b, lin_w, lin_b, out_h);
    k_copy_pos<<<(NN * 3 + 255) / 256, 256, 0, stream>>>(pos, out_pos);
}

// Round 7
// 477.565 us; speedup vs baseline: 4.6229x; 1.2565x over previous
//
#include <hip/hip_runtime.h>

#define NN 32768
#define HH 128
#define GG 50
#define EE 524288

constexpr float GSTEP = 10.0f / 49.0f;
constexpr float GCOEF = -0.5f / (GSTEP * GSTEP);
constexpr float PI_OVER_CUT = 0.31415926535897931f;   // pi / 10
constexpr float LOG2F_ = 0.69314718055994531f;
constexpr float LOG2E_ = 1.4426950408889634f;
constexpr float RLOG2E_ = 0.69314718055994531f;
constexpr float GC2 = GCOEF * LOG2E_;                 // gaussian exp -> exp2

typedef __attribute__((ext_vector_type(8))) short bf16x8;
typedef __attribute__((ext_vector_type(4))) float f32x4;
typedef unsigned short ushort_t;

__device__ __forceinline__ float fast_exp2(float x) {
    float r; asm("v_exp_f32 %0, %1" : "=v"(r) : "v"(x)); return r;
}
__device__ __forceinline__ float fast_log2(float x) {
    float r; asm("v_log_f32 %0, %1" : "=v"(r) : "v"(x)); return r;
}
__device__ __forceinline__ float fexpf(float x) {      // e^x via v_exp_f32
    return fast_exp2(x * LOG2E_);
}
__device__ __forceinline__ float sspf(float x) {       // softplus(x) - log2
    const float p = fast_exp2(x * LOG2E_);
    const float r = RLOG2E_ * fast_log2(1.0f + p) - LOG2F_;
    return (x > 80.0f) ? (x - LOG2F_) : r;
}
__device__ __forceinline__ unsigned fenc(float f) {
    unsigned b = __float_as_uint(f);
    return (b & 0x80000000u) ? ~b : (b | 0x80000000u);
}
__device__ __forceinline__ float fdec(unsigned u) {
    unsigned b = (u & 0x80000000u) ? (u ^ 0x80000000u) : ~u;
    return __uint_as_float(b);
}
__device__ __forceinline__ int get_mask(const void* mp, int mode, int e) {
    if (mode) return ((const unsigned char*)mp)[e] != 0;
    return ((const int*)mp)[e] != 0;
}
__device__ __forceinline__ ushort_t f2bf(float f) {   // RNE f32 -> bf16
    unsigned u = __float_as_uint(f);
    return (ushort_t)((u + 0x7FFFu + ((u >> 16) & 1u)) >> 16);
}
__device__ __forceinline__ float bflo(unsigned q) { return __uint_as_float(q << 16); }
__device__ __forceinline__ float bfhi(unsigned q) { return __uint_as_float(q & 0xFFFF0000u); }

#define FMA8(ACCROW, AV, B0, B1)                                   \
    ACCROW[0] += (AV) * B0.x; ACCROW[1] += (AV) * B0.y;            \
    ACCROW[2] += (AV) * B0.z; ACCROW[3] += (AV) * B0.w;            \
    ACCROW[4] += (AV) * B1.x; ACCROW[5] += (AV) * B1.y;            \
    ACCROW[6] += (AV) * B1.z; ACCROW[7] += (AV) * B1.w;

// ---------------------------------------------------------------------------
__global__ void k_detect(const unsigned char* __restrict__ mb, int* __restrict__ flag) {
    __shared__ int any;
    if (threadIdx.x == 0) any = 0;
    __syncthreads();
    int local = 0;
    for (int i = threadIdx.x; i < 16384; i += blockDim.x)
        if ((i & 3) != 0 && mb[i]) local = 1;
    if (local) atomicOr(&any, 1);
    __syncthreads();
    if (threadIdx.x == 0) *flag = any;   // 1 => byte mode, 0 => int32 mode
}

// ---------------------------------------------------------------------------
// One-time: transpose filter weights to bf16 [n][k] layouts (k zero-padded).
__global__ void k_prep_w(const float* __restrict__ filt_w1, const float* __restrict__ filt_w2,
                         ushort_t* __restrict__ w1t, ushort_t* __restrict__ w2t)
{
    const int t = blockIdx.x * 256 + threadIdx.x;
    if (t < 128 * 64) {                      // w1t[n][g], g padded 50->64
        const int n = t >> 6, g = t & 63;
        const float val = (g < GG) ? filt_w1[g * HH + n] : 0.0f;
        w1t[t] = f2bf(val);
    }
    if (t < 128 * 128) {                     // w2t[n][k]
        const int n = t >> 7, k = t & 127;
        w2t[t] = f2bf(filt_w2[k * HH + n]);
    }
}

// ---------------------------------------------------------------------------
// ub = bf16(h @ attn_w1[0:128]), vb = bf16(h @ attn_w1[128:256]),
// xhb = bf16(h @ lin1_w)
__global__ __launch_bounds__(256) void k_node_proj(
    const float* __restrict__ h, const float* __restrict__ attn_w1,
    const float* __restrict__ lin1_w,
    ushort_t* __restrict__ ub, ushort_t* __restrict__ vb, ushort_t* __restrict__ xhb)
{
    __shared__ alignas(16) float hT[HH][68];
    const int tid = threadIdx.x;
    const int n0 = blockIdx.x * 64;
    const int mat = blockIdx.y;
    const float* __restrict__ W = (mat == 0) ? attn_w1 : (mat == 1 ? attn_w1 + HH * HH : lin1_w);
    ushort_t* __restrict__ out = (mat == 0) ? ub : (mat == 1 ? vb : xhb);

    for (int idx = tid; idx < 64 * HH; idx += 256) {
        const int n = idx >> 7, k = idx & 127;
        hT[k][n] = h[(size_t)(n0 + n) * HH + k];
    }
    __syncthreads();

    const int te = tid & 15, tj = tid >> 4;
    float acc[4][8] = {};
    for (int k = 0; k < HH; k++) {
        const float4 a  = *(const float4*)&hT[k][te * 4];
        const float4 b0 = *(const float4*)(W + (size_t)k * HH + tj * 8);
        const float4 b1 = *(const float4*)(W + (size_t)k * HH + tj * 8 + 4);
        const float av[4] = {a.x, a.y, a.z, a.w};
#pragma unroll
        for (int i = 0; i < 4; i++) { const float ai = av[i]; FMA8(acc[i], ai, b0, b1); }
    }
#pragma unroll
    for (int i = 0; i < 4; i++) {
        unsigned pk[4];
#pragma unroll
        for (int p = 0; p < 4; p++)
            pk[p] = (unsigned)f2bf(acc[i][2 * p]) | ((unsigned)f2bf(acc[i][2 * p + 1]) << 16);
        uint4 r = {pk[0], pk[1], pk[2], pk[3]};
        *(uint4*)(out + (size_t)(n0 + te * 4 + i) * HH + tj * 8) = r;
    }
}

// ---------------------------------------------------------------------------
__global__ __launch_bounds__(256) void k_edge_score(
    const float* __restrict__ pos, const int* __restrict__ ei,
    const void* __restrict__ maskp, const int* __restrict__ flagp,
    const ushort_t* __restrict__ ub, const ushort_t* __restrict__ vb,
    const float* __restrict__ attn_w1, const float* __restrict__ attn_b1,
    const float* __restrict__ attn_w2, const float* __restrict__ attn_b2,
    float* __restrict__ dbuf, float* __restrict__ score, unsigned* __restrict__ menc)
{
    __shared__ alignas(16) float eaT[GG][64];
    __shared__ float dsh[64];
    __shared__ int rsh[64], csh[64];
    __shared__ float parts[64][17];
    const int tid = threadIdx.x;
    const int e0 = blockIdx.x * 64;

    if (tid < 64) {
        const int e = e0 + tid;
        const int r = ei[e], c = ei[EE + e];
        rsh[tid] = r; csh[tid] = c;
        const float dx = pos[r * 3 + 0] - pos[c * 3 + 0];
        const float dy = pos[r * 3 + 1] - pos[c * 3 + 1];
        const float dz = pos[r * 3 + 2] - pos[c * 3 + 2];
        const float d = sqrtf(dx * dx + dy * dy + dz * dz);
        dsh[tid] = d;
        dbuf[e] = d;
    }
    __syncthreads();
    {
        const int e = tid & 63, g0 = tid >> 6;
        const float d = dsh[e];
        for (int g = g0; g < GG; g += 4) {
            const float t = d - g * GSTEP;
            eaT[g][e] = fast_exp2(GC2 * t * t);
        }
    }
    __syncthreads();

    const int te = tid & 15, tj = tid >> 4;
    const float* __restrict__ W1C = attn_w1 + 256 * HH;
    float acc[4][8] = {};
    for (int g = 0; g < GG; g++) {
        const float4 a  = *(const float4*)&eaT[g][te * 4];
        const float4 b0 = *(const float4*)(W1C + g * HH + tj * 8);
        const float4 b1 = *(const float4*)(W1C + g * HH + tj * 8 + 4);
        const float av[4] = {a.x, a.y, a.z, a.w};
#pragma unroll
        for (int i = 0; i < 4; i++) { const float ai = av[i]; FMA8(acc[i], ai, b0, b1); }
    }

    const float4 w20 = *(const float4*)(attn_w2 + tj * 8);
    const float4 w21 = *(const float4*)(attn_w2 + tj * 8 + 4);
    const float4 ab0 = *(const float4*)(attn_b1 + tj * 8);
    const float4 ab1 = *(const float4*)(attn_b1 + tj * 8 + 4);
    const float w2v[8] = {w20.x, w20.y, w20.z, w20.w, w21.x, w21.y, w21.z, w21.w};
    const float b1v[8] = {ab0.x, ab0.y, ab0.z, ab0.w, ab1.x, ab1.y, ab1.z, ab1.w};

#pragma unroll
    for (int i = 0; i < 4; i++) {
        const int le = te * 4 + i;
        const int r = rsh[le], c = csh[le];
        const uint4 uq = *(const uint4*)(ub + (size_t)r * HH + tj * 8);
        const uint4 vq = *(const uint4*)(vb + (size_t)c * HH + tj * 8);
        float uv[8];
        uv[0] = bflo(uq.x) + bflo(vq.x);  uv[1] = bfhi(uq.x) + bfhi(vq.x);
        uv[2] = bflo(uq.y) + bflo(vq.y);  uv[3] = bfhi(uq.y) + bfhi(vq.y);
        uv[4] = bflo(uq.z) + bflo(vq.z);  uv[5] = bfhi(uq.z) + bfhi(vq.z);
        uv[6] = bflo(uq.w) + bflo(vq.w);  uv[7] = bfhi(uq.w) + bfhi(vq.w);
        float pe = 0.0f;
#pragma unroll
        for (int jj = 0; jj < 8; jj++) {
            float z = acc[i][jj] + uv[jj] + b1v[jj];
            z = fmaxf(z, 0.0f);
            pe += z * w2v[jj];
        }
        parts[le][tj] = pe;
    }
    __syncthreads();
    if (tid < 64) {
        float s = attn_b2[0];
#pragma unroll
        for (int t = 0; t < 16; t++) s += parts[tid][t];
        score[e0 + tid] = s;
        const int mode = *flagp;
        if (get_mask(maskp, mode, e0 + tid))
            atomicMax(&menc[rsh[tid]], fenc(s));
    }
}

// ---------------------------------------------------------------------------
// Merged: histogram by dest + masked exp-sum by source (one edge pass).
__global__ void k_prep_edges(const float* __restrict__ score, const int* __restrict__ ei,
                             const void* __restrict__ maskp, const int* __restrict__ flagp,
                             const unsigned* __restrict__ menc,
                             float* __restrict__ ssum, int* __restrict__ count)
{
    const int e = blockIdx.x * 256 + threadIdx.x;
    if (e >= EE) return;
    atomicAdd(&count[ei[EE + e]], 1);
    const int mode = *flagp;
    if (get_mask(maskp, mode, e)) {
        const int r = ei[e];
        const float m = fdec(menc[r]);
        atomicAdd(&ssum[r], fexpf(score[e] - m));
    }
}

// ---------------------------------------------------------------------------
__global__ __launch_bounds__(512) void k_scan(const int* __restrict__ count,
                                              int* __restrict__ offsets,
                                              int* __restrict__ cursor)
{
    __shared__ int s[512];
    const int t = threadIdx.x;
    const int base_i = t * 64;
    int sum = 0;
    for (int i = 0; i < 64; i++) sum += count[base_i + i];
    s[t] = sum;
    __syncthreads();
    for (int off = 1; off < 512; off <<= 1) {
        int v = (t >= off) ? s[t - off] : 0;
        __syncthreads();
        s[t] += v;
        __syncthreads();
    }
    int run = s[t] - sum;   // exclusive prefix
    for (int i = 0; i < 64; i++) {
        offsets[base_i + i] = run;
        cursor[base_i + i] = run;
        run += count[base_i + i];
    }
    if (t == 511) offsets[NN] = run;   // == EE
}

__global__ void k_scatter(const int* __restrict__ ei, int* __restrict__ cursor,
                          int* __restrict__ perm)
{
    const int e = blockIdx.x * 256 + threadIdx.x;
    if (e >= EE) return;
    const int c = ei[EE + e];
    const int pos = atomicAdd(&cursor[c], 1);
    perm[pos] = e;
}

// ---------------------------------------------------------------------------
// MFMA filter MLP on dest-sorted edges + LDS segmented reduction.
// 64 edges/block, 4 waves, ~34KB LDS -> 4 blocks/CU. xh gathered as bf16
// into registers BEFORE the GEMMs (latency hidden under MFMA phases).
// LDS map (32KB main buffer):
//   [0,8K)   EA  bf16[64e][64k]            -> WBh (16KB, restaged 2x)
//   [8,16K)  W1h bf16[64n][64k] (restaged) -> (part of WBh)
//   [16,32K) T1  bf16[64e][128k]
//   [0,32K)  msgb f32[64][128] (+8*g4 col-skew) after GEMM2
__global__ __launch_bounds__(256, 4) void k_filter_mfma(
    const int* __restrict__ ei, const void* __restrict__ maskp, const int* __restrict__ flagp,
    const float* __restrict__ dbuf, const float* __restrict__ score,
    const unsigned* __restrict__ menc, const float* __restrict__ ssum,
    const int* __restrict__ perm,
    const ushort_t* __restrict__ w1t, const float* __restrict__ filt_b1,
    const ushort_t* __restrict__ w2t, const float* __restrict__ filt_b2,
    const ushort_t* __restrict__ xhb, float* __restrict__ agg)
{
    __shared__ alignas(16) unsigned char smem[32768];
    unsigned char* EA = smem;
    unsigned char* W1 = smem + 8192;
    unsigned char* T1 = smem + 16384;
    unsigned char* WB = smem;
    float* msgb = (float*)smem;

    __shared__ float dsh[64], decsh[64], Csh[64];
    __shared__ int rsh[64], csh[64];
    __shared__ int shflags;

    const int tid  = threadIdx.x;
    const int e0   = blockIdx.x * 64;
    const int lane = tid & 63;
    const int wv   = tid >> 6;
    const int col0 = lane & 15;
    const int g4   = lane >> 4;

    // ---- phase A: scalar prep + stage W1 half0 ----
    if (tid < 64) {
        const int pe = perm[e0 + tid];
        const int r = ei[pe];
        rsh[tid] = r;
        csh[tid] = ei[EE + pe];
        const float d = dbuf[pe];
        dsh[tid] = d;
        Csh[tid] = 0.5f * (cosf(d * PI_OVER_CUT) + 1.0f);
        const int mode = *flagp;
        float dec = 1.0f;
        if (get_mask(maskp, mode, pe)) {
            const float m = fdec(menc[r]);
            dec = fexpf(score[pe] - m) / (ssum[r] + 1e-16f);
        }
        decsh[tid] = dec;
    }
    if (tid == 64) {
        const int cfirst = ei[EE + perm[e0]];
        const int clast  = ei[EE + perm[e0 + 63]];
        int f = 0;
        if (e0 > 0 && ei[EE + perm[e0 - 1]] == cfirst) f |= 1;
        if (e0 + 64 < EE && ei[EE + perm[e0 + 64]] == clast) f |= 2;
        shflags = f;
    }
    for (int p = tid; p < 512; p += 256) {       // W1 half0: 8KB
        const int byte = p * 16;
        const int n = byte >> 7;
        *(float4*)(W1 + (byte ^ ((n & 7) << 4))) = *(const float4*)((const char*)w1t + byte);
    }
    __syncthreads();

    // ---- phase B: EA fill + xh register prefetch ----
    {
        const int e = tid & 63, jg = tid >> 6;
        const float d = dsh[e], dec = decsh[e];
        for (int jj = jg; jj < 8; jj += 4) {
            bf16x8 pk;
#pragma unroll
            for (int b = 0; b < 8; b++) {
                const int g = jj * 8 + b;
                float val = 0.0f;
                if (g < GG) { const float t = d - g * GSTEP; val = fast_exp2(GC2 * t * t) * dec; }
                pk[b] = (short)f2bf(val);
            }
            const int byte = e * 128 + jj * 16;
            *(bf16x8*)(EA + (byte ^ ((e & 7) << 4))) = pk;
        }
    }
    int rr[4]; float CC[4];
#pragma unroll
    for (int rg = 0; rg < 4; rg++) {
        const int e = wv * 16 + g4 * 4 + rg;
        rr[rg] = rsh[e];
        CC[rg] = Csh[e];
    }
    ushort_t xr[4][8];                           // issued here, used in epilogue2
#pragma unroll
    for (int rg = 0; rg < 4; rg++)
#pragma unroll
        for (int n = 0; n < 8; n++)
            xr[rg][n] = xhb[(size_t)rr[rg] * HH + n * 16 + col0];
    float b1v[8], b2v[8];
#pragma unroll
    for (int n = 0; n < 8; n++) {
        b1v[n] = filt_b1[n * 16 + col0];
        b2v[n] = filt_b2[n * 16 + col0];
    }
    __syncthreads();

    // ---- GEMM1: T1 = ssp(ea @ w1 + b1), W1 staged in two 8KB halves ----
    const int m = wv * 16 + col0;
    f32x4 acc[8] = {};
#pragma unroll
    for (int h = 0; h < 2; h++) {
        if (h == 1) {
            __syncthreads();
            for (int p = tid; p < 512; p += 256) {
                const int byte = p * 16;
                const int n = byte >> 7;
                *(float4*)(W1 + (byte ^ ((n & 7) << 4))) =
                    *(const float4*)((const char*)w1t + 8192 + byte);
            }
            __syncthreads();
        }
#pragma unroll
        for (int kk = 0; kk < 2; kk++) {
            const int abyte = m * 128 + kk * 64 + g4 * 16;
            const bf16x8 af = *(const bf16x8*)(EA + (abyte ^ ((m & 7) << 4)));
#pragma unroll
            for (int q = 0; q < 4; q++) {
                const int l = q * 16 + col0;
                const int bbyte = l * 128 + kk * 64 + g4 * 16;
                const bf16x8 bf_ = *(const bf16x8*)(W1 + (bbyte ^ ((l & 7) << 4)));
                acc[h * 4 + q] = __builtin_amdgcn_mfma_f32_16x16x32_bf16(af, bf_, acc[h * 4 + q], 0, 0, 0);
            }
        }
    }
    // epilogue1 -> T1 (bf16): lane holds D[row][col=n*16+col0], row=wv*16+g4*4+rg
#pragma unroll
    for (int n = 0; n < 8; n++) {
#pragma unroll
        for (int rg = 0; rg < 4; rg++) {
            const int row = wv * 16 + g4 * 4 + rg;
            const float tv = sspf(acc[n][rg] + b1v[n]);
            const int lbyte = row * 256 + (n * 16 + col0) * 2;   // local offset in T1
            *(ushort_t*)(T1 + (lbyte ^ ((row & 7) << 4))) = f2bf(tv);
        }
    }
    __syncthreads();

    // ---- GEMM2: W = t1 @ w2 + b2, WB staged in two 16KB halves over EA/W1 ----
    f32x4 acc2[8] = {};
#pragma unroll
    for (int h = 0; h < 2; h++) {
        for (int p = tid; p < 1024; p += 256) {
            const int byte = p * 16;
            const int nl = byte >> 8;
            *(float4*)(WB + (byte ^ ((nl & 7) << 4))) =
                *(const float4*)((const char*)w2t + h * 16384 + byte);
        }
        __syncthreads();
#pragma unroll
        for (int kk = 0; kk < 4; kk++) {
            const int abyte = m * 256 + kk * 64 + g4 * 16;
            const bf16x8 af = *(const bf16x8*)(T1 + (abyte ^ ((m & 7) << 4)));
#pragma unroll
            for (int q = 0; q < 4; q++) {
                const int l = q * 16 + col0;
                const int bbyte = l * 256 + kk * 64 + g4 * 16;
                const bf16x8 bf_ = *(const bf16x8*)(WB + (bbyte ^ ((l & 7) << 4)));
                acc2[h * 4 + q] = __builtin_amdgcn_mfma_f32_16x16x32_bf16(af, bf_, acc2[h * 4 + q], 0, 0, 0);
            }
        }
        __syncthreads();   // h0: before restaging WB half1; h1: WB/T1 dead
    }

    // ---- epilogue2: msg = xh[r] * (W+b2) * C -> msgb (skewed, overlay) ----
#pragma unroll
    for (int n = 0; n < 8; n++) {
        const int col = n * 16 + col0;
#pragma unroll
        for (int rg = 0; rg < 4; rg++) {
            const int e = wv * 16 + g4 * 4 + rg;
            const float Wv = (acc2[n][rg] + b2v[n]) * CC[rg];
            const float xv = __uint_as_float(((unsigned)xr[rg][n]) << 16);
            msgb[e * 128 + ((col + 8 * g4) & 127)] = xv * Wv;
        }
    }
    __syncthreads();

    // ---- segmented reduction: 2 halves x 32 edges, all 256 threads ----
    {
        const int q = tid >> 7;          // 0 or 1
        const int j = tid & 127;
        const int base = q * 32;
        const int fl = shflags;
        const int cfirst = csh[base], clast = csh[base + 31];
        const int f1 = (q == 0) ? (fl & 1) : (csh[base - 1] == cfirst);
        const int f2 = (q == 1) ? (fl & 2) : (csh[base + 32] == clast);
        float a = msgb[base * 128 + ((j + 8 * ((base >> 2) & 3)) & 127)];
        int cur = cfirst;
        for (int e = base + 1; e < base + 32; e++) {
            const int de = csh[e];
            if (de != cur) {
                if ((cur == cfirst && f1) || (cur == clast && f2))
                    atomicAdd(&agg[(size_t)cur * HH + j], a);
                else
                    agg[(size_t)cur * HH + j] = a;
                a = 0.0f;
                cur = de;
            }
            a += msgb[e * 128 + ((j + 8 * ((e >> 2) & 3)) & 127)];
        }
        if ((cur == cfirst && f1) || (cur == clast && f2))
            atomicAdd(&agg[(size_t)cur * HH + j], a);
        else
            agg[(size_t)cur * HH + j] = a;
    }
}

// ---------------------------------------------------------------------------
__global__ __launch_bounds__(256) void k_final(
    const float* __restrict__ agg, const float* __restrict__ lin2_w,
    const float* __restrict__ lin2_b, const float* __restrict__ lin_w,
    const float* __restrict__ lin_b, float* __restrict__ out)
{
    __shared__ alignas(16) float AT[HH][68];
    __shared__ alignas(16) float T2T[HH][68];
    const int tid = threadIdx.x;
    const int n0 = blockIdx.x * 64;
    for (int idx = tid; idx < 64 * HH; idx += 256) {
        const int n = idx >> 7, k = idx & 127;
        AT[k][n] = agg[(size_t)(n0 + n) * HH + k];
    }
    __syncthreads();

    const int te = tid & 15, tj = tid >> 4;
    float acc[4][8] = {};
    for (int k = 0; k < HH; k++) {
        const float4 a  = *(const float4*)&AT[k][te * 4];
        const float4 b0 = *(const float4*)(lin2_w + (size_t)k * HH + tj * 8);
        const float4 b1 = *(const float4*)(lin2_w + (size_t)k * HH + tj * 8 + 4);
        const float av[4] = {a.x, a.y, a.z, a.w};
#pragma unroll
        for (int i = 0; i < 4; i++) { const float ai = av[i]; FMA8(acc[i], ai, b0, b1); }
    }
    const float4 l20 = *(const float4*)(lin2_b + tj * 8);
    const float4 l21 = *(const float4*)(lin2_b + tj * 8 + 4);
    const float l2v[8] = {l20.x, l20.y, l20.z, l20.w, l21.x, l21.y, l21.z, l21.w};
#pragma unroll
    for (int jj = 0; jj < 8; jj++) {
        const int j = tj * 8 + jj;
#pragma unroll
        for (int i = 0; i < 4; i++)
            T2T[j][te * 4 + i] = sspf(acc[i][jj] + l2v[jj]);
    }
    __syncthreads();

    float acc2[4][8] = {};
    for (int k = 0; k < HH; k++) {
        const float4 a  = *(const float4*)&T2T[k][te * 4];
        const float4 b0 = *(const float4*)(lin_w + (size_t)k * HH + tj * 8);
        const float4 b1 = *(const float4*)(lin_w + (size_t)k * HH + tj * 8 + 4);
        const float av[4] = {a.x, a.y, a.z, a.w};
#pragma unroll
        for (int i = 0; i < 4; i++) { const float ai = av[i]; FMA8(acc2[i], ai, b0, b1); }
    }
    const float4 lb0 = *(const float4*)(lin_b + tj * 8);
    const float4 lb1 = *(const float4*)(lin_b + tj * 8 + 4);
    const float lbv[8] = {lb0.x, lb0.y, lb0.z, lb0.w, lb1.x, lb1.y, lb1.z, lb1.w};
#pragma unroll
    for (int i = 0; i < 4; i++) {
        float* o = out + (size_t)(n0 + te * 4 + i) * HH + tj * 8;
        float4 r0 = {acc2[i][0] + lbv[0], acc2[i][1] + lbv[1], acc2[i][2] + lbv[2], acc2[i][3] + lbv[3]};
        float4 r1 = {acc2[i][4] + lbv[4], acc2[i][5] + lbv[5], acc2[i][6] + lbv[6], acc2[i][7] + lbv[7]};
        *(float4*)o = r0;
        *(float4*)(o + 4) = r1;
    }
}

// ---------------------------------------------------------------------------
__global__ void k_copy_pos(const float* __restrict__ pos, float* __restrict__ out) {
    const int i = blockIdx.x * 256 + threadIdx.x;
    if (i < NN * 3) out[i] = pos[i];
}

// ---------------------------------------------------------------------------
extern "C" void kernel_launch(void* const* d_in, const int* in_sizes, int n_in,
                              void* d_out, int out_size, void* d_ws, size_t ws_size,
                              hipStream_t stream)
{
    const float* h       = (const float*)d_in[0];
    const float* pos     = (const float*)d_in[1];
    const int*   ei      = (const int*)d_in[2];
    const void*  maskp   = d_in[3];
    const float* attn_w1 = (const float*)d_in[4];
    const float* attn_b1 = (const float*)d_in[5];
    const float* attn_w2 = (const float*)d_in[6];
    const float* attn_b2 = (const float*)d_in[7];
    const float* filt_w1 = (const float*)d_in[8];
    const float* filt_b1 = (const float*)d_in[9];
    const float* filt_w2 = (const float*)d_in[10];
    const float* filt_b2 = (const float*)d_in[11];
    const float* lin1_w  = (const float*)d_in[12];
    const float* lin2_w  = (const float*)d_in[13];
    const float* lin2_b  = (const float*)d_in[14];
    const float* lin_w   = (const float*)d_in[15];
    const float* lin_b   = (const float*)d_in[16];

    char* p = (char*)d_ws;
    auto alloc = [&](size_t bytes) { char* r = p; p += (bytes + 255) & ~(size_t)255; return r; };

    ushort_t* ub    = (ushort_t*)alloc((size_t)NN * HH * 2);
    ushort_t* vb    = (ushort_t*)alloc((size_t)NN * HH * 2);
    ushort_t* xhb   = (ushort_t*)alloc((size_t)NN * HH * 2);
    float*    dbuf  = (float*)alloc((size_t)EE * 4);
    float*    score = (float*)alloc((size_t)EE * 4);
    unsigned* menc  = (unsigned*)alloc((size_t)NN * 4);
    float*    ssum  = (float*)alloc((size_t)NN * 4);
    float*    agg   = (float*)alloc((size_t)NN * HH * 4);
    int*      flag  = (int*)alloc(4);
    ushort_t* w1t   = (ushort_t*)alloc((size_t)128 * 64 * 2);
    ushort_t* w2t   = (ushort_t*)alloc((size_t)128 * 128 * 2);

    int* count   = (int*)ub;                // carved from ub (dead after k_edge_score)
    int* offsets = count + NN;              // NN+1 ints
    int* cursor  = offsets + NN + 64;
    int* perm    = cursor + NN;             // EE ints; 2.43 MB << 8 MB

    float* out_h   = (float*)d_out;
    float* out_pos = out_h + (size_t)NN * HH;

    hipMemsetAsync(menc, 0, NN * sizeof(unsigned), stream);
    hipMemsetAsync(ssum, 0, NN * sizeof(float), stream);

    k_detect<<<1, 256, 0, stream>>>((const unsigned char*)maskp, flag);
    k_prep_w<<<64, 256, 0, stream>>>(filt_w1, filt_w2, w1t, w2t);
    k_node_proj<<<dim3(NN / 64, 3), 256, 0, stream>>>(h, attn_w1, lin1_w, ub, vb, xhb);
    k_edge_score<<<EE / 64, 256, 0, stream>>>(pos, ei, maskp, flag, ub, vb,
                                              attn_w1, attn_b1, attn_w2, attn_b2,
                                              dbuf, score, menc);

    // ub dead from here; build dest-sorted permutation in its space.
    hipMemsetAsync(count, 0, NN * sizeof(int), stream);
    k_prep_edges<<<EE / 256, 256, 0, stream>>>(score, ei, maskp, flag, menc, ssum, count);
    k_scan<<<1, 512, 0, stream>>>(count, offsets, cursor);
    k_scatter<<<EE / 256, 256, 0, stream>>>(ei, cursor, perm);

    hipMemsetAsync(agg, 0, (size_t)NN * HH * sizeof(float), stream);
    k_filter_mfma<<<EE / 64, 256, 0, stream>>>(ei, maskp, flag, dbuf, score, menc, ssum,
                                               perm, w1t, filt_b1, w2t, filt_b2, xhb, agg);

    k_final<<<NN / 64, 256, 0, stream>>>(agg, lin2_w, lin2_b, lin_w, lin_b, out_h);
    k_copy_pos<<<(NN * 3 + 255) / 256, 256, 0, stream>>>(pos, out_pos);
}

// Round 8
// 456.520 us; speedup vs baseline: 4.8360x; 1.0461x over previous
//
#include <hip/hip_runtime.h>

#define NN 32768
#define HH 128
#define GG 50
#define EE 524288

constexpr float GSTEP = 10.0f / 49.0f;
constexpr float GCOEF = -0.5f / (GSTEP * GSTEP);
constexpr float PI_OVER_CUT = 0.31415926535897931f;   // pi / 10
constexpr float LOG2F_ = 0.69314718055994531f;
constexpr float LOG2E_ = 1.4426950408889634f;
constexpr float RLOG2E_ = 0.69314718055994531f;
constexpr float GC2 = GCOEF * LOG2E_;                 // gaussian exp -> exp2

typedef __attribute__((ext_vector_type(8))) short bf16x8;
typedef __attribute__((ext_vector_type(4))) float f32x4;
typedef unsigned short ushort_t;

__device__ __forceinline__ float fast_exp2(float x) {
    float r; asm("v_exp_f32 %0, %1" : "=v"(r) : "v"(x)); return r;
}
__device__ __forceinline__ float fast_log2(float x) {
    float r; asm("v_log_f32 %0, %1" : "=v"(r) : "v"(x)); return r;
}
__device__ __forceinline__ float fexpf(float x) {      // e^x via v_exp_f32
    return fast_exp2(x * LOG2E_);
}
__device__ __forceinline__ float sspf(float x) {       // softplus(x) - log2
    const float p = fast_exp2(x * LOG2E_);
    const float r = RLOG2E_ * fast_log2(1.0f + p) - LOG2F_;
    return (x > 80.0f) ? (x - LOG2F_) : r;
}
__device__ __forceinline__ unsigned fenc(float f) {
    unsigned b = __float_as_uint(f);
    return (b & 0x80000000u) ? ~b : (b | 0x80000000u);
}
__device__ __forceinline__ float fdec(unsigned u) {
    unsigned b = (u & 0x80000000u) ? (u ^ 0x80000000u) : ~u;
    return __uint_as_float(b);
}
__device__ __forceinline__ int get_mask(const void* mp, int mode, int e) {
    if (mode) return ((const unsigned char*)mp)[e] != 0;
    return ((const int*)mp)[e] != 0;
}
__device__ __forceinline__ ushort_t f2bf(float f) {   // RNE f32 -> bf16
    unsigned u = __float_as_uint(f);
    return (ushort_t)((u + 0x7FFFu + ((u >> 16) & 1u)) >> 16);
}
__device__ __forceinline__ float bf2f(ushort_t s) { return __uint_as_float(((unsigned)s) << 16); }
__device__ __forceinline__ float bflo(unsigned q) { return __uint_as_float(q << 16); }
__device__ __forceinline__ float bfhi(unsigned q) { return __uint_as_float(q & 0xFFFF0000u); }

#define FMA8(ACCROW, AV, B0, B1)                                   \
    ACCROW[0] += (AV) * B0.x; ACCROW[1] += (AV) * B0.y;            \
    ACCROW[2] += (AV) * B0.z; ACCROW[3] += (AV) * B0.w;            \
    ACCROW[4] += (AV) * B1.x; ACCROW[5] += (AV) * B1.y;            \
    ACCROW[6] += (AV) * B1.z; ACCROW[7] += (AV) * B1.w;

// ---------------------------------------------------------------------------
__global__ void k_detect(const unsigned char* __restrict__ mb, int* __restrict__ flag) {
    __shared__ int any;
    if (threadIdx.x == 0) any = 0;
    __syncthreads();
    int local = 0;
    for (int i = threadIdx.x; i < 16384; i += blockDim.x)
        if ((i & 3) != 0 && mb[i]) local = 1;
    if (local) atomicOr(&any, 1);
    __syncthreads();
    if (threadIdx.x == 0) *flag = any;   // 1 => byte mode, 0 => int32 mode
}

// ---------------------------------------------------------------------------
// One-time: transpose weights to bf16 [n][k] layouts (k zero-padded).
// w1t[n][g] from filt_w1, w2t[n][k] from filt_w2, w1ct[n][g] from attn_w1 rows 256+.
__global__ void k_prep_w(const float* __restrict__ filt_w1, const float* __restrict__ filt_w2,
                         const float* __restrict__ attn_w1,
                         ushort_t* __restrict__ w1t, ushort_t* __restrict__ w2t,
                         ushort_t* __restrict__ w1ct)
{
    const int t = blockIdx.x * 256 + threadIdx.x;
    if (t < 128 * 64) {                      // w1t[n][g], g padded 50->64
        const int n = t >> 6, g = t & 63;
        const float val = (g < GG) ? filt_w1[g * HH + n] : 0.0f;
        w1t[t] = f2bf(val);
        const float cval = (g < GG) ? attn_w1[(size_t)(256 + g) * HH + n] : 0.0f;
        w1ct[t] = f2bf(cval);
    }
    if (t < 128 * 128) {                     // w2t[n][k]
        const int n = t >> 7, k = t & 127;
        w2t[t] = f2bf(filt_w2[k * HH + n]);
    }
}

// ---------------------------------------------------------------------------
// ub = bf16(h @ attn_w1[0:128]), vb = bf16(h @ attn_w1[128:256]),
// xhb = bf16(h @ lin1_w)
__global__ __launch_bounds__(256) void k_node_proj(
    const float* __restrict__ h, const float* __restrict__ attn_w1,
    const float* __restrict__ lin1_w,
    ushort_t* __restrict__ ub, ushort_t* __restrict__ vb, ushort_t* __restrict__ xhb)
{
    __shared__ alignas(16) float hT[HH][68];
    const int tid = threadIdx.x;
    const int n0 = blockIdx.x * 64;
    const int mat = blockIdx.y;
    const float* __restrict__ W = (mat == 0) ? attn_w1 : (mat == 1 ? attn_w1 + HH * HH : lin1_w);
    ushort_t* __restrict__ out = (mat == 0) ? ub : (mat == 1 ? vb : xhb);

    for (int idx = tid; idx < 64 * HH; idx += 256) {
        const int n = idx >> 7, k = idx & 127;
        hT[k][n] = h[(size_t)(n0 + n) * HH + k];
    }
    __syncthreads();

    const int te = tid & 15, tj = tid >> 4;
    float acc[4][8] = {};
    for (int k = 0; k < HH; k++) {
        const float4 a  = *(const float4*)&hT[k][te * 4];
        const float4 b0 = *(const float4*)(W + (size_t)k * HH + tj * 8);
        const float4 b1 = *(const float4*)(W + (size_t)k * HH + tj * 8 + 4);
        const float av[4] = {a.x, a.y, a.z, a.w};
#pragma unroll
        for (int i = 0; i < 4; i++) { const float ai = av[i]; FMA8(acc[i], ai, b0, b1); }
    }
#pragma unroll
    for (int i = 0; i < 4; i++) {
        unsigned pk[4];
#pragma unroll
        for (int p = 0; p < 4; p++)
            pk[p] = (unsigned)f2bf(acc[i][2 * p]) | ((unsigned)f2bf(acc[i][2 * p + 1]) << 16);
        uint4 r = {pk[0], pk[1], pk[2], pk[3]};
        *(uint4*)(out + (size_t)(n0 + te * 4 + i) * HH + tj * 8) = r;
    }
}

// ---------------------------------------------------------------------------
// Edge scores via MFMA: score = w2 . relu(u[r] + v[c] + ea@W1C + b1) + b2.
// 64 edges/block, 4 waves. u/v prefetched to regs BEFORE the GEMM (T14).
__global__ __launch_bounds__(256, 4) void k_edge_score(
    const float* __restrict__ pos, const int* __restrict__ ei,
    const void* __restrict__ maskp, const int* __restrict__ flagp,
    const ushort_t* __restrict__ ub, const ushort_t* __restrict__ vb,
    const ushort_t* __restrict__ w1ct, const float* __restrict__ attn_b1,
    const float* __restrict__ attn_w2, const float* __restrict__ attn_b2,
    float* __restrict__ dbuf, float* __restrict__ score, unsigned* __restrict__ menc)
{
    __shared__ alignas(16) unsigned char EA[8192];     // bf16[64e][64k], swz ((e&7)<<4)
    __shared__ alignas(16) unsigned char WC[16384];    // bf16[128n][64k], swz ((n&7)<<4)
    __shared__ float dsh[64];
    __shared__ int rsh[64], csh[64];

    const int tid  = threadIdx.x;
    const int e0   = blockIdx.x * 64;
    const int lane = tid & 63;
    const int wv   = tid >> 6;
    const int col0 = lane & 15;
    const int g4   = lane >> 4;

    if (tid < 64) {
        const int e = e0 + tid;
        const int r = ei[e], c = ei[EE + e];
        rsh[tid] = r; csh[tid] = c;
        const float dx = pos[r * 3 + 0] - pos[c * 3 + 0];
        const float dy = pos[r * 3 + 1] - pos[c * 3 + 1];
        const float dz = pos[r * 3 + 2] - pos[c * 3 + 2];
        const float d = sqrtf(dx * dx + dy * dy + dz * dz);
        dsh[tid] = d;
        dbuf[e] = d;
    }
    for (int p = tid; p < 1024; p += 256) {            // stage WC: 16KB
        const int byte = p * 16;
        const int n = byte >> 7;
        *(float4*)(WC + (byte ^ ((n & 7) << 4))) = *(const float4*)((const char*)w1ct + byte);
    }
    __syncthreads();

    // u/v register prefetch (consumed in epilogue; hidden under EA fill + GEMM)
    int rrv[4], ccv[4];
#pragma unroll
    for (int rg = 0; rg < 4; rg++) {
        const int e = wv * 16 + g4 * 4 + rg;
        rrv[rg] = rsh[e];
        ccv[rg] = csh[e];
    }
    ushort_t ur[4][8], vr[4][8];
#pragma unroll
    for (int rg = 0; rg < 4; rg++)
#pragma unroll
        for (int n = 0; n < 8; n++) {
            ur[rg][n] = ub[(size_t)rrv[rg] * HH + n * 16 + col0];
            vr[rg][n] = vb[(size_t)ccv[rg] * HH + n * 16 + col0];
        }

    // EA fill (bf16 gaussians, no decay here)
    {
        const int e = tid & 63, jg = tid >> 6;
        const float d = dsh[e];
        for (int jj = jg; jj < 8; jj += 4) {
            bf16x8 pk;
#pragma unroll
            for (int b = 0; b < 8; b++) {
                const int g = jj * 8 + b;
                float val = 0.0f;
                if (g < GG) { const float t = d - g * GSTEP; val = fast_exp2(GC2 * t * t); }
                pk[b] = (short)f2bf(val);
            }
            const int byte = e * 128 + jj * 16;
            *(bf16x8*)(EA + (byte ^ ((e & 7) << 4))) = pk;
        }
    }
    float b1v[8], w2v[8];
#pragma unroll
    for (int n = 0; n < 8; n++) {
        b1v[n] = attn_b1[n * 16 + col0];
        w2v[n] = attn_w2[n * 16 + col0];
    }
    __syncthreads();

    // GEMM: acc[n] = (ea @ W1C) fragment
    const int m = wv * 16 + col0;
    f32x4 acc[8] = {};
#pragma unroll
    for (int kk = 0; kk < 2; kk++) {
        const int abyte = m * 128 + kk * 64 + g4 * 16;
        const bf16x8 af = *(const bf16x8*)(EA + (abyte ^ ((m & 7) << 4)));
#pragma unroll
        for (int n = 0; n < 8; n++) {
            const int l = n * 16 + col0;
            const int bbyte = l * 128 + kk * 64 + g4 * 16;
            const bf16x8 bf_ = *(const bf16x8*)(WC + (bbyte ^ ((l & 7) << 4)));
            acc[n] = __builtin_amdgcn_mfma_f32_16x16x32_bf16(af, bf_, acc[n], 0, 0, 0);
        }
    }

    // epilogue: relu + dot(w2) per lane, then 16-lane shfl reduce per edge row
    float pe[4] = {0.0f, 0.0f, 0.0f, 0.0f};
#pragma unroll
    for (int n = 0; n < 8; n++) {
#pragma unroll
        for (int rg = 0; rg < 4; rg++) {
            float z = acc[n][rg] + bf2f(ur[rg][n]) + bf2f(vr[rg][n]) + b1v[n];
            z = fmaxf(z, 0.0f);
            pe[rg] += z * w2v[n];
        }
    }
#pragma unroll
    for (int mask = 1; mask <= 8; mask <<= 1) {
#pragma unroll
        for (int rg = 0; rg < 4; rg++)
            pe[rg] += __shfl_xor(pe[rg], mask, 64);
    }
    if (col0 == 0) {
        const float b2 = attn_b2[0];
        const int mode = *flagp;
#pragma unroll
        for (int rg = 0; rg < 4; rg++) {
            const int e = wv * 16 + g4 * 4 + rg;
            const float s = pe[rg] + b2;
            score[e0 + e] = s;
            if (get_mask(maskp, mode, e0 + e))
                atomicMax(&menc[rsh[e]], fenc(s));
        }
    }
}

// ---------------------------------------------------------------------------
// Merged: histogram by dest + masked exp-sum by source (one edge pass).
__global__ void k_prep_edges(const float* __restrict__ score, const int* __restrict__ ei,
                             const void* __restrict__ maskp, const int* __restrict__ flagp,
                             const unsigned* __restrict__ menc,
                             float* __restrict__ ssum, int* __restrict__ count)
{
    const int e = blockIdx.x * 256 + threadIdx.x;
    if (e >= EE) return;
    atomicAdd(&count[ei[EE + e]], 1);
    const int mode = *flagp;
    if (get_mask(maskp, mode, e)) {
        const int r = ei[e];
        const float m = fdec(menc[r]);
        atomicAdd(&ssum[r], fexpf(score[e] - m));
    }
}

// ---------------------------------------------------------------------------
__global__ __launch_bounds__(512) void k_scan(const int* __restrict__ count,
                                              int* __restrict__ offsets,
                                              int* __restrict__ cursor)
{
    __shared__ int s[512];
    const int t = threadIdx.x;
    const int base_i = t * 64;
    int sum = 0;
    for (int i = 0; i < 64; i++) sum += count[base_i + i];
    s[t] = sum;
    __syncthreads();
    for (int off = 1; off < 512; off <<= 1) {
        int v = (t >= off) ? s[t - off] : 0;
        __syncthreads();
        s[t] += v;
        __syncthreads();
    }
    int run = s[t] - sum;   // exclusive prefix
    for (int i = 0; i < 64; i++) {
        offsets[base_i + i] = run;
        cursor[base_i + i] = run;
        run += count[base_i + i];
    }
    if (t == 511) offsets[NN] = run;   // == EE
}

__global__ void k_scatter(const int* __restrict__ ei, int* __restrict__ cursor,
                          int* __restrict__ perm)
{
    const int e = blockIdx.x * 256 + threadIdx.x;
    if (e >= EE) return;
    const int c = ei[EE + e];
    const int pos = atomicAdd(&cursor[c], 1);
    perm[pos] = e;
}

// ---------------------------------------------------------------------------
// MFMA filter MLP on dest-sorted edges + LDS segmented reduction.
__global__ __launch_bounds__(256, 4) void k_filter_mfma(
    const int* __restrict__ ei, const void* __restrict__ maskp, const int* __restrict__ flagp,
    const float* __restrict__ dbuf, const float* __restrict__ score,
    const unsigned* __restrict__ menc, const float* __restrict__ ssum,
    const int* __restrict__ perm,
    const ushort_t* __restrict__ w1t, const float* __restrict__ filt_b1,
    const ushort_t* __restrict__ w2t, const float* __restrict__ filt_b2,
    const ushort_t* __restrict__ xhb, float* __restrict__ agg)
{
    __shared__ alignas(16) unsigned char smem[32768];
    unsigned char* EA = smem;
    unsigned char* W1 = smem + 8192;
    unsigned char* T1 = smem + 16384;
    unsigned char* WB = smem;
    float* msgb = (float*)smem;

    __shared__ float dsh[64], decsh[64], Csh[64];
    __shared__ int rsh[64], csh[64];
    __shared__ int shflags;

    const int tid  = threadIdx.x;
    const int e0   = blockIdx.x * 64;
    const int lane = tid & 63;
    const int wv   = tid >> 6;
    const int col0 = lane & 15;
    const int g4   = lane >> 4;

    // ---- phase A: scalar prep + stage W1 half0 ----
    if (tid < 64) {
        const int pe = perm[e0 + tid];
        const int r = ei[pe];
        rsh[tid] = r;
        csh[tid] = ei[EE + pe];
        const float d = dbuf[pe];
        dsh[tid] = d;
        Csh[tid] = 0.5f * (cosf(d * PI_OVER_CUT) + 1.0f);
        const int mode = *flagp;
        float dec = 1.0f;
        if (get_mask(maskp, mode, pe)) {
            const float m = fdec(menc[r]);
            dec = fexpf(score[pe] - m) / (ssum[r] + 1e-16f);
        }
        decsh[tid] = dec;
    }
    if (tid == 64) {
        const int cfirst = ei[EE + perm[e0]];
        const int clast  = ei[EE + perm[e0 + 63]];
        int f = 0;
        if (e0 > 0 && ei[EE + perm[e0 - 1]] == cfirst) f |= 1;
        if (e0 + 64 < EE && ei[EE + perm[e0 + 64]] == clast) f |= 2;
        shflags = f;
    }
    for (int p = tid; p < 512; p += 256) {       // W1 half0: 8KB
        const int byte = p * 16;
        const int n = byte >> 7;
        *(float4*)(W1 + (byte ^ ((n & 7) << 4))) = *(const float4*)((const char*)w1t + byte);
    }
    __syncthreads();

    // ---- phase B: EA fill + xh register prefetch ----
    {
        const int e = tid & 63, jg = tid >> 6;
        const float d = dsh[e], dec = decsh[e];
        for (int jj = jg; jj < 8; jj += 4) {
            bf16x8 pk;
#pragma unroll
            for (int b = 0; b < 8; b++) {
                const int g = jj * 8 + b;
                float val = 0.0f;
                if (g < GG) { const float t = d - g * GSTEP; val = fast_exp2(GC2 * t * t) * dec; }
                pk[b] = (short)f2bf(val);
            }
            const int byte = e * 128 + jj * 16;
            *(bf16x8*)(EA + (byte ^ ((e & 7) << 4))) = pk;
        }
    }
    int rr[4]; float CC[4];
#pragma unroll
    for (int rg = 0; rg < 4; rg++) {
        const int e = wv * 16 + g4 * 4 + rg;
        rr[rg] = rsh[e];
        CC[rg] = Csh[e];
    }
    ushort_t xr[4][8];                           // issued here, used in epilogue2
#pragma unroll
    for (int rg = 0; rg < 4; rg++)
#pragma unroll
        for (int n = 0; n < 8; n++)
            xr[rg][n] = xhb[(size_t)rr[rg] * HH + n * 16 + col0];
    float b1v[8], b2v[8];
#pragma unroll
    for (int n = 0; n < 8; n++) {
        b1v[n] = filt_b1[n * 16 + col0];
        b2v[n] = filt_b2[n * 16 + col0];
    }
    __syncthreads();

    // ---- GEMM1: T1 = ssp(ea @ w1 + b1), W1 staged in two 8KB halves ----
    const int m = wv * 16 + col0;
    f32x4 acc[8] = {};
#pragma unroll
    for (int h = 0; h < 2; h++) {
        if (h == 1) {
            __syncthreads();
            for (int p = tid; p < 512; p += 256) {
                const int byte = p * 16;
                const int n = byte >> 7;
                *(float4*)(W1 + (byte ^ ((n & 7) << 4))) =
                    *(const float4*)((const char*)w1t + 8192 + byte);
            }
            __syncthreads();
        }
#pragma unroll
        for (int kk = 0; kk < 2; kk++) {
            const int abyte = m * 128 + kk * 64 + g4 * 16;
            const bf16x8 af = *(const bf16x8*)(EA + (abyte ^ ((m & 7) << 4)));
#pragma unroll
            for (int q = 0; q < 4; q++) {
                const int l = q * 16 + col0;
                const int bbyte = l * 128 + kk * 64 + g4 * 16;
                const bf16x8 bf_ = *(const bf16x8*)(W1 + (bbyte ^ ((l & 7) << 4)));
                acc[h * 4 + q] = __builtin_amdgcn_mfma_f32_16x16x32_bf16(af, bf_, acc[h * 4 + q], 0, 0, 0);
            }
        }
    }
    // epilogue1 -> T1 (bf16): lane holds D[row][col=n*16+col0], row=wv*16+g4*4+rg
#pragma unroll
    for (int n = 0; n < 8; n++) {
#pragma unroll
        for (int rg = 0; rg < 4; rg++) {
            const int row = wv * 16 + g4 * 4 + rg;
            const float tv = sspf(acc[n][rg] + b1v[n]);
            const int lbyte = row * 256 + (n * 16 + col0) * 2;   // local offset in T1
            *(ushort_t*)(T1 + (lbyte ^ ((row & 7) << 4))) = f2bf(tv);
        }
    }
    __syncthreads();

    // ---- GEMM2: W = t1 @ w2 + b2, WB staged in two 16KB halves over EA/W1 ----
    f32x4 acc2[8] = {};
#pragma unroll
    for (int h = 0; h < 2; h++) {
        for (int p = tid; p < 1024; p += 256) {
            const int byte = p * 16;
            const int nl = byte >> 8;
            *(float4*)(WB + (byte ^ ((nl & 7) << 4))) =
                *(const float4*)((const char*)w2t + h * 16384 + byte);
        }
        __syncthreads();
#pragma unroll
        for (int kk = 0; kk < 4; kk++) {
            const int abyte = m * 256 + kk * 64 + g4 * 16;
            const bf16x8 af = *(const bf16x8*)(T1 + (abyte ^ ((m & 7) << 4)));
#pragma unroll
            for (int q = 0; q < 4; q++) {
                const int l = q * 16 + col0;
                const int bbyte = l * 256 + kk * 64 + g4 * 16;
                const bf16x8 bf_ = *(const bf16x8*)(WB + (bbyte ^ ((l & 7) << 4)));
                acc2[h * 4 + q] = __builtin_amdgcn_mfma_f32_16x16x32_bf16(af, bf_, acc2[h * 4 + q], 0, 0, 0);
            }
        }
        __syncthreads();   // h0: before restaging WB half1; h1: WB/T1 dead
    }

    // ---- epilogue2: msg = xh[r] * (W+b2) * C -> msgb (skewed, overlay) ----
#pragma unroll
    for (int n = 0; n < 8; n++) {
        const int col = n * 16 + col0;
#pragma unroll
        for (int rg = 0; rg < 4; rg++) {
            const int e = wv * 16 + g4 * 4 + rg;
            const float Wv = (acc2[n][rg] + b2v[n]) * CC[rg];
            const float xv = __uint_as_float(((unsigned)xr[rg][n]) << 16);
            msgb[e * 128 + ((col + 8 * g4) & 127)] = xv * Wv;
        }
    }
    __syncthreads();

    // ---- segmented reduction: 2 halves x 32 edges, all 256 threads ----
    {
        const int q = tid >> 7;          // 0 or 1
        const int j = tid & 127;
        const int base = q * 32;
        const int fl = shflags;
        const int cfirst = csh[base], clast = csh[base + 31];
        const int f1 = (q == 0) ? (fl & 1) : (csh[base - 1] == cfirst);
        const int f2 = (q == 1) ? (fl & 2) : (csh[base + 32] == clast);
        float a = msgb[base * 128 + ((j + 8 * ((base >> 2) & 3)) & 127)];
        int cur = cfirst;
        for (int e = base + 1; e < base + 32; e++) {
            const int de = csh[e];
            if (de != cur) {
                if ((cur == cfirst && f1) || (cur == clast && f2))
                    atomicAdd(&agg[(size_t)cur * HH + j], a);
                else
                    agg[(size_t)cur * HH + j] = a;
                a = 0.0f;
                cur = de;
            }
            a += msgb[e * 128 + ((j + 8 * ((e >> 2) & 3)) & 127)];
        }
        if ((cur == cfirst && f1) || (cur == clast && f2))
            atomicAdd(&agg[(size_t)cur * HH + j], a);
        else
            agg[(size_t)cur * HH + j] = a;
    }
}

// ---------------------------------------------------------------------------
__global__ __launch_bounds__(256) void k_final(
    const float* __restrict__ agg, const float* __restrict__ lin2_w,
    const float* __restrict__ lin2_b, const float* __restrict__ lin_w,
    const float* __restrict__ lin_b, float* __restrict__ out)
{
    __shared__ alignas(16) float AT[HH][68];
    __shared__ alignas(16) float T2T[HH][68];
    const int tid = threadIdx.x;
    const int n0 = blockIdx.x * 64;
    for (int idx = tid; idx < 64 * HH; idx += 256) {
        const int n = idx >> 7, k = idx & 127;
        AT[k][n] = agg[(size_t)(n0 + n) * HH + k];
    }
    __syncthreads();

    const int te = tid & 15, tj = tid >> 4;
    float acc[4][8] = {};
    for (int k = 0; k < HH; k++) {
        const float4 a  = *(const float4*)&AT[k][te * 4];
        const float4 b0 = *(const float4*)(lin2_w + (size_t)k * HH + tj * 8);
        const float4 b1 = *(const float4*)(lin2_w + (size_t)k * HH + tj * 8 + 4);
        const float av[4] = {a.x, a.y, a.z, a.w};
#pragma unroll
        for (int i = 0; i < 4; i++) { const float ai = av[i]; FMA8(acc[i], ai, b0, b1); }
    }
    const float4 l20 = *(const float4*)(lin2_b + tj * 8);
    const float4 l21 = *(const float4*)(lin2_b + tj * 8 + 4);
    const float l2v[8] = {l20.x, l20.y, l20.z, l20.w, l21.x, l21.y, l21.z, l21.w};
#pragma unroll
    for (int jj = 0; jj < 8; jj++) {
        const int j = tj * 8 + jj;
#pragma unroll
        for (int i = 0; i < 4; i++)
            T2T[j][te * 4 + i] = sspf(acc[i][jj] + l2v[jj]);
    }
    __syncthreads();

    float acc2[4][8] = {};
    for (int k = 0; k < HH; k++) {
        const float4 a  = *(const float4*)&T2T[k][te * 4];
        const float4 b0 = *(const float4*)(lin_w + (size_t)k * HH + tj * 8);
        const float4 b1 = *(const float4*)(lin_w + (size_t)k * HH + tj * 8 + 4);
        const float av[4] = {a.x, a.y, a.z, a.w};
#pragma unroll
        for (int i = 0; i < 4; i++) { const float ai = av[i]; FMA8(acc2[i], ai, b0, b1); }
    }
    const float4 lb0 = *(const float4*)(lin_b + tj * 8);
    const float4 lb1 = *(const float4*)(lin_b + tj * 8 + 4);
    const float lbv[8] = {lb0.x, lb0.y, lb0.z, lb0.w, lb1.x, lb1.y, lb1.z, lb1.w};
#pragma unroll
    for (int i = 0; i < 4; i++) {
        float* o = out + (size_t)(n0 + te * 4 + i) * HH + tj * 8;
        float4 r0 = {acc2[i][0] + lbv[0], acc2[i][1] + lbv[1], acc2[i][2] + lbv[2], acc2[i][3] + lbv[3]};
        float4 r1 = {acc2[i][4] + lbv[4], acc2[i][5] + lbv[5], acc2[i][6] + lbv[6], acc2[i][7] + lbv[7]};
        *(float4*)o = r0;
        *(float4*)(o + 4) = r1;
    }
}

// ---------------------------------------------------------------------------
__global__ void k_copy_pos(const float* __restrict__ pos, float* __restrict__ out) {
    const int i = blockIdx.x * 256 + threadIdx.x;
    if (i < NN * 3) out[i] = pos[i];
}

// ---------------------------------------------------------------------------
extern "C" void kernel_launch(void* const* d_in, const int* in_sizes, int n_in,
                              void* d_out, int out_size, void* d_ws, size_t ws_size,
                              hipStream_t stream)
{
    const float* h       = (const float*)d_in[0];
    const float* pos     = (const float*)d_in[1];
    const int*   ei      = (const int*)d_in[2];
    const void*  maskp   = d_in[3];
    const float* attn_w1 = (const float*)d_in[4];
    const float* attn_b1 = (const float*)d_in[5];
    const float* attn_w2 = (const float*)d_in[6];
    const float* attn_b2 = (const float*)d_in[7];
    const float* filt_w1 = (const float*)d_in[8];
    const float* filt_b1 = (const float*)d_in[9];
    const float* filt_w2 = (const float*)d_in[10];
    const float* filt_b2 = (const float*)d_in[11];
    const float* lin1_w  = (const float*)d_in[12];
    const float* lin2_w  = (const float*)d_in[13];
    const float* lin2_b  = (const float*)d_in[14];
    const float* lin_w   = (const float*)d_in[15];
    const float* lin_b   = (const float*)d_in[16];

    char* p = (char*)d_ws;
    auto alloc = [&](size_t bytes) { char* r = p; p += (bytes + 255) & ~(size_t)255; return r; };

    ushort_t* ub    = (ushort_t*)alloc((size_t)NN * HH * 2);
    ushort_t* vb    = (ushort_t*)alloc((size_t)NN * HH * 2);
    ushort_t* xhb   = (ushort_t*)alloc((size_t)NN * HH * 2);
    float*    dbuf  = (float*)alloc((size_t)EE * 4);
    float*    score = (float*)alloc((size_t)EE * 4);
    unsigned* menc  = (unsigned*)alloc((size_t)NN * 4);
    float*    ssum  = (float*)alloc((size_t)NN * 4);
    float*    agg   = (float*)alloc((size_t)NN * HH * 4);
    int*      flag  = (int*)alloc(4);
    ushort_t* w1t   = (ushort_t*)alloc((size_t)128 * 64 * 2);
    ushort_t* w2t   = (ushort_t*)alloc((size_t)128 * 128 * 2);
    ushort_t* w1ct  = (ushort_t*)alloc((size_t)128 * 64 * 2);

    int* count   = (int*)ub;                // carved from ub (dead after k_edge_score)
    int* offsets = count + NN;              // NN+1 ints
    int* cursor  = offsets + NN + 64;
    int* perm    = cursor + NN;             // EE ints

    float* out_h   = (float*)d_out;
    float* out_pos = out_h + (size_t)NN * HH;

    hipMemsetAsync(menc, 0, NN * sizeof(unsigned), stream);
    hipMemsetAsync(ssum, 0, NN * sizeof(float), stream);

    k_detect<<<1, 256, 0, stream>>>((const unsigned char*)maskp, flag);
    k_prep_w<<<64, 256, 0, stream>>>(filt_w1, filt_w2, attn_w1, w1t, w2t, w1ct);
    k_node_proj<<<dim3(NN / 64, 3), 256, 0, stream>>>(h, attn_w1, lin1_w, ub, vb, xhb);
    k_edge_score<<<EE / 64, 256, 0, stream>>>(pos, ei, maskp, flag, ub, vb,
                                              w1ct, attn_b1, attn_w2, attn_b2,
                                              dbuf, score, menc);

    // ub dead from here; build dest-sorted permutation in its space.
    hipMemsetAsync(count, 0, NN * sizeof(int), stream);
    k_prep_edges<<<EE / 256, 256, 0, stream>>>(score, ei, maskp, flag, menc, ssum, count);
    k_scan<<<1, 512, 0, stream>>>(count, offsets, cursor);
    k_scatter<<<EE / 256, 256, 0, stream>>>(ei, cursor, perm);

    hipMemsetAsync(agg, 0, (size_t)NN * HH * sizeof(float), stream);
    k_filter_mfma<<<EE / 64, 256, 0, stream>>>(ei, maskp, flag, dbuf, score, menc, ssum,
                                               perm, w1t, filt_b1, w2t, filt_b2, xhb, agg);

    k_final<<<NN / 64, 256, 0, stream>>>(agg, lin2_w, lin2_b, lin_w, lin_b, out_h);
    k_copy_pos<<<(NN * 3 + 255) / 256, 256, 0, stream>>>(pos, out_pos);
}

// Round 9
// 350.668 us; speedup vs baseline: 6.2958x; 1.3019x over previous
//
#include <hip/hip_runtime.h>

#define NN 32768
#define HH 128
#define GG 50
#define EE 524288

constexpr float GSTEP = 10.0f / 49.0f;
constexpr float GCOEF = -0.5f / (GSTEP * GSTEP);
constexpr float PI_OVER_CUT = 0.31415926535897931f;   // pi / 10
constexpr float LOG2F_ = 0.69314718055994531f;
constexpr float LOG2E_ = 1.4426950408889634f;
constexpr float RLOG2E_ = 0.69314718055994531f;
constexpr float GC2 = GCOEF * LOG2E_;                 // gaussian exp -> exp2

typedef __attribute__((ext_vector_type(8))) short bf16x8;
typedef __attribute__((ext_vector_type(4))) float f32x4;
typedef unsigned short ushort_t;

__device__ __forceinline__ float fast_exp2(float x) {
    float r; asm("v_exp_f32 %0, %1" : "=v"(r) : "v"(x)); return r;
}
__device__ __forceinline__ float fast_log2(float x) {
    float r; asm("v_log_f32 %0, %1" : "=v"(r) : "v"(x)); return r;
}
__device__ __forceinline__ float fexpf(float x) {      // e^x via v_exp_f32
    return fast_exp2(x * LOG2E_);
}
__device__ __forceinline__ float sspf(float x) {       // softplus(x) - log2
    const float p = fast_exp2(x * LOG2E_);
    const float r = RLOG2E_ * fast_log2(1.0f + p) - LOG2F_;
    return (x > 80.0f) ? (x - LOG2F_) : r;
}
__device__ __forceinline__ unsigned fenc(float f) {
    unsigned b = __float_as_uint(f);
    return (b & 0x80000000u) ? ~b : (b | 0x80000000u);
}
__device__ __forceinline__ float fdec(unsigned u) {
    unsigned b = (u & 0x80000000u) ? (u ^ 0x80000000u) : ~u;
    return __uint_as_float(b);
}
__device__ __forceinline__ int get_mask(const void* mp, int mode, int e) {
    if (mode) return ((const unsigned char*)mp)[e] != 0;
    return ((const int*)mp)[e] != 0;
}
__device__ __forceinline__ ushort_t f2bf(float f) {   // RNE f32 -> bf16
    unsigned u = __float_as_uint(f);
    return (ushort_t)((u + 0x7FFFu + ((u >> 16) & 1u)) >> 16);
}
__device__ __forceinline__ float bf2f(ushort_t s) { return __uint_as_float(((unsigned)s) << 16); }

// ---------------------------------------------------------------------------
__global__ void k_detect(const unsigned char* __restrict__ mb, int* __restrict__ flag) {
    __shared__ int any;
    if (threadIdx.x == 0) any = 0;
    __syncthreads();
    int local = 0;
    for (int i = threadIdx.x; i < 16384; i += blockDim.x)
        if ((i & 3) != 0 && mb[i]) local = 1;
    if (local) atomicOr(&any, 1);
    __syncthreads();
    if (threadIdx.x == 0) *flag = any;   // 1 => byte mode, 0 => int32 mode
}

// ---------------------------------------------------------------------------
// One-time: transpose all weights to bf16 [n][k] layouts (k zero-padded).
__global__ void k_prep_w(const float* __restrict__ filt_w1, const float* __restrict__ filt_w2,
                         const float* __restrict__ attn_w1, const float* __restrict__ lin1_w,
                         const float* __restrict__ lin2_w, const float* __restrict__ lin_w,
                         ushort_t* __restrict__ w1t, ushort_t* __restrict__ w1ct,
                         ushort_t* __restrict__ w2t, ushort_t* __restrict__ wut,
                         ushort_t* __restrict__ wvt, ushort_t* __restrict__ wxt,
                         ushort_t* __restrict__ l2t, ushort_t* __restrict__ lwt)
{
    const int t = blockIdx.x * 256 + threadIdx.x;
    if (t < 8192) {                          // w1t[n][g], g padded 50->64
        const int n = t >> 6, g = t & 63;
        w1t[t] = f2bf((g < GG) ? filt_w1[g * HH + n] : 0.0f);
    } else if (t < 16384) {                  // w1ct[n][g]
        const int i = t - 8192, n = i >> 6, g = i & 63;
        w1ct[i] = f2bf((g < GG) ? attn_w1[(size_t)(256 + g) * HH + n] : 0.0f);
    } else if (t < 32768) {                  // w2t[n][k]
        const int i = t - 16384, n = i >> 7, k = i & 127;
        w2t[i] = f2bf(filt_w2[k * HH + n]);
    } else if (t < 49152) {                  // wut[n][k] = attn_w1 rows 0..127
        const int i = t - 32768, n = i >> 7, k = i & 127;
        wut[i] = f2bf(attn_w1[(size_t)k * HH + n]);
    } else if (t < 65536) {                  // wvt[n][k] = attn_w1 rows 128..255
        const int i = t - 49152, n = i >> 7, k = i & 127;
        wvt[i] = f2bf(attn_w1[(size_t)(128 + k) * HH + n]);
    } else if (t < 81920) {                  // wxt[n][k] = lin1_w
        const int i = t - 65536, n = i >> 7, k = i & 127;
        wxt[i] = f2bf(lin1_w[(size_t)k * HH + n]);
    } else if (t < 98304) {                  // l2t[n][k] = lin2_w
        const int i = t - 81920, n = i >> 7, k = i & 127;
        l2t[i] = f2bf(lin2_w[(size_t)k * HH + n]);
    } else if (t < 114688) {                 // lwt[n][k] = lin_w
        const int i = t - 98304, n = i >> 7, k = i & 127;
        lwt[i] = f2bf(lin_w[(size_t)k * HH + n]);
    }
}

// ---------------------------------------------------------------------------
// MFMA node projections: out = bf16(h @ W) for W in {attn_u, attn_v, lin1}.
__global__ __launch_bounds__(256, 4) void k_node_proj(
    const float* __restrict__ h,
    const ushort_t* __restrict__ wut, const ushort_t* __restrict__ wvt,
    const ushort_t* __restrict__ wxt,
    ushort_t* __restrict__ ub, ushort_t* __restrict__ vb, ushort_t* __restrict__ xhb)
{
    __shared__ alignas(16) unsigned char smem[32768];
    unsigned char* HB = smem;          // bf16[64][128], swz ((row&7)<<4)
    unsigned char* WB = smem + 16384;  // bf16[64n][128k] half, swz ((n&7)<<4)

    const int tid = threadIdx.x;
    const int n0 = blockIdx.x * 64;
    const int mat = blockIdx.y;
    const ushort_t* __restrict__ wt = (mat == 0) ? wut : (mat == 1 ? wvt : wxt);
    ushort_t* __restrict__ out = (mat == 0) ? ub : (mat == 1 ? vb : xhb);

    for (int p = tid; p < 2048; p += 256) {        // stage HB (f32 -> bf16)
        const int row = p >> 5, c4 = p & 31;
        const float4 v = *(const float4*)(h + (size_t)(n0 + row) * HH + c4 * 4);
        uint2 pk = {(unsigned)f2bf(v.x) | ((unsigned)f2bf(v.y) << 16),
                    (unsigned)f2bf(v.z) | ((unsigned)f2bf(v.w) << 16)};
        const int lbyte = row * 256 + c4 * 8;
        *(uint2*)(HB + (lbyte ^ ((row & 7) << 4))) = pk;
    }
    for (int p = tid; p < 1024; p += 256) {        // stage WB half0
        const int byte = p * 16; const int nl = byte >> 8;
        *(float4*)(WB + (byte ^ ((nl & 7) << 4))) = *(const float4*)((const char*)wt + byte);
    }
    __syncthreads();

    const int lane = tid & 63, wv = tid >> 6, col0 = lane & 15, g4 = lane >> 4;
    const int m = wv * 16 + col0;
    f32x4 acc[8] = {};
#pragma unroll
    for (int hh2 = 0; hh2 < 2; hh2++) {
        if (hh2 == 1) {
            __syncthreads();
            for (int p = tid; p < 1024; p += 256) {
                const int byte = p * 16; const int nl = byte >> 8;
                *(float4*)(WB + (byte ^ ((nl & 7) << 4))) =
                    *(const float4*)((const char*)wt + 16384 + byte);
            }
            __syncthreads();
        }
#pragma unroll
        for (int kk = 0; kk < 4; kk++) {
            const int abyte = m * 256 + kk * 64 + g4 * 16;
            const bf16x8 af = *(const bf16x8*)(HB + (abyte ^ ((m & 7) << 4)));
#pragma unroll
            for (int q = 0; q < 4; q++) {
                const int l = q * 16 + col0;
                const int bbyte = l * 256 + kk * 64 + g4 * 16;
                const bf16x8 bf_ = *(const bf16x8*)(WB + (bbyte ^ ((l & 7) << 4)));
                acc[hh2 * 4 + q] = __builtin_amdgcn_mfma_f32_16x16x32_bf16(af, bf_, acc[hh2 * 4 + q], 0, 0, 0);
            }
        }
    }
#pragma unroll
    for (int f = 0; f < 8; f++) {
        const int col = (f >> 2) * 64 + (f & 3) * 16 + col0;
#pragma unroll
        for (int rg = 0; rg < 4; rg++) {
            const int row = wv * 16 + g4 * 4 + rg;
            out[(size_t)(n0 + row) * HH + col] = f2bf(acc[f][rg]);
        }
    }
}

// ---------------------------------------------------------------------------
// Edge scores via MFMA + dest histogram.
__global__ __launch_bounds__(256, 4) void k_edge_score(
    const float* __restrict__ pos, const int* __restrict__ ei,
    const void* __restrict__ maskp, const int* __restrict__ flagp,
    const ushort_t* __restrict__ ub, const ushort_t* __restrict__ vb,
    const ushort_t* __restrict__ w1ct, const float* __restrict__ attn_b1,
    const float* __restrict__ attn_w2, const float* __restrict__ attn_b2,
    float* __restrict__ dbuf, float* __restrict__ score, unsigned* __restrict__ menc,
    int* __restrict__ count)
{
    __shared__ alignas(16) unsigned char EA[8192];     // bf16[64e][64k], swz ((e&7)<<4)
    __shared__ alignas(16) unsigned char WC[16384];    // bf16[128n][64k], swz ((n&7)<<4)
    __shared__ float dsh[64];
    __shared__ int rsh[64], csh[64];

    const int tid  = threadIdx.x;
    const int e0   = blockIdx.x * 64;
    const int lane = tid & 63;
    const int wv   = tid >> 6;
    const int col0 = lane & 15;
    const int g4   = lane >> 4;

    if (tid < 64) {
        const int e = e0 + tid;
        const int r = ei[e], c = ei[EE + e];
        rsh[tid] = r; csh[tid] = c;
        atomicAdd(&count[c], 1);
        const float dx = pos[r * 3 + 0] - pos[c * 3 + 0];
        const float dy = pos[r * 3 + 1] - pos[c * 3 + 1];
        const float dz = pos[r * 3 + 2] - pos[c * 3 + 2];
        const float d = sqrtf(dx * dx + dy * dy + dz * dz);
        dsh[tid] = d;
        dbuf[e] = d;
    }
    for (int p = tid; p < 1024; p += 256) {            // stage WC: 16KB
        const int byte = p * 16;
        const int n = byte >> 7;
        *(float4*)(WC + (byte ^ ((n & 7) << 4))) = *(const float4*)((const char*)w1ct + byte);
    }
    __syncthreads();

    // u/v register prefetch (consumed in epilogue; hidden under EA fill + GEMM)
    int rrv[4], ccv[4];
#pragma unroll
    for (int rg = 0; rg < 4; rg++) {
        const int e = wv * 16 + g4 * 4 + rg;
        rrv[rg] = rsh[e];
        ccv[rg] = csh[e];
    }
    ushort_t ur[4][8], vr[4][8];
#pragma unroll
    for (int rg = 0; rg < 4; rg++)
#pragma unroll
        for (int n = 0; n < 8; n++) {
            ur[rg][n] = ub[(size_t)rrv[rg] * HH + n * 16 + col0];
            vr[rg][n] = vb[(size_t)ccv[rg] * HH + n * 16 + col0];
        }

    // EA fill (bf16 gaussians, no decay here)
    {
        const int e = tid & 63, jg = tid >> 6;
        const float d = dsh[e];
        for (int jj = jg; jj < 8; jj += 4) {
            bf16x8 pk;
#pragma unroll
            for (int b = 0; b < 8; b++) {
                const int g = jj * 8 + b;
                float val = 0.0f;
                if (g < GG) { const float t = d - g * GSTEP; val = fast_exp2(GC2 * t * t); }
                pk[b] = (short)f2bf(val);
            }
            const int byte = e * 128 + jj * 16;
            *(bf16x8*)(EA + (byte ^ ((e & 7) << 4))) = pk;
        }
    }
    float b1v[8], w2v[8];
#pragma unroll
    for (int n = 0; n < 8; n++) {
        b1v[n] = attn_b1[n * 16 + col0];
        w2v[n] = attn_w2[n * 16 + col0];
    }
    __syncthreads();

    const int m = wv * 16 + col0;
    f32x4 acc[8] = {};
#pragma unroll
    for (int kk = 0; kk < 2; kk++) {
        const int abyte = m * 128 + kk * 64 + g4 * 16;
        const bf16x8 af = *(const bf16x8*)(EA + (abyte ^ ((m & 7) << 4)));
#pragma unroll
        for (int n = 0; n < 8; n++) {
            const int l = n * 16 + col0;
            const int bbyte = l * 128 + kk * 64 + g4 * 16;
            const bf16x8 bf_ = *(const bf16x8*)(WC + (bbyte ^ ((l & 7) << 4)));
            acc[n] = __builtin_amdgcn_mfma_f32_16x16x32_bf16(af, bf_, acc[n], 0, 0, 0);
        }
    }

    float pe[4] = {0.0f, 0.0f, 0.0f, 0.0f};
#pragma unroll
    for (int n = 0; n < 8; n++) {
#pragma unroll
        for (int rg = 0; rg < 4; rg++) {
            float z = acc[n][rg] + bf2f(ur[rg][n]) + bf2f(vr[rg][n]) + b1v[n];
            z = fmaxf(z, 0.0f);
            pe[rg] += z * w2v[n];
        }
    }
#pragma unroll
    for (int mask = 1; mask <= 8; mask <<= 1) {
#pragma unroll
        for (int rg = 0; rg < 4; rg++)
            pe[rg] += __shfl_xor(pe[rg], mask, 64);
    }
    if (col0 == 0) {
        const float b2 = attn_b2[0];
        const int mode = *flagp;
#pragma unroll
        for (int rg = 0; rg < 4; rg++) {
            const int e = wv * 16 + g4 * 4 + rg;
            const float s = pe[rg] + b2;
            score[e0 + e] = s;
            if (get_mask(maskp, mode, e0 + e))
                atomicMax(&menc[rsh[e]], fenc(s));
        }
    }
}

// ---------------------------------------------------------------------------
__global__ void k_ssum(const float* __restrict__ score, const int* __restrict__ ei,
                       const void* __restrict__ maskp, const int* __restrict__ flagp,
                       const unsigned* __restrict__ menc, float* __restrict__ ssum)
{
    const int e = blockIdx.x * 256 + threadIdx.x;
    if (e >= EE) return;
    const int mode = *flagp;
    if (get_mask(maskp, mode, e)) {
        const int r = ei[e];
        const float m = fdec(menc[r]);
        atomicAdd(&ssum[r], fexpf(score[e] - m));
    }
}

// ---------------------------------------------------------------------------
__global__ __launch_bounds__(512) void k_scan(const int* __restrict__ count,
                                              int* __restrict__ cursor)
{
    __shared__ int s[512];
    const int t = threadIdx.x;
    const int base_i = t * 64;
    int sum = 0;
    for (int i = 0; i < 64; i++) sum += count[base_i + i];
    s[t] = sum;
    __syncthreads();
    for (int off = 1; off < 512; off <<= 1) {
        int v = (t >= off) ? s[t - off] : 0;
        __syncthreads();
        s[t] += v;
        __syncthreads();
    }
    int run = s[t] - sum;   // exclusive prefix
    for (int i = 0; i < 64; i++) {
        cursor[base_i + i] = run;
        run += count[base_i + i];
    }
}

// ---------------------------------------------------------------------------
// Scatter edges into dest-sorted order, materializing packed records
// erec[pos] = {d, dec, r|(c<<16), 0}. ssum/menc final before this runs.
__global__ void k_scatter(const int* __restrict__ ei, const void* __restrict__ maskp,
                          const int* __restrict__ flagp,
                          const float* __restrict__ dbuf, const float* __restrict__ score,
                          const unsigned* __restrict__ menc, const float* __restrict__ ssum,
                          int* __restrict__ cursor, uint4* __restrict__ erec)
{
    const int e = blockIdx.x * 256 + threadIdx.x;
    if (e >= EE) return;
    const int r = ei[e], c = ei[EE + e];
    const int pos = atomicAdd(&cursor[c], 1);
    const float d = dbuf[e];
    float dec = 1.0f;
    const int mode = *flagp;
    if (get_mask(maskp, mode, e)) {
        const float m = fdec(menc[r]);
        dec = fexpf(score[e] - m) / (ssum[r] + 1e-16f);
    }
    uint4 rec = {__float_as_uint(d), __float_as_uint(dec),
                 (unsigned)r | ((unsigned)c << 16), 0u};
    erec[pos] = rec;
}

// ---------------------------------------------------------------------------
// MFMA filter MLP on dest-sorted edge records + LDS segmented reduction.
__global__ __launch_bounds__(256, 4) void k_filter_mfma(
    const uint4* __restrict__ erec,
    const ushort_t* __restrict__ w1t, const float* __restrict__ filt_b1,
    const ushort_t* __restrict__ w2t, const float* __restrict__ filt_b2,
    const ushort_t* __restrict__ xhb, float* __restrict__ agg)
{
    __shared__ alignas(16) unsigned char smem[32768];
    unsigned char* EA = smem;
    unsigned char* W1 = smem + 8192;
    unsigned char* T1 = smem + 16384;
    unsigned char* WB = smem;
    float* msgb = (float*)smem;

    __shared__ float dsh[64], decsh[64], Csh[64];
    __shared__ int rsh[64], csh[64];
    __shared__ int shflags;

    const int tid  = threadIdx.x;
    const int e0   = blockIdx.x * 64;
    const int lane = tid & 63;
    const int wv   = tid >> 6;
    const int col0 = lane & 15;
    const int g4   = lane >> 4;

    // ---- phase A: coalesced record load + stage W1 half0 ----
    if (tid < 64) {
        const uint4 rec = erec[e0 + tid];
        const float d = __uint_as_float(rec.x);
        dsh[tid] = d;
        decsh[tid] = __uint_as_float(rec.y);
        rsh[tid] = (int)(rec.z & 0xFFFFu);
        csh[tid] = (int)(rec.z >> 16);
        Csh[tid] = 0.5f * (cosf(d * PI_OVER_CUT) + 1.0f);
    }
    if (tid == 64) {
        const unsigned cf = erec[e0].z >> 16;
        const unsigned cl = erec[e0 + 63].z >> 16;
        int f = 0;
        if (e0 > 0 && (erec[e0 - 1].z >> 16) == cf) f |= 1;
        if (e0 + 64 < EE && (erec[e0 + 64].z >> 16) == cl) f |= 2;
        shflags = f;
    }
    for (int p = tid; p < 512; p += 256) {       // W1 half0: 8KB
        const int byte = p * 16;
        const int n = byte >> 7;
        *(float4*)(W1 + (byte ^ ((n & 7) << 4))) = *(const float4*)((const char*)w1t + byte);
    }
    __syncthreads();

    // ---- phase B: EA fill + xh register prefetch ----
    {
        const int e = tid & 63, jg = tid >> 6;
        const float d = dsh[e], dec = decsh[e];
        for (int jj = jg; jj < 8; jj += 4) {
            bf16x8 pk;
#pragma unroll
            for (int b = 0; b < 8; b++) {
                const int g = jj * 8 + b;
                float val = 0.0f;
                if (g < GG) { const float t = d - g * GSTEP; val = fast_exp2(GC2 * t * t) * dec; }
                pk[b] = (short)f2bf(val);
            }
            const int byte = e * 128 + jj * 16;
            *(bf16x8*)(EA + (byte ^ ((e & 7) << 4))) = pk;
        }
    }
    int rr[4]; float CC[4];
#pragma unroll
    for (int rg = 0; rg < 4; rg++) {
        const int e = wv * 16 + g4 * 4 + rg;
        rr[rg] = rsh[e];
        CC[rg] = Csh[e];
    }
    ushort_t xr[4][8];                           // issued here, used in epilogue2
#pragma unroll
    for (int rg = 0; rg < 4; rg++)
#pragma unroll
        for (int n = 0; n < 8; n++)
            xr[rg][n] = xhb[(size_t)rr[rg] * HH + n * 16 + col0];
    float b1v[8], b2v[8];
#pragma unroll
    for (int n = 0; n < 8; n++) {
        b1v[n] = filt_b1[n * 16 + col0];
        b2v[n] = filt_b2[n * 16 + col0];
    }
    __syncthreads();

    // ---- GEMM1: T1 = ssp(ea @ w1 + b1), W1 staged in two 8KB halves ----
    const int m = wv * 16 + col0;
    f32x4 acc[8] = {};
#pragma unroll
    for (int h = 0; h < 2; h++) {
        if (h == 1) {
            __syncthreads();
            for (int p = tid; p < 512; p += 256) {
                const int byte = p * 16;
                const int n = byte >> 7;
                *(float4*)(W1 + (byte ^ ((n & 7) << 4))) =
                    *(const float4*)((const char*)w1t + 8192 + byte);
            }
            __syncthreads();
        }
#pragma unroll
        for (int kk = 0; kk < 2; kk++) {
            const int abyte = m * 128 + kk * 64 + g4 * 16;
            const bf16x8 af = *(const bf16x8*)(EA + (abyte ^ ((m & 7) << 4)));
#pragma unroll
            for (int q = 0; q < 4; q++) {
                const int l = q * 16 + col0;
                const int bbyte = l * 128 + kk * 64 + g4 * 16;
                const bf16x8 bf_ = *(const bf16x8*)(W1 + (bbyte ^ ((l & 7) << 4)));
                acc[h * 4 + q] = __builtin_amdgcn_mfma_f32_16x16x32_bf16(af, bf_, acc[h * 4 + q], 0, 0, 0);
            }
        }
    }
    // epilogue1 -> T1 (bf16)
#pragma unroll
    for (int n = 0; n < 8; n++) {
#pragma unroll
        for (int rg = 0; rg < 4; rg++) {
            const int row = wv * 16 + g4 * 4 + rg;
            const float tv = sspf(acc[n][rg] + b1v[n]);
            const int lbyte = row * 256 + (n * 16 + col0) * 2;
            *(ushort_t*)(T1 + (lbyte ^ ((row & 7) << 4))) = f2bf(tv);
        }
    }
    __syncthreads();

    // ---- GEMM2: W = t1 @ w2 + b2, WB staged in two 16KB halves over EA/W1 ----
    f32x4 acc2[8] = {};
#pragma unroll
    for (int h = 0; h < 2; h++) {
        for (int p = tid; p < 1024; p += 256) {
            const int byte = p * 16;
            const int nl = byte >> 8;
            *(float4*)(WB + (byte ^ ((nl & 7) << 4))) =
                *(const float4*)((const char*)w2t + h * 16384 + byte);
        }
        __syncthreads();
#pragma unroll
        for (int kk = 0; kk < 4; kk++) {
            const int abyte = m * 256 + kk * 64 + g4 * 16;
            const bf16x8 af = *(const bf16x8*)(T1 + (abyte ^ ((m & 7) << 4)));
#pragma unroll
            for (int q = 0; q < 4; q++) {
                const int l = q * 16 + col0;
                const int bbyte = l * 256 + kk * 64 + g4 * 16;
                const bf16x8 bf_ = *(const bf16x8*)(WB + (bbyte ^ ((l & 7) << 4)));
                acc2[h * 4 + q] = __builtin_amdgcn_mfma_f32_16x16x32_bf16(af, bf_, acc2[h * 4 + q], 0, 0, 0);
            }
        }
        __syncthreads();
    }

    // ---- epilogue2: msg = xh[r] * (W+b2) * C -> msgb (skewed, overlay) ----
#pragma unroll
    for (int n = 0; n < 8; n++) {
        const int col = n * 16 + col0;
#pragma unroll
        for (int rg = 0; rg < 4; rg++) {
            const int e = wv * 16 + g4 * 4 + rg;
            const float Wv = (acc2[n][rg] + b2v[n]) * CC[rg];
            const float xv = __uint_as_float(((unsigned)xr[rg][n]) << 16);
            msgb[e * 128 + ((col + 8 * g4) & 127)] = xv * Wv;
        }
    }
    __syncthreads();

    // ---- segmented reduction: 2 halves x 32 edges, all 256 threads ----
    {
        const int q = tid >> 7;          // 0 or 1
        const int j = tid & 127;
        const int base = q * 32;
        const int fl = shflags;
        const int cfirst = csh[base], clast = csh[base + 31];
        const int f1 = (q == 0) ? (fl & 1) : (csh[base - 1] == cfirst);
        const int f2 = (q == 1) ? (fl & 2) : (csh[base + 32] == clast);
        float a = msgb[base * 128 + ((j + 8 * ((base >> 2) & 3)) & 127)];
        int cur = cfirst;
        for (int e = base + 1; e < base + 32; e++) {
            const int de = csh[e];
            if (de != cur) {
                if ((cur == cfirst && f1) || (cur == clast && f2))
                    atomicAdd(&agg[(size_t)cur * HH + j], a);
                else
                    agg[(size_t)cur * HH + j] = a;
                a = 0.0f;
                cur = de;
            }
            a += msgb[e * 128 + ((j + 8 * ((e >> 2) & 3)) & 127)];
        }
        if ((cur == cfirst && f1) || (cur == clast && f2))
            atomicAdd(&agg[(size_t)cur * HH + j], a);
        else
            agg[(size_t)cur * HH + j] = a;
    }
}

// ---------------------------------------------------------------------------
// MFMA final: out = ssp(agg @ lin2 + b2) @ lin + b.
__global__ __launch_bounds__(256, 4) void k_final(
    const float* __restrict__ agg, const ushort_t* __restrict__ l2t,
    const float* __restrict__ lin2_b, const ushort_t* __restrict__ lwt,
    const float* __restrict__ lin_b, float* __restrict__ out)
{
    __shared__ alignas(16) unsigned char smem[32768];
    unsigned char* AB = smem;          // bf16[64][128] swz; later T1
    unsigned char* WB = smem + 16384;
    unsigned char* T1 = smem;

    const int tid = threadIdx.x;
    const int n0 = blockIdx.x * 64;

    for (int p = tid; p < 2048; p += 256) {        // stage AB (f32 -> bf16)
        const int row = p >> 5, c4 = p & 31;
        const float4 v = *(const float4*)(agg + (size_t)(n0 + row) * HH + c4 * 4);
        uint2 pk = {(unsigned)f2bf(v.x) | ((unsigned)f2bf(v.y) << 16),
                    (unsigned)f2bf(v.z) | ((unsigned)f2bf(v.w) << 16)};
        const int lbyte = row * 256 + c4 * 8;
        *(uint2*)(AB + (lbyte ^ ((row & 7) << 4))) = pk;
    }
    for (int p = tid; p < 1024; p += 256) {        // stage WB: l2t half0
        const int byte = p * 16; const int nl = byte >> 8;
        *(float4*)(WB + (byte ^ ((nl & 7) << 4))) = *(const float4*)((const char*)l2t + byte);
    }
    __syncthreads();

    const int lane = tid & 63, wv = tid >> 6, col0 = lane & 15, g4 = lane >> 4;
    const int m = wv * 16 + col0;
    float b1v[8], b2v[8];
#pragma unroll
    for (int f = 0; f < 8; f++) {
        const int colf = (f >> 2) * 64 + (f & 3) * 16 + col0;
        b1v[f] = lin2_b[colf];
        b2v[f] = lin_b[colf];
    }

    f32x4 acc[8] = {};
#pragma unroll
    for (int h = 0; h < 2; h++) {
        if (h == 1) {
            __syncthreads();
            for (int p = tid; p < 1024; p += 256) {
                const int byte = p * 16; const int nl = byte >> 8;
                *(float4*)(WB + (byte ^ ((nl & 7) << 4))) =
                    *(const float4*)((const char*)l2t + 16384 + byte);
            }
            __syncthreads();
        }
#pragma unroll
        for (int kk = 0; kk < 4; kk++) {
            const int abyte = m * 256 + kk * 64 + g4 * 16;
            const bf16x8 af = *(const bf16x8*)(AB + (abyte ^ ((m & 7) << 4)));
#pragma unroll
            for (int q = 0; q < 4; q++) {
                const int l = q * 16 + col0;
                const int bbyte = l * 256 + kk * 64 + g4 * 16;
                const bf16x8 bf_ = *(const bf16x8*)(WB + (bbyte ^ ((l & 7) << 4)));
                acc[h * 4 + q] = __builtin_amdgcn_mfma_f32_16x16x32_bf16(af, bf_, acc[h * 4 + q], 0, 0, 0);
            }
        }
    }
    __syncthreads();   // all GEMM1 reads done; AB may be overlaid by T1

    // T2 = ssp(acc + b1) -> T1 (bf16); stage WB: lwt half0 in parallel
#pragma unroll
    for (int f = 0; f < 8; f++) {
        const int colf = (f >> 2) * 64 + (f & 3) * 16 + col0;
#pragma unroll
        for (int rg = 0; rg < 4; rg++) {
            const int row = wv * 16 + g4 * 4 + rg;
            const float tv = sspf(acc[f][rg] + b1v[f]);
            const int lbyte = row * 256 + colf * 2;
            *(ushort_t*)(T1 + (lbyte ^ ((row & 7) << 4))) = f2bf(tv);
        }
    }
    for (int p = tid; p < 1024; p += 256) {
        const int byte = p * 16; const int nl = byte >> 8;
        *(float4*)(WB + (byte ^ ((nl & 7) << 4))) = *(const float4*)((const char*)lwt + byte);
    }
    __syncthreads();

    f32x4 acc2[8] = {};
#pragma unroll
    for (int h = 0; h < 2; h++) {
        if (h == 1) {
            __syncthreads();
            for (int p = tid; p < 1024; p += 256) {
                const int byte = p * 16; const int nl = byte >> 8;
                *(float4*)(WB + (byte ^ ((nl & 7) << 4))) =
                    *(const float4*)((const char*)lwt + 16384 + byte);
            }
            __syncthreads();
        }
#pragma unroll
        for (int kk = 0; kk < 4; kk++) {
            const int abyte = m * 256 + kk * 64 + g4 * 16;
            const bf16x8 af = *(const bf16x8*)(T1 + (abyte ^ ((m & 7) << 4)));
#pragma unroll
            for (int q = 0; q < 4; q++) {
                const int l = q * 16 + col0;
                const int bbyte = l * 256 + kk * 64 + g4 * 16;
                const bf16x8 bf_ = *(const bf16x8*)(WB + (bbyte ^ ((l & 7) << 4)));
                acc2[h * 4 + q] = __builtin_amdgcn_mfma_f32_16x16x32_bf16(af, bf_, acc2[h * 4 + q], 0, 0, 0);
            }
        }
    }
#pragma unroll
    for (int f = 0; f < 8; f++) {
        const int colf = (f >> 2) * 64 + (f & 3) * 16 + col0;
#pragma unroll
        for (int rg = 0; rg < 4; rg++) {
            const int row = wv * 16 + g4 * 4 + rg;
            out[(size_t)(n0 + row) * HH + colf] = acc2[f][rg] + b2v[f];
        }
    }
}

// ---------------------------------------------------------------------------
__global__ void k_copy_pos(const float* __restrict__ pos, float* __restrict__ out) {
    const int i = blockIdx.x * 256 + threadIdx.x;
    if (i < NN * 3) out[i] = pos[i];
}

// ---------------------------------------------------------------------------
extern "C" void kernel_launch(void* const* d_in, const int* in_sizes, int n_in,
                              void* d_out, int out_size, void* d_ws, size_t ws_size,
                              hipStream_t stream)
{
    const float* h       = (const float*)d_in[0];
    const float* pos     = (const float*)d_in[1];
    const int*   ei      = (const int*)d_in[2];
    const void*  maskp   = d_in[3];
    const float* attn_w1 = (const float*)d_in[4];
    const float* attn_b1 = (const float*)d_in[5];
    const float* attn_w2 = (const float*)d_in[6];
    const float* attn_b2 = (const float*)d_in[7];
    const float* filt_w1 = (const float*)d_in[8];
    const float* filt_b1 = (const float*)d_in[9];
    const float* filt_w2 = (const float*)d_in[10];
    const float* filt_b2 = (const float*)d_in[11];
    const float* lin1_w  = (const float*)d_in[12];
    const float* lin2_w  = (const float*)d_in[13];
    const float* lin2_b  = (const float*)d_in[14];
    const float* lin_w   = (const float*)d_in[15];
    const float* lin_b   = (const float*)d_in[16];

    char* p = (char*)d_ws;
    auto alloc = [&](size_t bytes) { char* r = p; p += (bytes + 255) & ~(size_t)255; return r; };

    ushort_t* ub    = (ushort_t*)alloc((size_t)NN * HH * 2);
    ushort_t* vb    = (ushort_t*)alloc((size_t)NN * HH * 2);
    ushort_t* xhb   = (ushort_t*)alloc((size_t)NN * HH * 2);
    float*    dbuf  = (float*)alloc((size_t)EE * 4);
    float*    score = (float*)alloc((size_t)EE * 4);
    unsigned* menc  = (unsigned*)alloc((size_t)NN * 4);   // menc/ssum/count contiguous
    float*    ssum  = (float*)alloc((size_t)NN * 4);      // (each 128KB, 256B-aligned)
    int*      count = (int*)alloc((size_t)NN * 4);
    int*      cursor= (int*)alloc((size_t)NN * 4);
    float*    agg   = (float*)alloc((size_t)NN * HH * 4);
    int*      flag  = (int*)alloc(4);
    uint4*    erec  = (uint4*)alloc((size_t)EE * 16);
    ushort_t* w1t   = (ushort_t*)alloc((size_t)128 * 64 * 2);
    ushort_t* w1ct  = (ushort_t*)alloc((size_t)128 * 64 * 2);
    ushort_t* w2t   = (ushort_t*)alloc((size_t)128 * 128 * 2);
    ushort_t* wut   = (ushort_t*)alloc((size_t)128 * 128 * 2);
    ushort_t* wvt   = (ushort_t*)alloc((size_t)128 * 128 * 2);
    ushort_t* wxt   = (ushort_t*)alloc((size_t)128 * 128 * 2);
    ushort_t* l2t   = (ushort_t*)alloc((size_t)128 * 128 * 2);
    ushort_t* lwt   = (ushort_t*)alloc((size_t)128 * 128 * 2);

    float* out_h   = (float*)d_out;
    float* out_pos = out_h + (size_t)NN * HH;

    hipMemsetAsync(menc, 0, (size_t)3 * NN * 4, stream);   // menc + ssum + count

    k_detect<<<1, 256, 0, stream>>>((const unsigned char*)maskp, flag);
    k_prep_w<<<448, 256, 0, stream>>>(filt_w1, filt_w2, attn_w1, lin1_w, lin2_w, lin_w,
                                      w1t, w1ct, w2t, wut, wvt, wxt, l2t, lwt);
    k_node_proj<<<dim3(NN / 64, 3), 256, 0, stream>>>(h, wut, wvt, wxt, ub, vb, xhb);
    k_edge_score<<<EE / 64, 256, 0, stream>>>(pos, ei, maskp, flag, ub, vb,
                                              w1ct, attn_b1, attn_w2, attn_b2,
                                              dbuf, score, menc, count);
    k_ssum<<<EE / 256, 256, 0, stream>>>(score, ei, maskp, flag, menc, ssum);
    k_scan<<<1, 512, 0, stream>>>(count, cursor);
    k_scatter<<<EE / 256, 256, 0, stream>>>(ei, maskp, flag, dbuf, score, menc, ssum,
                                            cursor, erec);

    hipMemsetAsync(agg, 0, (size_t)NN * HH * sizeof(float), stream);
    k_filter_mfma<<<EE / 64, 256, 0, stream>>>(erec, w1t, filt_b1, w2t, filt_b2, xhb, agg);

    k_final<<<NN / 64, 256, 0, stream>>>(agg, l2t, lin2_b, lwt, lin_b, out_h);
    k_copy_pos<<<(NN * 3 + 255) / 256, 256, 0, stream>>>(pos, out_pos);
}